// Round 1
// baseline (9163.067 us; speedup 1.0000x reference)
//
#include <hip/hip_runtime.h>
#include <hip/hip_bf16.h>

#define DEV_INLINE __device__ __forceinline__

constexpr int kN   = 50000;
constexpr int kNT  = 300000;
constexpr int kR   = 64;
constexpr int kRP  = 16;
constexpr int kE   = 32;
constexpr int kC   = 32;
constexpr int kLW  = 64;
constexpr int kNRP = kN * kRP;   // 800000

// ---------- dtype-flexible load helpers ----------
DEV_INLINE float ldf(const void* p, long long i, int isbf) {
  if (isbf) return __bfloat162float(((const __hip_bfloat16*)p)[i]);
  return ((const float*)p)[i];
}
DEV_INLINE float bflo(unsigned u) { union { unsigned x; float f; } a; a.x = u << 16;        return a.f; }
DEV_INLINE float bfhi(unsigned u) { union { unsigned x; float f; } a; a.x = u & 0xffff0000u; return a.f; }

DEV_INLINE float wave_sum(float v) {
#pragma unroll
  for (int off = 32; off > 0; off >>= 1) v += __shfl_down(v, off, 64);
  return v;
}

// ---------- dtype detection ----------
// weights1 ~ N(0,0.05). If truly bf16, all |v|<=1. If fp32 misread as bf16,
// the low-half words are random-exponent bf16s -> |v|>1 / NaN with certainty.
__global__ void k_detect(const void* __restrict__ w1, int* __restrict__ flag) {
  __shared__ int bad;
  if (threadIdx.x == 0) bad = 0;
  __syncthreads();
  const __hip_bfloat16* b = (const __hip_bfloat16*)w1;
  for (int i = threadIdx.x; i < 1024; i += blockDim.x) {
    float v = __bfloat162float(b[i]);
    if (!(v <= 1.0f && v >= -1.0f)) atomicOr(&bad, 1);
  }
  __syncthreads();
  if (threadIdx.x == 0) flag[0] = bad ? 0 : 1;   // 1 = bf16 inputs/outputs
}

// ---------- MLP weights -> LDS ----------
DEV_INLINE void load_w_lds(const void* Wa, const void* ba, const void* Wb, const void* bb,
                           int isbf, float* swa, float* sba, float* swb, float* sbb) {
  const int tid = threadIdx.x;
  for (int i = tid; i < kR * kLW; i += 256) swa[i] = ldf(Wa, i, isbf);
  for (int i = tid; i < kLW * kRP; i += 256) swb[i] = ldf(Wb, i, isbf);
  if (tid < kLW) sba[tid] = ldf(ba, tid, isbf);
  else if (tid < kLW + kRP) sbb[tid - kLW] = ldf(bb, tid - kLW, isbf);
  __syncthreads();
}

// ---------- per-edge MLP + softmax -> lat[16] ----------
DEV_INLINE void compute_lat16(const void* nhots, long long t, int isbf,
                              const float* swa, const float* sba,
                              const float* swb, const float* sbb, float lat[kRP]) {
  float x[kR];
  if (isbf) {
    const __hip_bfloat16* q = (const __hip_bfloat16*)nhots + t * kR;
#pragma unroll
    for (int j = 0; j < kR; j++) x[j] = __bfloat162float(q[j]);
  } else {
    const float* q = (const float*)nhots + t * kR;
#pragma unroll
    for (int j = 0; j < kR; j++) x[j] = q[j];
  }
  float hid[kLW];
#pragma unroll 4
  for (int j = 0; j < kLW; j++) {
    float a = sba[j];
#pragma unroll
    for (int l = 0; l < kR; l++) a = fmaf(x[l], swa[l * kLW + j], a);
    hid[j] = fmaxf(a, 0.f);
  }
#pragma unroll 4
  for (int p = 0; p < kRP; p++) {
    float a = sbb[p];
#pragma unroll
    for (int l = 0; l < kLW; l++) a = fmaf(hid[l], swb[l * kRP + p], a);
    lat[p] = a;
  }
  float m = lat[0];
#pragma unroll
  for (int p = 1; p < kRP; p++) m = fmaxf(m, lat[p]);
  float s = 0.f;
#pragma unroll
  for (int p = 0; p < kRP; p++) { lat[p] = __expf(lat[p] - m); s += lat[p]; }
  const float inv = 1.f / s;
#pragma unroll
  for (int p = 0; p < kRP; p++) lat[p] *= inv;
}

// ---------- K1: lat1/lat2 + colsum/rowsum scatter ----------
template <bool STORE>
__global__ void __launch_bounds__(256)
k_lat(const int* __restrict__ s_idx, const int* __restrict__ o_idx,
      const void* __restrict__ nhots,
      const void* W1a, const void* b1a, const void* W1b, const void* b1b,
      const void* W2a, const void* b2a, const void* W2b, const void* b2b,
      const int* __restrict__ flag,
      float* __restrict__ lat1o, float* __restrict__ lat2o,
      float* __restrict__ colsum, float* __restrict__ rowsum) {
  __shared__ float swa[kR * kLW], swb[kLW * kRP], sba[kLW], sbb[kRP];
  const int tid = threadIdx.x;
  const int isbf = *flag;
  const long long t = (long long)blockIdx.x * 256 + tid;
  const bool valid = t < kNT;
  const long long tt = valid ? t : 0;
  const int s = s_idx[tt], o = o_idx[tt];
  float lat[kRP];

  // ---- MLP1 -> colsum ----
  load_w_lds(W1a, b1a, W1b, b1b, isbf, swa, sba, swb, sbb);
  compute_lat16(nhots, tt, isbf, swa, sba, swb, sbb, lat);
  if (STORE && valid) {
#pragma unroll
    for (int p = 0; p < kRP; p++) lat1o[t * kRP + p] = lat[p];
  }
  {
    float v0 = valid ? lat[0] : 0.f;      // k=0 -> colsum[0] hotspot
    v0 = wave_sum(v0);
    if ((tid & 63) == 0) atomicAdd(&colsum[0], v0);
  }
  if (valid) {
#pragma unroll
    for (int k = 1; k < kRP; k++) atomicAdd(&colsum[o * k], lat[k]);
  }
  __syncthreads();

  // ---- MLP2 -> rowsum ----
  load_w_lds(W2a, b2a, W2b, b2b, isbf, swa, sba, swb, sbb);
  compute_lat16(nhots, tt, isbf, swa, sba, swb, sbb, lat);
  if (STORE && valid) {
#pragma unroll
    for (int p = 0; p < kRP; p++) lat2o[t * kRP + p] = lat[p];
  }
  {
    float v0 = valid ? lat[0] : 0.f;
    v0 = wave_sum(v0);
    if ((tid & 63) == 0) atomicAdd(&rowsum[0], v0);
  }
  if (valid) {
#pragma unroll
    for (int k = 1; k < kRP; k++) atomicAdd(&rowsum[s * k], lat[k]);
  }
}

// ---------- K2: layer-1 spmm scatter into h ----------
template <bool USE_LAT>
__global__ void __launch_bounds__(256)
k_layer1(const int* __restrict__ s_idx, const int* __restrict__ o_idx,
         const void* __restrict__ nhots,
         const void* W1a, const void* b1a, const void* W1b, const void* b1b,
         const void* __restrict__ wt1, const int* __restrict__ flag,
         const float* __restrict__ lat1, const float* __restrict__ colsum,
         float* __restrict__ h) {
  const int tid = threadIdx.x;
  const int isbf = *flag;
  const long long t = (long long)blockIdx.x * 256 + tid;
  const bool valid = t < kNT;
  const long long tt = valid ? t : 0;
  const int s = s_idx[tt], o = o_idx[tt];

  float lat[kRP];
  if constexpr (USE_LAT) {
    const float4* lp = (const float4*)(lat1 + tt * kRP);
#pragma unroll
    for (int q = 0; q < 4; q++) {
      float4 u = lp[q];
      lat[q * 4 + 0] = u.x; lat[q * 4 + 1] = u.y; lat[q * 4 + 2] = u.z; lat[q * 4 + 3] = u.w;
    }
  } else {
    __shared__ float swa[kR * kLW], swb[kLW * kRP], sba[kLW], sbb[kRP];
    load_w_lds(W1a, b1a, W1b, b1b, isbf, swa, sba, swb, sbb);
    compute_lat16(nhots, tt, isbf, swa, sba, swb, sbb, lat);
  }

  float acc[kE];
#pragma unroll
  for (int c = 0; c < kE; c++) acc[c] = 0.f;

  if (isbf) {
#pragma unroll 4
    for (int k = 0; k < kRP; k++) {
      const int idx = o * k;
      const float v = lat[k] / colsum[idx];
      const uint4* rp = (const uint4*)((const __hip_bfloat16*)wt1 + (size_t)idx * kE);
#pragma unroll
      for (int q = 0; q < 4; q++) {
        uint4 u = rp[q];
        acc[q * 8 + 0] = fmaf(v, bflo(u.x), acc[q * 8 + 0]);
        acc[q * 8 + 1] = fmaf(v, bfhi(u.x), acc[q * 8 + 1]);
        acc[q * 8 + 2] = fmaf(v, bflo(u.y), acc[q * 8 + 2]);
        acc[q * 8 + 3] = fmaf(v, bfhi(u.y), acc[q * 8 + 3]);
        acc[q * 8 + 4] = fmaf(v, bflo(u.z), acc[q * 8 + 4]);
        acc[q * 8 + 5] = fmaf(v, bfhi(u.z), acc[q * 8 + 5]);
        acc[q * 8 + 6] = fmaf(v, bflo(u.w), acc[q * 8 + 6]);
        acc[q * 8 + 7] = fmaf(v, bfhi(u.w), acc[q * 8 + 7]);
      }
    }
  } else {
#pragma unroll 4
    for (int k = 0; k < kRP; k++) {
      const int idx = o * k;
      const float v = lat[k] / colsum[idx];
      const float4* rp = (const float4*)((const float*)wt1 + (size_t)idx * kE);
#pragma unroll
      for (int q = 0; q < 8; q++) {
        float4 u = rp[q];
        acc[q * 4 + 0] = fmaf(v, u.x, acc[q * 4 + 0]);
        acc[q * 4 + 1] = fmaf(v, u.y, acc[q * 4 + 1]);
        acc[q * 4 + 2] = fmaf(v, u.z, acc[q * 4 + 2]);
        acc[q * 4 + 3] = fmaf(v, u.w, acc[q * 4 + 3]);
      }
    }
  }
  if (valid) {
#pragma unroll
    for (int c = 0; c < kE; c++) atomicAdd(&h[(size_t)s * kE + c], acc[c]);
  }
}

// ---------- K3: h = relu(h + bias1) ----------
__global__ void __launch_bounds__(256)
k_relu_bias(float* __restrict__ h, const void* __restrict__ bias1, const int* __restrict__ flag) {
  const int i = blockIdx.x * 256 + threadIdx.x;
  if (i < kN * kE) {
    const int isbf = *flag;
    h[i] = fmaxf(h[i] + ldf(bias1, i & (kE - 1), isbf), 0.f);
  }
}

// ---------- K4a: layer-2 scatter into h2 (row 0 via LDS accumulator) ----------
template <bool USE_LAT>
__global__ void __launch_bounds__(256)
k_layer2_h2(const int* __restrict__ s_idx, const int* __restrict__ o_idx,
            const void* __restrict__ nhots,
            const void* W2a, const void* b2a, const void* W2b, const void* b2b,
            const int* __restrict__ flag, const float* __restrict__ lat2,
            const float* __restrict__ rowsum, const float* __restrict__ h,
            float* __restrict__ h2) {
  __shared__ float acc0[kE];
  const int tid = threadIdx.x;
  if (tid < kE) acc0[tid] = 0.f;
  const int isbf = *flag;
  const long long t = (long long)blockIdx.x * 256 + tid;
  const bool valid = t < kNT;
  const long long tt = valid ? t : 0;
  const int s = s_idx[tt], o = o_idx[tt];

  float lat[kRP];
  if constexpr (USE_LAT) {
    __syncthreads();
    const float4* lp = (const float4*)(lat2 + tt * kRP);
#pragma unroll
    for (int q = 0; q < 4; q++) {
      float4 u = lp[q];
      lat[q * 4 + 0] = u.x; lat[q * 4 + 1] = u.y; lat[q * 4 + 2] = u.z; lat[q * 4 + 3] = u.w;
    }
  } else {
    __shared__ float swa[kR * kLW], swb[kLW * kRP], sba[kLW], sbb[kRP];
    load_w_lds(W2a, b2a, W2b, b2b, isbf, swa, sba, swb, sbb);  // has trailing sync
    compute_lat16(nhots, tt, isbf, swa, sba, swb, sbb, lat);
  }

  float hv[kE];
  {
    const float4* hp = (const float4*)(h + (size_t)o * kE);
#pragma unroll
    for (int q = 0; q < 8; q++) {
      float4 u = hp[q];
      hv[q * 4 + 0] = u.x; hv[q * 4 + 1] = u.y; hv[q * 4 + 2] = u.z; hv[q * 4 + 3] = u.w;
    }
  }

  if (valid) {
#pragma unroll 1
    for (int k = 0; k < kRP; k++) {
      const int idx = s * k;
      const float v = lat[k] / rowsum[idx];
      if (idx == 0) {
#pragma unroll
        for (int c = 0; c < kE; c++) atomicAdd(&acc0[c], v * hv[c]);
      } else {
        float* dst = h2 + (size_t)idx * kE;
#pragma unroll
        for (int c = 0; c < kE; c++) atomicAdd(dst + c, v * hv[c]);
      }
    }
  }
  __syncthreads();
  if (tid < kE) atomicAdd(&h2[tid], acc0[tid]);
}

// ---------- K5a: out[n,c] = sum_r h2[r*N+n,:] . W2[r,:,c] + bias2 ----------
__global__ void __launch_bounds__(256)
k_out_h2(const float* __restrict__ h2, const void* __restrict__ W2,
         const void* __restrict__ bias2, const int* __restrict__ flag,
         void* __restrict__ out) {
  __shared__ float sw[kRP * kE * kC];   // 64 KB
  const int tid = threadIdx.x;
  const int isbf = *flag;
  for (int i = tid; i < kRP * kE * kC; i += 256) sw[i] = ldf(W2, i, isbf);
  __syncthreads();
  const int lane = tid & 31;
  const int grp = tid >> 5;
  const float b = ldf(bias2, lane, isbf);
  for (int np = blockIdx.x * 8 + grp; np < kN; np += gridDim.x * 8) {
    float acc = b;
#pragma unroll 4
    for (int r = 0; r < kRP; r++) {
      const float* row = h2 + ((size_t)r * kN + np) * kE;
#pragma unroll
      for (int hh = 0; hh < kE; hh++)
        acc = fmaf(row[hh], sw[(r * kE + hh) * kC + lane], acc);
    }
    if (isbf) ((__hip_bfloat16*)out)[(size_t)np * kC + lane] = __float2bfloat16(acc);
    else ((float*)out)[(size_t)np * kC + lane] = acc;
  }
}

// ---------- K4b (fallback, no h2 in ws): per-contribution matvec -> out32 ----------
template <bool USE_LAT>
__global__ void __launch_bounds__(256)
k_layer2_direct(const int* __restrict__ s_idx, const int* __restrict__ o_idx,
                const void* __restrict__ nhots,
                const void* W2a, const void* b2a, const void* W2b, const void* b2b,
                const void* __restrict__ wt2,
                const int* __restrict__ flag, const float* __restrict__ lat2,
                const float* __restrict__ rowsum, const float* __restrict__ h,
                float* __restrict__ out32) {
  __shared__ float zacc[kE];
  const int tid = threadIdx.x;
  if (tid < kE) zacc[tid] = 0.f;
  const int isbf = *flag;
  const long long t = (long long)blockIdx.x * 256 + tid;
  const bool valid = t < kNT;
  const long long tt = valid ? t : 0;
  const int s = s_idx[tt], o = o_idx[tt];

  float lat[kRP];
  if constexpr (USE_LAT) {
    __syncthreads();
    const float4* lp = (const float4*)(lat2 + tt * kRP);
#pragma unroll
    for (int q = 0; q < 4; q++) {
      float4 u = lp[q];
      lat[q * 4 + 0] = u.x; lat[q * 4 + 1] = u.y; lat[q * 4 + 2] = u.z; lat[q * 4 + 3] = u.w;
    }
  } else {
    __shared__ float swa[kR * kLW], swb[kLW * kRP], sba[kLW], sbb[kRP];
    load_w_lds(W2a, b2a, W2b, b2b, isbf, swa, sba, swb, sbb);
    compute_lat16(nhots, tt, isbf, swa, sba, swb, sbb, lat);
  }

  float hv[kE];
  {
    const float4* hp = (const float4*)(h + (size_t)o * kE);
#pragma unroll
    for (int q = 0; q < 8; q++) {
      float4 u = hp[q];
      hv[q * 4 + 0] = u.x; hv[q * 4 + 1] = u.y; hv[q * 4 + 2] = u.z; hv[q * 4 + 3] = u.w;
    }
  }

  if (valid) {
#pragma unroll 1
    for (int k = 0; k < kRP; k++) {
      const int idx = s * k;
      const float v = lat[k] / rowsum[idx];
      if (idx == 0) {
#pragma unroll
        for (int c = 0; c < kE; c++) atomicAdd(&zacc[c], v * hv[c]);
      } else {
        const int r = idx / kN, nn = idx % kN;
        float* dst = out32 + (size_t)nn * kC;
#pragma unroll 1
        for (int c = 0; c < kC; c++) {
          float a = 0.f;
#pragma unroll
          for (int hh = 0; hh < kE; hh++)
            a = fmaf(hv[hh], ldf(wt2, (size_t)(r * kE + hh) * kC + c, isbf), a);
          atomicAdd(dst + c, v * a);
        }
      }
    }
  }
  __syncthreads();
  if (tid < kC) {
    float a = 0.f;
#pragma unroll
    for (int hh = 0; hh < kE; hh++)
      a = fmaf(zacc[hh], ldf(wt2, (size_t)hh * kC + tid, isbf), a);
    atomicAdd(&out32[tid], a);
  }
}

__global__ void __launch_bounds__(256)
k_out_direct(const float* __restrict__ out32, const void* __restrict__ bias2,
             const int* __restrict__ flag, void* __restrict__ out) {
  const int i = blockIdx.x * 256 + threadIdx.x;
  if (i < kN * kC) {
    const int isbf = *flag;
    const float v = out32[i] + ldf(bias2, i & (kC - 1), isbf);
    if (isbf) ((__hip_bfloat16*)out)[i] = __float2bfloat16(v);
    else ((float*)out)[i] = v;
  }
}

// ---------- host ----------
extern "C" void kernel_launch(void* const* d_in, const int* in_sizes, int n_in,
                              void* d_out, int out_size, void* d_ws, size_t ws_size,
                              hipStream_t stream) {
  (void)in_sizes; (void)n_in; (void)out_size;
  const int* s_idx = (const int*)d_in[0];
  const int* o_idx = (const int*)d_in[1];
  const void* nhots = d_in[2];
  const void* W1a = d_in[3]; const void* b1a = d_in[4];
  const void* W1b = d_in[5]; const void* b1b = d_in[6];
  const void* W2a = d_in[7]; const void* b2a = d_in[8];
  const void* W2b = d_in[9]; const void* b2b = d_in[10];
  const void* wt1 = d_in[11]; const void* wt2 = d_in[12];
  const void* bias1 = d_in[13]; const void* bias2 = d_in[14];

  char* ws = (char*)d_ws;
  const size_t SZ_CS  = (size_t)kNRP * 4;            // 3.2 MB
  const size_t SZ_H   = (size_t)kN * kE * 4;         // 6.4 MB
  const size_t SZ_H2  = (size_t)kNRP * kE * 4;       // 102.4 MB
  const size_t SZ_LAT = (size_t)kNT * kRP * 4;       // 19.2 MB
  const size_t SZ_O32 = (size_t)kN * kC * 4;         // 6.4 MB

  const size_t base = 256 + 2 * SZ_CS + SZ_H;
  bool use_h2, store_lat;
  if      (ws_size >= base + SZ_H2 + 2 * SZ_LAT) { use_h2 = true;  store_lat = true;  }
  else if (ws_size >= base + SZ_H2)              { use_h2 = true;  store_lat = false; }
  else if (ws_size >= base + SZ_O32 + 2 * SZ_LAT){ use_h2 = false; store_lat = true;  }
  else                                           { use_h2 = false; store_lat = false; }

  size_t off = 0;
  int*   flag   = (int*)(ws + off);   off += 256;
  float* colsum = (float*)(ws + off); off += SZ_CS;
  float* rowsum = (float*)(ws + off); off += SZ_CS;
  float* hbuf   = (float*)(ws + off); off += SZ_H;
  float* big    = (float*)(ws + off);
  const size_t bigsz = use_h2 ? SZ_H2 : SZ_O32;     off += bigsz;
  float* lat1 = nullptr, *lat2 = nullptr;
  if (store_lat) { lat1 = (float*)(ws + off); off += SZ_LAT; lat2 = (float*)(ws + off); off += SZ_LAT; }

  hipMemsetAsync(ws + 256, 0, 2 * SZ_CS + SZ_H + bigsz, stream);
  k_detect<<<1, 256, 0, stream>>>(wt1, flag);

  const dim3 blk(256);
  const int gEdges = (kNT + 255) / 256;
  const int gElems = (kN * kE + 255) / 256;

  if (store_lat)
    k_lat<true><<<gEdges, blk, 0, stream>>>(s_idx, o_idx, nhots, W1a, b1a, W1b, b1b,
                                            W2a, b2a, W2b, b2b, flag, lat1, lat2, colsum, rowsum);
  else
    k_lat<false><<<gEdges, blk, 0, stream>>>(s_idx, o_idx, nhots, W1a, b1a, W1b, b1b,
                                             W2a, b2a, W2b, b2b, flag, lat1, lat2, colsum, rowsum);

  if (store_lat)
    k_layer1<true><<<gEdges, blk, 0, stream>>>(s_idx, o_idx, nhots, W1a, b1a, W1b, b1b,
                                               wt1, flag, lat1, colsum, hbuf);
  else
    k_layer1<false><<<gEdges, blk, 0, stream>>>(s_idx, o_idx, nhots, W1a, b1a, W1b, b1b,
                                                wt1, flag, lat1, colsum, hbuf);

  k_relu_bias<<<gElems, blk, 0, stream>>>(hbuf, bias1, flag);

  if (use_h2) {
    if (store_lat)
      k_layer2_h2<true><<<gEdges, blk, 0, stream>>>(s_idx, o_idx, nhots, W2a, b2a, W2b, b2b,
                                                    flag, lat2, rowsum, hbuf, big);
    else
      k_layer2_h2<false><<<gEdges, blk, 0, stream>>>(s_idx, o_idx, nhots, W2a, b2a, W2b, b2b,
                                                     flag, lat2, rowsum, hbuf, big);
    k_out_h2<<<2048, blk, 0, stream>>>(big, wt2, bias2, flag, d_out);
  } else {
    if (store_lat)
      k_layer2_direct<true><<<gEdges, blk, 0, stream>>>(s_idx, o_idx, nhots, W2a, b2a, W2b, b2b,
                                                        wt2, flag, lat2, rowsum, hbuf, big);
    else
      k_layer2_direct<false><<<gEdges, blk, 0, stream>>>(s_idx, o_idx, nhots, W2a, b2a, W2b, b2b,
                                                         wt2, flag, lat2, rowsum, hbuf, big);
    k_out_direct<<<gElems, blk, 0, stream>>>(big, bias2, flag, d_out);
  }
}

// Round 2
// 3590.713 us; speedup vs baseline: 2.5519x; 2.5519x over previous
//
#include <hip/hip_runtime.h>
#include <hip/hip_bf16.h>

#define DEV_INLINE __device__ __forceinline__

constexpr int kN   = 50000;
constexpr int kNT  = 300000;
constexpr int kR   = 64;
constexpr int kRP  = 16;
constexpr int kE   = 32;
constexpr int kC   = 32;
constexpr int kLW  = 64;
constexpr int kNRP = kN * kRP;   // 800000

// ---------- dtype-flexible load ----------
DEV_INLINE float ldf(const void* p, long long i, int isbf) {
  if (isbf) return __bfloat162float(((const __hip_bfloat16*)p)[i]);
  return ((const float*)p)[i];
}

DEV_INLINE float wave_sum(float v) {
#pragma unroll
  for (int off = 32; off > 0; off >>= 1) v += __shfl_down(v, off, 64);
  return v;
}

// ---------- dtype detection (weights1 ~ N(0,0.05): bf16 values stay in [-1,1]) ----------
__global__ void k_detect(const void* __restrict__ w1, int* __restrict__ flag) {
  __shared__ int bad;
  if (threadIdx.x == 0) bad = 0;
  __syncthreads();
  const __hip_bfloat16* b = (const __hip_bfloat16*)w1;
  for (int i = threadIdx.x; i < 1024; i += blockDim.x) {
    float v = __bfloat162float(b[i]);
    if (!(v <= 1.0f && v >= -1.0f)) atomicOr(&bad, 1);
  }
  __syncthreads();
  if (threadIdx.x == 0) flag[0] = bad ? 0 : 1;   // 1 = bf16 tensors
}

// ---------- MLP weights -> LDS ----------
DEV_INLINE void load_w_lds(const void* Wa, const void* ba, const void* Wb, const void* bb,
                           int isbf, float* swa, float* sba, float* swb, float* sbb) {
  const int tid = threadIdx.x;
  for (int i = tid; i < kR * kLW; i += 256) swa[i] = ldf(Wa, i, isbf);
  for (int i = tid; i < kLW * kRP; i += 256) swb[i] = ldf(Wb, i, isbf);
  if (tid < kLW) sba[tid] = ldf(ba, tid, isbf);
  else if (tid < kLW + kRP) sbb[tid - kLW] = ldf(bb, tid - kLW, isbf);
  __syncthreads();
}

// ---------- per-edge MLP + softmax ----------
DEV_INLINE void compute_lat16(const void* nhots, long long t, int isbf,
                              const float* swa, const float* sba,
                              const float* swb, const float* sbb, float lat[kRP]) {
  float x[kR];
  if (isbf) {
    const __hip_bfloat16* q = (const __hip_bfloat16*)nhots + t * kR;
#pragma unroll
    for (int j = 0; j < kR; j++) x[j] = __bfloat162float(q[j]);
  } else {
    const float* q = (const float*)nhots + t * kR;
#pragma unroll
    for (int j = 0; j < kR; j++) x[j] = q[j];
  }
  float hid[kLW];
#pragma unroll 4
  for (int j = 0; j < kLW; j++) {
    float a = sba[j];
#pragma unroll
    for (int l = 0; l < kR; l++) a = fmaf(x[l], swa[l * kLW + j], a);
    hid[j] = fmaxf(a, 0.f);
  }
#pragma unroll 4
  for (int p = 0; p < kRP; p++) {
    float a = sbb[p];
#pragma unroll
    for (int l = 0; l < kLW; l++) a = fmaf(hid[l], swb[l * kRP + p], a);
    lat[p] = a;
  }
  float m = lat[0];
#pragma unroll
  for (int p = 1; p < kRP; p++) m = fmaxf(m, lat[p]);
  float s = 0.f;
#pragma unroll
  for (int p = 0; p < kRP; p++) { lat[p] = __expf(lat[p] - m); s += lat[p]; }
  const float inv = 1.f / s;
#pragma unroll
  for (int p = 0; p < kRP; p++) lat[p] *= inv;
}

// ---------- K1: MLPs -> lat1/lat2 + colsum/rowsum + degree count ----------
__global__ void __launch_bounds__(256)
k_lat(const int* __restrict__ s_idx, const int* __restrict__ o_idx,
      const void* __restrict__ nhots,
      const void* W1a, const void* b1a, const void* W1b, const void* b1b,
      const void* W2a, const void* b2a, const void* W2b, const void* b2b,
      const int* __restrict__ flag,
      float* __restrict__ lat1o, float* __restrict__ lat2o,
      float* __restrict__ colsum, float* __restrict__ rowsum,
      int* __restrict__ cnt_s) {
  __shared__ float swa[kR * kLW], swb[kLW * kRP], sba[kLW], sbb[kRP];
  const int tid = threadIdx.x;
  const int isbf = *flag;
  const long long t = (long long)blockIdx.x * 256 + tid;
  const bool valid = t < kNT;
  const long long tt = valid ? t : 0;
  const int s = s_idx[tt], o = o_idx[tt];
  float lat[kRP];

  // MLP1 -> lat1, colsum
  load_w_lds(W1a, b1a, W1b, b1b, isbf, swa, sba, swb, sbb);
  compute_lat16(nhots, tt, isbf, swa, sba, swb, sbb, lat);
  if (valid) {
#pragma unroll
    for (int p = 0; p < kRP; p++) lat1o[t * kRP + p] = lat[p];
    atomicAdd(&cnt_s[s], 1);
  }
  {
    float v0 = valid ? lat[0] : 0.f;           // k=0 -> colsum[0] hotspot: wave-reduce
    v0 = wave_sum(v0);
    if ((tid & 63) == 0) atomicAdd(&colsum[0], v0);
  }
  if (valid) {
#pragma unroll
    for (int k = 1; k < kRP; k++) atomicAdd(&colsum[o * k], lat[k]);
  }
  __syncthreads();

  // MLP2 -> lat2, rowsum
  load_w_lds(W2a, b2a, W2b, b2b, isbf, swa, sba, swb, sbb);
  compute_lat16(nhots, tt, isbf, swa, sba, swb, sbb, lat);
  if (valid) {
#pragma unroll
    for (int p = 0; p < kRP; p++) lat2o[t * kRP + p] = lat[p];
  }
  {
    float v0 = valid ? lat[0] : 0.f;
    v0 = wave_sum(v0);
    if ((tid & 63) == 0) atomicAdd(&rowsum[0], v0);
  }
  if (valid) {
#pragma unroll
    for (int k = 1; k < kRP; k++) atomicAdd(&rowsum[s * k], lat[k]);
  }
}

// ---------- K2: exclusive scan of cnt_s -> rowptr (single block) ----------
__global__ void __launch_bounds__(1024)
k_scan(const int* __restrict__ cnt, int* __restrict__ rowptr) {
  __shared__ int sdata[1024];
  __shared__ int sbase;
  if (threadIdx.x == 0) { sbase = 0; rowptr[0] = 0; }
  __syncthreads();
  for (int base = 0; base < kN; base += 1024) {
    const int i = base + threadIdx.x;
    int v = (i < kN) ? cnt[i] : 0;
    sdata[threadIdx.x] = v;
    __syncthreads();
    for (int off = 1; off < 1024; off <<= 1) {
      int tmp = (threadIdx.x >= off) ? sdata[threadIdx.x - off] : 0;
      __syncthreads();
      sdata[threadIdx.x] += tmp;
      __syncthreads();
    }
    const int incl = sdata[threadIdx.x] + sbase;
    if (i < kN) rowptr[i + 1] = incl;
    __syncthreads();
    if (threadIdx.x == 1023) sbase = incl;
    __syncthreads();
  }
}

// ---------- K3: scatter edge ids into CSR (eo = {edge, o_idx}) ----------
__global__ void __launch_bounds__(256)
k_scatter(const int* __restrict__ s_idx, const int* __restrict__ o_idx,
          const int* __restrict__ rowptr, int* __restrict__ cursor,
          int2* __restrict__ eo) {
  const int e = blockIdx.x * 256 + threadIdx.x;
  if (e < kNT) {
    const int s = s_idx[e];
    const int pos = atomicAdd(&cursor[s], 1);
    int2 v; v.x = e; v.y = o_idx[e];
    eo[rowptr[s] + pos] = v;
  }
}

// ---------- K4: normalize lat1 /= colsum[o*k], lat2 /= rowsum[s*k] in place ----------
__global__ void __launch_bounds__(256)
k_norm(const int* __restrict__ s_idx, const int* __restrict__ o_idx,
       const float* __restrict__ colsum, const float* __restrict__ rowsum,
       float* __restrict__ lat1, float* __restrict__ lat2) {
  const long long i = (long long)blockIdx.x * 256 + threadIdx.x;
  if (i < (long long)kNT * kRP) {
    const int e = (int)(i >> 4);
    const int k = (int)(i & 15);
    const int s = s_idx[e], o = o_idx[e];
    lat1[i] /= colsum[o * k];
    lat2[i] /= rowsum[s * k];
  }
}

// ---------- K5: layer-1 gather: h[s] = relu(bias1 + sum_e sum_k v1n * wt1[o*k]) ----------
__global__ void __launch_bounds__(256)
k_layer1g(const int* __restrict__ rowptr, const int2* __restrict__ eo,
          const float* __restrict__ lat1n, const void* __restrict__ wt1,
          const void* __restrict__ bias1, const int* __restrict__ flag,
          float* __restrict__ h) {
  const int isbf = *flag;
  const int tid = threadIdx.x;
  const int wave = tid >> 6, lane = tid & 63;
  const int c = lane & 31, half = lane >> 5;
  for (int s = blockIdx.x * 4 + wave; s < kN; s += gridDim.x * 4) {
    float acc = 0.f;
    const int beg = rowptr[s], end = rowptr[s + 1];
    for (int j = beg; j < end; j++) {
      const int2 E = eo[j];
      const float* lp = lat1n + (size_t)E.x * kRP + half * 8;
#pragma unroll
      for (int jj = 0; jj < 8; jj++) {
        const int k = half * 8 + jj;
        acc = fmaf(lp[jj], ldf(wt1, (long long)(E.y * k) * kE + c, isbf), acc);
      }
    }
    acc += __shfl_xor(acc, 32);
    if (half == 0) {
      const float v = acc + ldf(bias1, c, isbf);
      h[(size_t)s * kE + c] = fmaxf(v, 0.f);
    }
  }
}

// ---------- K6: dense reduction for h2 row m=0 ----------
// hrow0 = sum_all_e v2n[e,0]*h[o] + sum_{e: s=0} sum_{k>=1} v2n[e,k]*h[o]
__global__ void __launch_bounds__(256)
k_hrow0(const int* __restrict__ s_idx, const int* __restrict__ o_idx,
        const float* __restrict__ lat2n, const float* __restrict__ h,
        float* __restrict__ hrow0) {
  __shared__ float sacc[8][kE];
  const int tid = threadIdx.x;
  const int grp = tid >> 5, c = tid & 31;
  float acc = 0.f;
  for (int e = blockIdx.x * 8 + grp; e < kNT; e += gridDim.x * 8) {
    const int s = s_idx[e], o = o_idx[e];
    const float* lp = lat2n + (size_t)e * kRP;
    float w = lp[0];
    if (s == 0) {
#pragma unroll
      for (int k = 1; k < kRP; k++) w += lp[k];
    }
    acc = fmaf(w, h[(size_t)o * kE + c], acc);
  }
  sacc[grp][c] = acc;
  __syncthreads();
  if (tid < kE) {
    float a = 0.f;
#pragma unroll
    for (int g = 0; g < 8; g++) a += sacc[g][tid];
    atomicAdd(&hrow0[tid], a);
  }
}

// ---------- K7: output gather + einsum ----------
// out[n,c] = bias2[c] + sum_r W2[r,:,c] . h2row(r*N+n)
// h2row(m) = [m==0: hrow0] + sum_{k=1..15, m%k==0, s=m/k<N} sum_{e in edges(s)} lat2n[e,k]*h[o_e]
__global__ void __launch_bounds__(256)
k_out(const int* __restrict__ rowptr, const int2* __restrict__ eo,
      const float* __restrict__ lat2n, const float* __restrict__ h,
      const float* __restrict__ hrow0, const void* __restrict__ W2,
      const void* __restrict__ bias2, const int* __restrict__ flag,
      void* __restrict__ out) {
  __shared__ float sW2[kRP * kE * kC];   // 64 KB
  const int isbf = *flag;
  const int tid = threadIdx.x;
  for (int i = tid; i < kRP * kE * kC; i += 256) sW2[i] = ldf(W2, i, isbf);
  __syncthreads();
  const int wave = tid >> 6, lane = tid & 63;
  const int c = lane & 31, half = lane >> 5;
  const float b = ldf(bias2, c, isbf);
  for (int n = blockIdx.x * 4 + wave; n < kN; n += gridDim.x * 4) {
    float acc = 0.f;
#pragma unroll 1
    for (int rr = 0; rr < 8; rr++) {
      const int r = half * 8 + rr;
      const int m = r * kN + n;
      float row = (m == 0) ? hrow0[c] : 0.f;
#pragma unroll
      for (int k = 1; k < kRP; k++) {
        if (m % k == 0) {
          const int s = m / k;
          if (s < kN) {
            const int beg = rowptr[s], end = rowptr[s + 1];
            for (int j = beg; j < end; j++) {
              const int2 E = eo[j];
              row = fmaf(lat2n[(size_t)E.x * kRP + k], h[(size_t)E.y * kE + c], row);
            }
          }
        }
      }
      const float* wrow = sW2 + r * (kE * kC);
#pragma unroll
      for (int hh = 0; hh < kE; hh++) {
        const float bh = __shfl(row, hh, 32);
        acc = fmaf(bh, wrow[hh * kC + c], acc);
      }
    }
    acc += __shfl_xor(acc, 32);
    if (half == 0) {
      const float v = acc + b;
      if (isbf) ((__hip_bfloat16*)out)[(size_t)n * kC + c] = __float2bfloat16(v);
      else ((float*)out)[(size_t)n * kC + c] = v;
    }
  }
}

// ---------- host ----------
extern "C" void kernel_launch(void* const* d_in, const int* in_sizes, int n_in,
                              void* d_out, int out_size, void* d_ws, size_t ws_size,
                              hipStream_t stream) {
  (void)in_sizes; (void)n_in; (void)out_size; (void)ws_size;
  const int* s_idx = (const int*)d_in[0];
  const int* o_idx = (const int*)d_in[1];
  const void* nhots = d_in[2];
  const void* W1a = d_in[3]; const void* b1a = d_in[4];
  const void* W1b = d_in[5]; const void* b1b = d_in[6];
  const void* W2a = d_in[7]; const void* b2a = d_in[8];
  const void* W2b = d_in[9]; const void* b2b = d_in[10];
  const void* wt1 = d_in[11]; const void* wt2 = d_in[12];
  const void* bias1 = d_in[13]; const void* bias2 = d_in[14];

  char* ws = (char*)d_ws;
  size_t off = 0;
  auto alloc = [&](size_t bytes) -> char* {
    char* p = ws + off;
    off = (off + bytes + 255) & ~(size_t)255;
    return p;
  };
  int*   flag   = (int*)  alloc(4);
  char*  z0     = ws + off;                          // memset range start
  float* colsum = (float*)alloc((size_t)kNRP * 4);   // 3.2 MB
  float* rowsum = (float*)alloc((size_t)kNRP * 4);   // 3.2 MB
  int*   cnt_s  = (int*)  alloc((size_t)kN * 4);
  int*   cursor = (int*)  alloc((size_t)kN * 4);
  float* hrow0  = (float*)alloc((size_t)kE * 4);
  const size_t zbytes = (size_t)((ws + off) - z0);   // ~6.8 MB
  int*   rowptr = (int*)  alloc((size_t)(kN + 1) * 4);
  float* lat1   = (float*)alloc((size_t)kNT * kRP * 4);  // 19.2 MB
  float* lat2   = (float*)alloc((size_t)kNT * kRP * 4);  // 19.2 MB
  int2*  eo     = (int2*) alloc((size_t)kNT * 8);        // 2.4 MB
  float* hbuf   = (float*)alloc((size_t)kN * kE * 4);    // 6.4 MB
  // total ~54.5 MB (round-1 proved ws >= ~112 MB via the use_h2 path)

  hipMemsetAsync(z0, 0, zbytes, stream);
  k_detect<<<1, 256, 0, stream>>>(wt1, flag);

  const dim3 blk(256);
  const int gEdges = (kNT + 255) / 256;

  k_lat<<<gEdges, blk, 0, stream>>>(s_idx, o_idx, nhots, W1a, b1a, W1b, b1b,
                                    W2a, b2a, W2b, b2b, flag,
                                    lat1, lat2, colsum, rowsum, cnt_s);
  k_scan<<<1, 1024, 0, stream>>>(cnt_s, rowptr);
  k_scatter<<<gEdges, blk, 0, stream>>>(s_idx, o_idx, rowptr, cursor, eo);
  k_norm<<<(kNT * kRP + 255) / 256, blk, 0, stream>>>(s_idx, o_idx, colsum, rowsum, lat1, lat2);
  k_layer1g<<<6400, blk, 0, stream>>>(rowptr, eo, lat1, wt1, bias1, flag, hbuf);
  k_hrow0<<<512, blk, 0, stream>>>(s_idx, o_idx, lat2, hbuf, hrow0);
  k_out<<<6400, blk, 0, stream>>>(rowptr, eo, lat2, hbuf, hrow0, wt2, bias2, flag, d_out);
}

// Round 3
// 1575.052 us; speedup vs baseline: 5.8176x; 2.2797x over previous
//
#include <hip/hip_runtime.h>
#include <hip/hip_bf16.h>

#define DEV_INLINE __device__ __forceinline__

constexpr int kN   = 50000;
constexpr int kNT  = 300000;
constexpr int kR   = 64;
constexpr int kRP  = 16;
constexpr int kE   = 32;
constexpr int kC   = 32;
constexpr int kLW  = 64;
constexpr int kNRP = kN * kRP;   // 800000

// ---------- dtype-flexible load ----------
DEV_INLINE float ldf(const void* p, long long i, int isbf) {
  if (isbf) return __bfloat162float(((const __hip_bfloat16*)p)[i]);
  return ((const float*)p)[i];
}

DEV_INLINE float wave_sum(float v) {
#pragma unroll
  for (int off = 32; off > 0; off >>= 1) v += __shfl_down(v, off, 64);
  return v;
}

// ---------- dtype detection (weights1 ~ N(0,0.05): bf16 values stay in [-1,1]) ----------
__global__ void k_detect(const void* __restrict__ w1, int* __restrict__ flag) {
  __shared__ int bad;
  if (threadIdx.x == 0) bad = 0;
  __syncthreads();
  const __hip_bfloat16* b = (const __hip_bfloat16*)w1;
  for (int i = threadIdx.x; i < 1024; i += blockDim.x) {
    float v = __bfloat162float(b[i]);
    if (!(v <= 1.0f && v >= -1.0f)) atomicOr(&bad, 1);
  }
  __syncthreads();
  if (threadIdx.x == 0) flag[0] = bad ? 0 : 1;   // 1 = bf16 tensors
}

// ---------- MLP weights -> LDS ----------
DEV_INLINE void load_w_lds(const void* Wa, const void* ba, const void* Wb, const void* bb,
                           int isbf, float* swa, float* sba, float* swb, float* sbb) {
  const int tid = threadIdx.x;
  for (int i = tid; i < kR * kLW; i += 256) swa[i] = ldf(Wa, i, isbf);
  for (int i = tid; i < kLW * kRP; i += 256) swb[i] = ldf(Wb, i, isbf);
  if (tid < kLW) sba[tid] = ldf(ba, tid, isbf);
  else if (tid < kLW + kRP) sbb[tid - kLW] = ldf(bb, tid - kLW, isbf);
  __syncthreads();
}

// ---------- per-edge MLP + softmax (float4 LDS reads) ----------
DEV_INLINE void compute_lat16(const void* nhots, long long t, int isbf,
                              const float* swa, const float* sba,
                              const float* swb, const float* sbb, float lat[kRP]) {
  float x[kR];
  if (isbf) {
    const uint4* q = (const uint4*)((const __hip_bfloat16*)nhots + t * kR);
#pragma unroll
    for (int v = 0; v < 8; v++) {               // 8 * 16B = 128B
      uint4 u = q[v];
      const unsigned w[4] = {u.x, u.y, u.z, u.w};
#pragma unroll
      for (int p = 0; p < 4; p++) {
        union { unsigned uu; float ff; } lo, hi;
        lo.uu = w[p] << 16; hi.uu = w[p] & 0xffff0000u;
        x[v * 8 + p * 2 + 0] = lo.ff;
        x[v * 8 + p * 2 + 1] = hi.ff;
      }
    }
  } else {
    const float4* q = (const float4*)((const float*)nhots + t * kR);
#pragma unroll
    for (int v = 0; v < 16; v++) {
      float4 u = q[v];
      x[v * 4 + 0] = u.x; x[v * 4 + 1] = u.y; x[v * 4 + 2] = u.z; x[v * 4 + 3] = u.w;
    }
  }
  float hid[kLW];
  const float4* swa4 = (const float4*)swa;      // row l: 16 float4 (j-contig)
  const float4* sba4 = (const float4*)sba;
#pragma unroll 2
  for (int jt = 0; jt < kLW / 4; jt++) {
    float4 a = sba4[jt];
#pragma unroll
    for (int l = 0; l < kR; l++) {
      float4 w = swa4[l * (kLW / 4) + jt];
      a.x = fmaf(x[l], w.x, a.x); a.y = fmaf(x[l], w.y, a.y);
      a.z = fmaf(x[l], w.z, a.z); a.w = fmaf(x[l], w.w, a.w);
    }
    hid[jt * 4 + 0] = fmaxf(a.x, 0.f); hid[jt * 4 + 1] = fmaxf(a.y, 0.f);
    hid[jt * 4 + 2] = fmaxf(a.z, 0.f); hid[jt * 4 + 3] = fmaxf(a.w, 0.f);
  }
  const float4* swb4 = (const float4*)swb;      // row l: 4 float4 (p-contig)
  const float4* sbb4 = (const float4*)sbb;
  float4 acc[4];
#pragma unroll
  for (int pt = 0; pt < 4; pt++) acc[pt] = sbb4[pt];
#pragma unroll
  for (int l = 0; l < kLW; l++) {
    const float hl = hid[l];
#pragma unroll
    for (int pt = 0; pt < 4; pt++) {
      float4 w = swb4[l * 4 + pt];
      acc[pt].x = fmaf(hl, w.x, acc[pt].x); acc[pt].y = fmaf(hl, w.y, acc[pt].y);
      acc[pt].z = fmaf(hl, w.z, acc[pt].z); acc[pt].w = fmaf(hl, w.w, acc[pt].w);
    }
  }
#pragma unroll
  for (int pt = 0; pt < 4; pt++) {
    lat[pt * 4 + 0] = acc[pt].x; lat[pt * 4 + 1] = acc[pt].y;
    lat[pt * 4 + 2] = acc[pt].z; lat[pt * 4 + 3] = acc[pt].w;
  }
  float m = lat[0];
#pragma unroll
  for (int p = 1; p < kRP; p++) m = fmaxf(m, lat[p]);
  float s = 0.f;
#pragma unroll
  for (int p = 0; p < kRP; p++) { lat[p] = __expf(lat[p] - m); s += lat[p]; }
  const float inv = 1.f / s;
#pragma unroll
  for (int p = 0; p < kRP; p++) lat[p] *= inv;
}

// ---------- K1: MLPs -> lat1/lat2 (raw) + colsum/rowsum + degree count ----------
__global__ void __launch_bounds__(256)
k_lat(const int* __restrict__ s_idx, const int* __restrict__ o_idx,
      const void* __restrict__ nhots,
      const void* W1a, const void* b1a, const void* W1b, const void* b1b,
      const void* W2a, const void* b2a, const void* W2b, const void* b2b,
      const int* __restrict__ flag,
      float* __restrict__ lat1o, float* __restrict__ lat2o,
      float* __restrict__ colsum, float* __restrict__ rowsum,
      int* __restrict__ cnt_s) {
  __shared__ __align__(16) float swa[kR * kLW];
  __shared__ __align__(16) float swb[kLW * kRP];
  __shared__ __align__(16) float sba[kLW];
  __shared__ __align__(16) float sbb[kRP];
  const int tid = threadIdx.x;
  const int isbf = *flag;
  const long long t = (long long)blockIdx.x * 256 + tid;
  const bool valid = t < kNT;
  const long long tt = valid ? t : 0;
  const int s = s_idx[tt], o = o_idx[tt];
  float lat[kRP];

  load_w_lds(W1a, b1a, W1b, b1b, isbf, swa, sba, swb, sbb);
  compute_lat16(nhots, tt, isbf, swa, sba, swb, sbb, lat);
  if (valid) {
    float4* lp = (float4*)(lat1o + t * kRP);
#pragma unroll
    for (int q = 0; q < 4; q++)
      lp[q] = make_float4(lat[q * 4], lat[q * 4 + 1], lat[q * 4 + 2], lat[q * 4 + 3]);
    atomicAdd(&cnt_s[s], 1);
  }
  {
    float v0 = valid ? lat[0] : 0.f;           // k=0 -> colsum[0] hotspot: wave-reduce
    v0 = wave_sum(v0);
    if ((tid & 63) == 0) atomicAdd(&colsum[0], v0);
  }
  if (valid) {
#pragma unroll
    for (int k = 1; k < kRP; k++) atomicAdd(&colsum[o * k], lat[k]);
  }
  __syncthreads();

  load_w_lds(W2a, b2a, W2b, b2b, isbf, swa, sba, swb, sbb);
  compute_lat16(nhots, tt, isbf, swa, sba, swb, sbb, lat);
  if (valid) {
    float4* lp = (float4*)(lat2o + t * kRP);
#pragma unroll
    for (int q = 0; q < 4; q++)
      lp[q] = make_float4(lat[q * 4], lat[q * 4 + 1], lat[q * 4 + 2], lat[q * 4 + 3]);
  }
  {
    float v0 = valid ? lat[0] : 0.f;
    v0 = wave_sum(v0);
    if ((tid & 63) == 0) atomicAdd(&rowsum[0], v0);
  }
  if (valid) {
#pragma unroll
    for (int k = 1; k < kRP; k++) atomicAdd(&rowsum[s * k], lat[k]);
  }
}

// ---------- K2: exclusive scan cnt_s -> rowptr (single block, shfl-based) ----------
__global__ void __launch_bounds__(1024)
k_scan(const int* __restrict__ cnt, int* __restrict__ rowptr) {
  __shared__ int wsum[16];
  __shared__ int sbase;
  const int tid = threadIdx.x;
  const int wave = tid >> 6, lane = tid & 63;
  if (tid == 0) { sbase = 0; rowptr[0] = 0; }
  __syncthreads();
  for (int base = 0; base < kN; base += 1024) {
    const int i = base + tid;
    int incl = (i < kN) ? cnt[i] : 0;
#pragma unroll
    for (int off = 1; off < 64; off <<= 1) {
      int tmp = __shfl_up(incl, off, 64);
      if (lane >= off) incl += tmp;
    }
    if (lane == 63) wsum[wave] = incl;
    __syncthreads();
    if (wave == 0 && lane < 16) {
      int w = wsum[lane];
#pragma unroll
      for (int off = 1; off < 16; off <<= 1) {
        int tmp = __shfl_up(w, off, 64);
        if (lane >= off) w += tmp;
      }
      wsum[lane] = w;    // inclusive wave sums
    }
    __syncthreads();
    incl += sbase + (wave > 0 ? wsum[wave - 1] : 0);
    if (i < kN) rowptr[i + 1] = incl;
    __syncthreads();
    if (tid == 1023) sbase = incl;
    __syncthreads();
  }
}

// ---------- K3: scatter edge ids into CSR (eo = {edge, o_idx}) ----------
__global__ void __launch_bounds__(256)
k_scatter(const int* __restrict__ s_idx, const int* __restrict__ o_idx,
          const int* __restrict__ rowptr, int* __restrict__ cursor,
          int2* __restrict__ eo) {
  const int e = blockIdx.x * 256 + threadIdx.x;
  if (e < kNT) {
    const int s = s_idx[e];
    const int pos = atomicAdd(&cursor[s], 1);
    int2 v; v.x = e; v.y = o_idx[e];
    eo[rowptr[s] + pos] = v;
  }
}

// ---------- K4: invert colsum/rowsum in place ----------
__global__ void __launch_bounds__(256)
k_rcp(float* __restrict__ colsum, float* __restrict__ rowsum) {
  const int i = blockIdx.x * 256 + threadIdx.x;
  if (i < kNRP) {
    float c = colsum[i]; colsum[i] = (c != 0.f) ? 1.f / c : 0.f;
    float r = rowsum[i]; rowsum[i] = (r != 0.f) ? 1.f / r : 0.f;
  }
}

// ---------- K5: layer-1 gather (normalization folded in) ----------
__global__ void __launch_bounds__(256)
k_layer1g(const int* __restrict__ rowptr, const int2* __restrict__ eo,
          const float* __restrict__ lat1, const float* __restrict__ csinv,
          const void* __restrict__ wt1, const void* __restrict__ bias1,
          const int* __restrict__ flag, float* __restrict__ h) {
  const int isbf = *flag;
  const int tid = threadIdx.x;
  const int wave = tid >> 6, lane = tid & 63;
  const int c = lane & 31, half = lane >> 5;
  for (int s = blockIdx.x * 4 + wave; s < kN; s += gridDim.x * 4) {
    float acc = 0.f;
    const int beg = rowptr[s], end = rowptr[s + 1];
    for (int j = beg; j < end; j++) {
      const int2 E = eo[j];
      const float4* lp = (const float4*)(lat1 + (size_t)E.x * kRP) + half * 2;
      const float4 la = lp[0], lb = lp[1];
      const float lv[8] = {la.x, la.y, la.z, la.w, lb.x, lb.y, lb.z, lb.w};
#pragma unroll
      for (int kk = 0; kk < 8; kk++) {
        const int k = half * 8 + kk;
        const int idx = E.y * k;
        const float t = lv[kk] * csinv[idx];
        acc = fmaf(t, ldf(wt1, (long long)idx * kE + c, isbf), acc);
      }
    }
    acc += __shfl_xor(acc, 32);
    if (half == 0) {
      const float v = acc + ldf(bias1, c, isbf);
      h[(size_t)s * kE + c] = fmaxf(v, 0.f);
    }
  }
}

// ---------- K6: dense k=0 reduction (raw; scaled by rowsumInv[0] in k_out2) ----------
__global__ void __launch_bounds__(256)
k_hrow0(const int* __restrict__ o_idx, const float* __restrict__ lat2,
        const float* __restrict__ h, float* __restrict__ hrow0) {
  __shared__ float sacc[8][kE];
  const int tid = threadIdx.x;
  const int grp = tid >> 5, c = tid & 31;
  float acc = 0.f;
  for (int e = blockIdx.x * 8 + grp; e < kNT; e += gridDim.x * 8) {
    acc = fmaf(lat2[(size_t)e * kRP], h[(size_t)o_idx[e] * kE + c], acc);
  }
  sacc[grp][c] = acc;
  __syncthreads();
  if (tid < kE) {
    float a = 0.f;
#pragma unroll
    for (int g = 0; g < 8; g++) a += sacc[g][tid];
    atomicAdd(&hrow0[tid], a);
  }
}

// ---------- K7: per-s walk -> U[s][k-1][c] (k=1..15), no atomics ----------
__global__ void __launch_bounds__(256)
k_u(const int* __restrict__ rowptr, const int2* __restrict__ eo,
    const float* __restrict__ lat2, const float* __restrict__ rsinv,
    const float* __restrict__ h, float* __restrict__ U) {
  const int tid = threadIdx.x;
  const int wave = tid >> 6, lane = tid & 63;
  const int c = lane & 31, half = lane >> 5;
  for (int s = blockIdx.x * 4 + wave; s < kN; s += gridDim.x * 4) {
    float u[8];
#pragma unroll
    for (int kk = 0; kk < 8; kk++) u[kk] = 0.f;
    const int beg = rowptr[s], end = rowptr[s + 1];
    for (int j = beg; j < end; j++) {
      const int2 E = eo[j];
      const float hv = h[(size_t)E.y * kE + c];
      const float4* lp = (const float4*)(lat2 + (size_t)E.x * kRP) + half * 2;
      const float4 la = lp[0], lb = lp[1];
      const float lv[8] = {la.x, la.y, la.z, la.w, lb.x, lb.y, lb.z, lb.w};
#pragma unroll
      for (int kk = 0; kk < 8; kk++) u[kk] = fmaf(lv[kk], hv, u[kk]);
    }
#pragma unroll
    for (int kk = 0; kk < 8; kk++) {
      const int k = half * 8 + kk;
      if (k >= 1) {   // half0 kk=0 is k=0 (handled by k_hrow0)
        const float sc = rsinv[s * k];
        U[((size_t)s * 15 + (k - 1)) * kE + c] = u[kk] * sc;
      }
    }
  }
}

// ---------- K8: out[n,c] = bias2 + sum_r W2[r]^T . (gathered U rows) ----------
__global__ void __launch_bounds__(256)
k_out2(const float* __restrict__ U, const float* __restrict__ hrow0,
       const float* __restrict__ rsinv, const void* __restrict__ W2,
       const void* __restrict__ bias2, const int* __restrict__ flag,
       void* __restrict__ out) {
  __shared__ float sW2[kRP * kE * kC];   // 64 KB
  const int isbf = *flag;
  const int tid = threadIdx.x;
  for (int i = tid; i < kRP * kE * kC; i += 256) sW2[i] = ldf(W2, i, isbf);
  __syncthreads();
  const int wave = tid >> 6, lane = tid & 63;
  const int c = lane & 31, half = lane >> 5;
  const float b = ldf(bias2, c, isbf);
  const float rs0 = rsinv[0];
  for (int n = blockIdx.x * 4 + wave; n < kN; n += gridDim.x * 4) {
    float acc = 0.f;
#pragma unroll 1
    for (int rr = 0; rr < 8; rr++) {
      const int r = half * 8 + rr;
      const int m = r * kN + n;
      float row = (m == 0) ? hrow0[c] * rs0 : 0.f;
#pragma unroll
      for (int k = 1; k < kRP; k++) {
        if (m % k == 0) {
          const int s = m / k;
          if (s < kN) row += U[((size_t)s * 15 + (k - 1)) * kE + c];
        }
      }
      const unsigned hb = (unsigned)(__ballot(row != 0.f) >> (half << 5));
      if (hb) {   // half-uniform branch
        const float* wrow = sW2 + r * (kE * kC);
#pragma unroll
        for (int hh = 0; hh < kE; hh++) {
          const float bh = __shfl(row, hh, 32);
          acc = fmaf(bh, wrow[hh * kC + c], acc);
        }
      }
    }
    acc += __shfl_xor(acc, 32);
    if (half == 0) {
      const float v = acc + b;
      if (isbf) ((__hip_bfloat16*)out)[(size_t)n * kC + c] = __float2bfloat16(v);
      else ((float*)out)[(size_t)n * kC + c] = v;
    }
  }
}

// ---------- host ----------
extern "C" void kernel_launch(void* const* d_in, const int* in_sizes, int n_in,
                              void* d_out, int out_size, void* d_ws, size_t ws_size,
                              hipStream_t stream) {
  (void)in_sizes; (void)n_in; (void)out_size; (void)ws_size;
  const int* s_idx = (const int*)d_in[0];
  const int* o_idx = (const int*)d_in[1];
  const void* nhots = d_in[2];
  const void* W1a = d_in[3]; const void* b1a = d_in[4];
  const void* W1b = d_in[5]; const void* b1b = d_in[6];
  const void* W2a = d_in[7]; const void* b2a = d_in[8];
  const void* W2b = d_in[9]; const void* b2b = d_in[10];
  const void* wt1 = d_in[11]; const void* wt2 = d_in[12];
  const void* bias1 = d_in[13]; const void* bias2 = d_in[14];

  char* ws = (char*)d_ws;
  size_t off = 0;
  auto alloc = [&](size_t bytes) -> char* {
    char* p = ws + off;
    off = (off + bytes + 255) & ~(size_t)255;
    return p;
  };
  int*   flag   = (int*)  alloc(4);
  char*  z0     = ws + off;                              // memset range start
  float* colsum = (float*)alloc((size_t)kNRP * 4);       // 3.2 MB
  float* rowsum = (float*)alloc((size_t)kNRP * 4);       // 3.2 MB
  int*   cnt_s  = (int*)  alloc((size_t)kN * 4);
  int*   cursor = (int*)  alloc((size_t)kN * 4);
  float* hrow0  = (float*)alloc((size_t)kE * 4);
  const size_t zbytes = (size_t)((ws + off) - z0);       // ~6.8 MB
  int*   rowptr = (int*)  alloc((size_t)(kN + 1) * 4);
  float* lat1   = (float*)alloc((size_t)kNT * kRP * 4);  // 19.2 MB
  float* lat2   = (float*)alloc((size_t)kNT * kRP * 4);  // 19.2 MB
  int2*  eo     = (int2*) alloc((size_t)kNT * 8);        // 2.4 MB
  float* hbuf   = (float*)alloc((size_t)kN * kE * 4);    // 6.4 MB
  float* U      = (float*)alloc((size_t)kN * 15 * kE * 4); // 96 MB (fully overwritten)
  // total ~150.6 MB; round-1 USE_LAT path (VGPR=44) proved ws >= 153.6 MB

  hipMemsetAsync(z0, 0, zbytes, stream);
  k_detect<<<1, 256, 0, stream>>>(wt1, flag);

  const dim3 blk(256);
  const int gEdges = (kNT + 255) / 256;

  k_lat<<<gEdges, blk, 0, stream>>>(s_idx, o_idx, nhots, W1a, b1a, W1b, b1b,
                                    W2a, b2a, W2b, b2b, flag,
                                    lat1, lat2, colsum, rowsum, cnt_s);
  k_scan<<<1, 1024, 0, stream>>>(cnt_s, rowptr);
  k_scatter<<<gEdges, blk, 0, stream>>>(s_idx, o_idx, rowptr, cursor, eo);
  k_rcp<<<(kNRP + 255) / 256, blk, 0, stream>>>(colsum, rowsum);
  k_layer1g<<<12500, blk, 0, stream>>>(rowptr, eo, lat1, colsum, wt1, bias1, flag, hbuf);
  k_hrow0<<<512, blk, 0, stream>>>(o_idx, lat2, hbuf, hrow0);
  k_u<<<12500, blk, 0, stream>>>(rowptr, eo, lat2, rowsum, hbuf, U);
  k_out2<<<1600, blk, 0, stream>>>(U, hrow0, rowsum, wt2, bias2, flag, d_out);
}

// Round 4
// 1393.836 us; speedup vs baseline: 6.5740x; 1.1300x over previous
//
#include <hip/hip_runtime.h>
#include <hip/hip_bf16.h>

#define DEV_INLINE __device__ __forceinline__

constexpr int kN   = 50000;
constexpr int kNT  = 300000;
constexpr int kR   = 64;
constexpr int kRP  = 16;
constexpr int kE   = 32;
constexpr int kC   = 32;
constexpr int kLW  = 64;
constexpr int kNRP = kN * kRP;   // 800000

typedef __attribute__((ext_vector_type(8))) short s8v;    // 8 bf16 (4 VGPRs)
typedef __attribute__((ext_vector_type(4))) float f32x4;  // MFMA acc

// ---------- dtype-flexible load ----------
DEV_INLINE float ldf(const void* p, long long i, int isbf) {
  if (isbf) return __bfloat162float(((const __hip_bfloat16*)p)[i]);
  return ((const float*)p)[i];
}

DEV_INLINE short f2bf(float f) {   // fp32 -> bf16 bits, RNE
  union { float f; unsigned u; } v; v.f = f;
  unsigned r = (v.u + 0x7fffu + ((v.u >> 16) & 1u)) >> 16;
  return (short)r;
}

// ---------- dtype detection (weights1 ~ N(0,0.05): bf16 values stay in [-1,1]) ----------
__global__ void k_detect(const void* __restrict__ w1, int* __restrict__ flag) {
  __shared__ int bad;
  if (threadIdx.x == 0) bad = 0;
  __syncthreads();
  const __hip_bfloat16* b = (const __hip_bfloat16*)w1;
  for (int i = threadIdx.x; i < 1024; i += blockDim.x) {
    float v = __bfloat162float(b[i]);
    if (!(v <= 1.0f && v >= -1.0f)) atomicOr(&bad, 1);
  }
  __syncthreads();
  if (threadIdx.x == 0) flag[0] = bad ? 0 : 1;   // 1 = bf16 tensors
}

// ---------- K0: degree counts for both CSRs ----------
__global__ void __launch_bounds__(256)
k_count(const int* __restrict__ s_idx, const int* __restrict__ o_idx,
        int* __restrict__ cnt_s, int* __restrict__ cnt_o) {
  const int e = blockIdx.x * 256 + threadIdx.x;
  if (e < kNT) {
    atomicAdd(&cnt_s[s_idx[e]], 1);
    atomicAdd(&cnt_o[o_idx[e]], 1);
  }
}

// ---------- exclusive scan (one 1024-thread block per array) ----------
DEV_INLINE void scan_block(const int* __restrict__ cnt, int* __restrict__ rowptr) {
  __shared__ int wsum[16];
  __shared__ int sbase;
  const int tid = threadIdx.x;
  const int wave = tid >> 6, lane = tid & 63;
  if (tid == 0) { sbase = 0; rowptr[0] = 0; }
  __syncthreads();
  for (int base = 0; base < kN; base += 1024) {
    const int i = base + tid;
    int incl = (i < kN) ? cnt[i] : 0;
#pragma unroll
    for (int off = 1; off < 64; off <<= 1) {
      int tmp = __shfl_up(incl, off, 64);
      if (lane >= off) incl += tmp;
    }
    if (lane == 63) wsum[wave] = incl;
    __syncthreads();
    if (wave == 0 && lane < 16) {
      int w = wsum[lane];
#pragma unroll
      for (int off = 1; off < 16; off <<= 1) {
        int tmp = __shfl_up(w, off, 64);
        if (lane >= off) w += tmp;
      }
      wsum[lane] = w;
    }
    __syncthreads();
    incl += sbase + (wave > 0 ? wsum[wave - 1] : 0);
    if (i < kN) rowptr[i + 1] = incl;
    __syncthreads();
    if (tid == 1023) sbase = incl;
    __syncthreads();
  }
}

__global__ void __launch_bounds__(1024)
k_scan2(const int* __restrict__ cnt_s, int* __restrict__ rowptr_s,
        const int* __restrict__ cnt_o, int* __restrict__ rowptr_o) {
  if (blockIdx.x == 0) scan_block(cnt_s, rowptr_s);
  else scan_block(cnt_o, rowptr_o);
}

// ---------- scatter edge ids into both CSRs ----------
__global__ void __launch_bounds__(256)
k_scatter2(const int* __restrict__ s_idx, const int* __restrict__ o_idx,
           const int* __restrict__ rowptr_s, int* __restrict__ cursor_s,
           const int* __restrict__ rowptr_o, int* __restrict__ cursor_o,
           int2* __restrict__ eo_s, int* __restrict__ e_o) {
  const int e = blockIdx.x * 256 + threadIdx.x;
  if (e < kNT) {
    const int s = s_idx[e], o = o_idx[e];
    const int ps = atomicAdd(&cursor_s[s], 1);
    int2 v; v.x = e; v.y = o;
    eo_s[rowptr_s[s] + ps] = v;
    const int po = atomicAdd(&cursor_o[o], 1);
    e_o[rowptr_o[o] + po] = e;
  }
}

// ---------- K1 (bf16 path): MFMA edge MLPs -> lat1/lat2, no atomics ----------
// Layouts [measured m89/m91/m118]: A[m=lane&15][k=(lane>>4)*8+j],
// B[k=(lane>>4)*8+j][n=lane&15], C/D col=lane&15, row=(lane>>4)*4+reg.
__global__ void __launch_bounds__(256)
k_lat_mfma(const int* __restrict__ flag, const void* __restrict__ nhots_,
           const void* W1a, const void* b1a, const void* W1b, const void* b1b,
           const void* W2a, const void* b2a, const void* W2b, const void* b2b,
           float* __restrict__ lat1o, float* __restrict__ lat2o) {
  if (*flag != 1) return;
  __shared__ short sW[kR * kLW];        // 8 KB staging (W1a then W2a)
  __shared__ short sWb[kLW * kRP];      // 2 KB (W1b then W2b)
  __shared__ float sbias[kLW + kRP];
  __shared__ short sH[4][32][72];       // per-wave H tile, pad 72 (2-way = free)
  const int tid = threadIdx.x;
  const int wave = tid >> 6, lane = tid & 63;
  const int p = lane & 15, q = lane >> 4, q8 = (lane >> 4) * 8;

  s8v   Ba[2][4][2];   // [mlp][ntile][kstep] layer-A W frags
  s8v   Bb[2][2];      // [mlp][kstep]       layer-B W frags
  float ba[2][4], bb2[2];

#pragma unroll
  for (int mlp = 0; mlp < 2; mlp++) {
    const short* Wa = (const short*)(mlp == 0 ? W1a : W2a);
    const short* Wb = (const short*)(mlp == 0 ? W1b : W2b);
    const __hip_bfloat16* bav = (const __hip_bfloat16*)(mlp == 0 ? b1a : b2a);
    const __hip_bfloat16* bbv = (const __hip_bfloat16*)(mlp == 0 ? b1b : b2b);
    if (mlp) __syncthreads();           // protect restage
    for (int i = tid; i < kR * kLW; i += 256) sW[i] = Wa[i];
    for (int i = tid; i < kLW * kRP; i += 256) sWb[i] = Wb[i];
    if (tid < kLW) sbias[tid] = __bfloat162float(bav[tid]);
    else if (tid < kLW + kRP) sbias[tid] = __bfloat162float(bbv[tid - kLW]);
    __syncthreads();
#pragma unroll
    for (int nt = 0; nt < 4; nt++) {
#pragma unroll
      for (int ks = 0; ks < 2; ks++)
#pragma unroll
        for (int j = 0; j < 8; j++)
          Ba[mlp][nt][ks][j] = sW[(ks * 32 + q8 + j) * kLW + nt * 16 + p];
      ba[mlp][nt] = sbias[nt * 16 + p];
    }
#pragma unroll
    for (int ks = 0; ks < 2; ks++)
#pragma unroll
      for (int j = 0; j < 8; j++)
        Bb[mlp][ks][j] = sWb[(ks * 32 + q8 + j) * kRP + p];
    bb2[mlp] = sbias[kLW + p];
  }
  __syncthreads();

  const int slot = blockIdx.x * 4 + wave;          // 32-edge tile id
  if (slot >= kNT / 32) return;                    // no barriers after this
  const int eb = slot * 32;
  const short* nh = (const short*)nhots_;

#pragma unroll
  for (int mlp = 0; mlp < 2; mlp++) {
    // ---- layer A: H = relu(X @ Wa + ba), 2 M-tiles of 16 edges ----
#pragma unroll
    for (int h = 0; h < 2; h++) {
      const int mb = eb + h * 16;
      const short* arow = nh + (size_t)(mb + p) * kR;
      const s8v a0 = *(const s8v*)(arow + q8);
      const s8v a1 = *(const s8v*)(arow + 32 + q8);
      f32x4 acc[4];
#pragma unroll
      for (int nt = 0; nt < 4; nt++) {
        acc[nt] = (f32x4)0.f;
        acc[nt] = __builtin_amdgcn_mfma_f32_16x16x32_bf16(a0, Ba[mlp][nt][0], acc[nt], 0, 0, 0);
        acc[nt] = __builtin_amdgcn_mfma_f32_16x16x32_bf16(a1, Ba[mlp][nt][1], acc[nt], 0, 0, 0);
      }
#pragma unroll
      for (int nt = 0; nt < 4; nt++)
#pragma unroll
        for (int reg = 0; reg < 4; reg++) {
          const float v = fmaxf(acc[nt][reg] + ba[mlp][nt], 0.f);
          sH[wave][h * 16 + q * 4 + reg][nt * 16 + p] = f2bf(v);
        }
    }
    // ---- layer B: logits = H @ Wb + bb, softmax over p ----
#pragma unroll
    for (int h = 0; h < 2; h++) {
      const int mb = eb + h * 16;
      const short* hr = &sH[wave][h * 16 + p][0];
      const s8v hA0 = *(const s8v*)(hr + q8);
      const s8v hA1 = *(const s8v*)(hr + 32 + q8);
      f32x4 acc = (f32x4)0.f;
      acc = __builtin_amdgcn_mfma_f32_16x16x32_bf16(hA0, Bb[mlp][0], acc, 0, 0, 0);
      acc = __builtin_amdgcn_mfma_f32_16x16x32_bf16(hA1, Bb[mlp][1], acc, 0, 0, 0);
      float* outp = (mlp == 0 ? lat1o : lat2o);
#pragma unroll
      for (int reg = 0; reg < 4; reg++) {
        const float v = acc[reg] + bb2[mlp];
        float m = v;
#pragma unroll
        for (int d = 1; d < 16; d <<= 1) m = fmaxf(m, __shfl_xor(m, d));
        const float e = __expf(v - m);
        float sum = e;
#pragma unroll
        for (int d = 1; d < 16; d <<= 1) sum += __shfl_xor(sum, d);
        outp[(size_t)(mb + q * 4 + reg) * kRP + p] = e / sum;
      }
    }
  }
}

// ---------- K1 fallback (fp32 inputs): VALU MLP ----------
DEV_INLINE void load_w_lds(const void* Wa, const void* ba, const void* Wb, const void* bb,
                           int isbf, float* swa, float* sba, float* swb, float* sbb) {
  const int tid = threadIdx.x;
  for (int i = tid; i < kR * kLW; i += 256) swa[i] = ldf(Wa, i, isbf);
  for (int i = tid; i < kLW * kRP; i += 256) swb[i] = ldf(Wb, i, isbf);
  if (tid < kLW) sba[tid] = ldf(ba, tid, isbf);
  else if (tid < kLW + kRP) sbb[tid - kLW] = ldf(bb, tid - kLW, isbf);
  __syncthreads();
}

DEV_INLINE void compute_lat16(const void* nhots, long long t,
                              const float* swa, const float* sba,
                              const float* swb, const float* sbb, float lat[kRP]) {
  float x[kR];
  const float4* qv = (const float4*)((const float*)nhots + t * kR);
#pragma unroll
  for (int v = 0; v < 16; v++) {
    float4 u = qv[v];
    x[v * 4 + 0] = u.x; x[v * 4 + 1] = u.y; x[v * 4 + 2] = u.z; x[v * 4 + 3] = u.w;
  }
  float hid[kLW];
  const float4* swa4 = (const float4*)swa;
  const float4* sba4 = (const float4*)sba;
#pragma unroll 2
  for (int jt = 0; jt < kLW / 4; jt++) {
    float4 a = sba4[jt];
#pragma unroll
    for (int l = 0; l < kR; l++) {
      float4 w = swa4[l * (kLW / 4) + jt];
      a.x = fmaf(x[l], w.x, a.x); a.y = fmaf(x[l], w.y, a.y);
      a.z = fmaf(x[l], w.z, a.z); a.w = fmaf(x[l], w.w, a.w);
    }
    hid[jt * 4 + 0] = fmaxf(a.x, 0.f); hid[jt * 4 + 1] = fmaxf(a.y, 0.f);
    hid[jt * 4 + 2] = fmaxf(a.z, 0.f); hid[jt * 4 + 3] = fmaxf(a.w, 0.f);
  }
  const float4* swb4 = (const float4*)swb;
  const float4* sbb4 = (const float4*)sbb;
  float4 acc[4];
#pragma unroll
  for (int pt = 0; pt < 4; pt++) acc[pt] = sbb4[pt];
#pragma unroll
  for (int l = 0; l < kLW; l++) {
    const float hl = hid[l];
#pragma unroll
    for (int pt = 0; pt < 4; pt++) {
      float4 w = swb4[l * 4 + pt];
      acc[pt].x = fmaf(hl, w.x, acc[pt].x); acc[pt].y = fmaf(hl, w.y, acc[pt].y);
      acc[pt].z = fmaf(hl, w.z, acc[pt].z); acc[pt].w = fmaf(hl, w.w, acc[pt].w);
    }
  }
#pragma unroll
  for (int pt = 0; pt < 4; pt++) {
    lat[pt * 4 + 0] = acc[pt].x; lat[pt * 4 + 1] = acc[pt].y;
    lat[pt * 4 + 2] = acc[pt].z; lat[pt * 4 + 3] = acc[pt].w;
  }
  float m = lat[0];
#pragma unroll
  for (int pp = 1; pp < kRP; pp++) m = fmaxf(m, lat[pp]);
  float s = 0.f;
#pragma unroll
  for (int pp = 0; pp < kRP; pp++) { lat[pp] = __expf(lat[pp] - m); s += lat[pp]; }
  const float inv = 1.f / s;
#pragma unroll
  for (int pp = 0; pp < kRP; pp++) lat[pp] *= inv;
}

__global__ void __launch_bounds__(256)
k_lat_valu(const int* __restrict__ flag, const void* __restrict__ nhots,
           const void* W1a, const void* b1a, const void* W1b, const void* b1b,
           const void* W2a, const void* b2a, const void* W2b, const void* b2b,
           float* __restrict__ lat1o, float* __restrict__ lat2o) {
  if (*flag != 0) return;
  __shared__ __align__(16) float swa[kR * kLW];
  __shared__ __align__(16) float swb[kLW * kRP];
  __shared__ __align__(16) float sba[kLW];
  __shared__ __align__(16) float sbb[kRP];
  const long long t = (long long)blockIdx.x * 256 + threadIdx.x;
  const bool valid = t < kNT;
  const long long tt = valid ? t : 0;
  float lat[kRP];
  load_w_lds(W1a, b1a, W1b, b1b, 0, swa, sba, swb, sbb);
  compute_lat16(nhots, tt, swa, sba, swb, sbb, lat);
  if (valid) {
    float4* lp = (float4*)(lat1o + t * kRP);
#pragma unroll
    for (int qq = 0; qq < 4; qq++)
      lp[qq] = make_float4(lat[qq * 4], lat[qq * 4 + 1], lat[qq * 4 + 2], lat[qq * 4 + 3]);
  }
  __syncthreads();
  load_w_lds(W2a, b2a, W2b, b2b, 0, swa, sba, swb, sbb);
  compute_lat16(nhots, tt, swa, sba, swb, sbb, lat);
  if (valid) {
    float4* lp = (float4*)(lat2o + t * kRP);
#pragma unroll
    for (int qq = 0; qq < 4; qq++)
      lp[qq] = make_float4(lat[qq * 4], lat[qq * 4 + 1], lat[qq * 4 + 2], lat[qq * 4 + 3]);
  }
}

// ---------- per-node partial sums C1[o][k], R2[s][k] (CSR walks, no big atomics) ----------
__global__ void __launch_bounds__(256)
k_partials(const int* __restrict__ rowptr_s, const int2* __restrict__ eo_s,
           const int* __restrict__ rowptr_o, const int* __restrict__ e_o,
           const float* __restrict__ lat1, const float* __restrict__ lat2,
           float* __restrict__ C1, float* __restrict__ R2,
           float* __restrict__ tots) {
  __shared__ float st[2][4];
  const int tid = threadIdx.x;
  const int wave = tid >> 6, lane = tid & 63;
  const int k = lane & 15, g = lane >> 4;
  float t1 = 0.f, t2 = 0.f;
  const int nw = gridDim.x * 4;
  for (int n = blockIdx.x * 4 + wave; n < kN; n += nw) {
    {
      const int beg = rowptr_s[n], end = rowptr_s[n + 1];
      float acc = 0.f;
      for (int j = beg + g; j < end; j += 4)
        acc += lat2[(size_t)eo_s[j].x * kRP + k];
      acc += __shfl_xor(acc, 16); acc += __shfl_xor(acc, 32);
      if (g == 0) { R2[n * kRP + k] = acc; if (k == 0) t2 += acc; }
    }
    {
      const int beg = rowptr_o[n], end = rowptr_o[n + 1];
      float acc = 0.f;
      for (int j = beg + g; j < end; j += 4)
        acc += lat1[(size_t)e_o[j] * kRP + k];
      acc += __shfl_xor(acc, 16); acc += __shfl_xor(acc, 32);
      if (g == 0) { C1[n * kRP + k] = acc; if (k == 0) t1 += acc; }
    }
  }
  if (lane == 0) { st[0][wave] = t1; st[1][wave] = t2; }
  __syncthreads();
  if (tid == 0) {
    atomicAdd(&tots[0], st[0][0] + st[0][1] + st[0][2] + st[0][3]);
    atomicAdd(&tots[1], st[1][0] + st[1][1] + st[1][2] + st[1][3]);
  }
}

// ---------- csinv/rsinv via divisor enumeration ----------
__global__ void __launch_bounds__(256)
k_norms(const float* __restrict__ C1, const float* __restrict__ R2,
        const float* __restrict__ tots,
        float* __restrict__ csinv, float* __restrict__ rsinv) {
  const int m = blockIdx.x * 256 + threadIdx.x;
  if (m < kNRP) {
    float cs = (m == 0) ? tots[0] : 0.f;
    float rs = (m == 0) ? tots[1] : 0.f;
#pragma unroll
    for (int k = 1; k < kRP; k++) {
      if (m % k == 0) {
        const int q = m / k;
        if (q < kN) { cs += C1[q * kRP + k]; rs += R2[q * kRP + k]; }
      }
    }
    csinv[m] = (cs != 0.f) ? 1.f / cs : 0.f;
    rsinv[m] = (rs != 0.f) ? 1.f / rs : 0.f;
  }
}

// ---------- layer-1 gather (normalization folded in) ----------
__global__ void __launch_bounds__(256)
k_layer1g(const int* __restrict__ rowptr, const int2* __restrict__ eo,
          const float* __restrict__ lat1, const float* __restrict__ csinv,
          const void* __restrict__ wt1, const void* __restrict__ bias1,
          const int* __restrict__ flag, float* __restrict__ h) {
  const int isbf = *flag;
  const int tid = threadIdx.x;
  const int wave = tid >> 6, lane = tid & 63;
  const int c = lane & 31, half = lane >> 5;
  for (int s = blockIdx.x * 4 + wave; s < kN; s += gridDim.x * 4) {
    float acc = 0.f;
    const int beg = rowptr[s], end = rowptr[s + 1];
    for (int j = beg; j < end; j++) {
      const int2 E = eo[j];
      const float4* lp = (const float4*)(lat1 + (size_t)E.x * kRP) + half * 2;
      const float4 la = lp[0], lb = lp[1];
      const float lv[8] = {la.x, la.y, la.z, la.w, lb.x, lb.y, lb.z, lb.w};
#pragma unroll
      for (int kk = 0; kk < 8; kk++) {
        const int k = half * 8 + kk;
        const int idx = E.y * k;
        const float t = lv[kk] * csinv[idx];
        acc = fmaf(t, ldf(wt1, (long long)idx * kE + c, isbf), acc);
      }
    }
    acc += __shfl_xor(acc, 32);
    if (half == 0) {
      const float v = acc + ldf(bias1, c, isbf);
      h[(size_t)s * kE + c] = fmaxf(v, 0.f);
    }
  }
}

// ---------- dense k=0 reduction (raw; scaled by rsinv[0] in k_out2) ----------
__global__ void __launch_bounds__(256)
k_hrow0(const int* __restrict__ o_idx, const float* __restrict__ lat2,
        const float* __restrict__ h, float* __restrict__ hrow0) {
  __shared__ float sacc[8][kE];
  const int tid = threadIdx.x;
  const int grp = tid >> 5, c = tid & 31;
  float acc = 0.f;
  for (int e = blockIdx.x * 8 + grp; e < kNT; e += gridDim.x * 8)
    acc = fmaf(lat2[(size_t)e * kRP], h[(size_t)o_idx[e] * kE + c], acc);
  sacc[grp][c] = acc;
  __syncthreads();
  if (tid < kE) {
    float a = 0.f;
#pragma unroll
    for (int g = 0; g < 8; g++) a += sacc[g][tid];
    atomicAdd(&hrow0[tid], a);
  }
}

// ---------- per-s walk -> U[s][k-1][c] (k=1..15), no atomics ----------
__global__ void __launch_bounds__(256)
k_u(const int* __restrict__ rowptr, const int2* __restrict__ eo,
    const float* __restrict__ lat2, const float* __restrict__ rsinv,
    const float* __restrict__ h, float* __restrict__ U) {
  const int tid = threadIdx.x;
  const int wave = tid >> 6, lane = tid & 63;
  const int c = lane & 31, half = lane >> 5;
  for (int s = blockIdx.x * 4 + wave; s < kN; s += gridDim.x * 4) {
    float u[8];
#pragma unroll
    for (int kk = 0; kk < 8; kk++) u[kk] = 0.f;
    const int beg = rowptr[s], end = rowptr[s + 1];
    for (int j = beg; j < end; j++) {
      const int2 E = eo[j];
      const float hv = h[(size_t)E.y * kE + c];
      const float4* lp = (const float4*)(lat2 + (size_t)E.x * kRP) + half * 2;
      const float4 la = lp[0], lb = lp[1];
      const float lv[8] = {la.x, la.y, la.z, la.w, lb.x, lb.y, lb.z, lb.w};
#pragma unroll
      for (int kk = 0; kk < 8; kk++) u[kk] = fmaf(lv[kk], hv, u[kk]);
    }
#pragma unroll
    for (int kk = 0; kk < 8; kk++) {
      const int k = half * 8 + kk;
      if (k >= 1) {
        const float sc = rsinv[s * k];
        U[((size_t)s * 15 + (k - 1)) * kE + c] = u[kk] * sc;
      }
    }
  }
}

// ---------- out[n,c] = bias2 + sum_r W2[r]^T . (gathered U rows) ----------
__global__ void __launch_bounds__(256)
k_out2(const float* __restrict__ U, const float* __restrict__ hrow0,
       const float* __restrict__ rsinv, const void* __restrict__ W2,
       const void* __restrict__ bias2, const int* __restrict__ flag,
       void* __restrict__ out) {
  __shared__ float sW2[kRP * kE * kC];   // 64 KB
  const int isbf = *flag;
  const int tid = threadIdx.x;
  for (int i = tid; i < kRP * kE * kC; i += 256) sW2[i] = ldf(W2, i, isbf);
  __syncthreads();
  const int wave = tid >> 6, lane = tid & 63;
  const int c = lane & 31, half = lane >> 5;
  const float b = ldf(bias2, c, isbf);
  const float rs0 = rsinv[0];
  for (int n = blockIdx.x * 4 + wave; n < kN; n += gridDim.x * 4) {
    float acc = 0.f;
#pragma unroll 1
    for (int rr = 0; rr < 8; rr++) {
      const int r = half * 8 + rr;
      const int m = r * kN + n;
      float row = (m == 0) ? hrow0[c] * rs0 : 0.f;
#pragma unroll
      for (int k = 1; k < kRP; k++) {
        if (m % k == 0) {
          const int s = m / k;
          if (s < kN) row += U[((size_t)s * 15 + (k - 1)) * kE + c];
        }
      }
      const unsigned hb = (unsigned)(__ballot(row != 0.f) >> (half << 5));
      if (hb) {
        const float* wrow = sW2 + r * (kE * kC);
#pragma unroll
        for (int hh = 0; hh < kE; hh++) {
          const float bh = __shfl(row, hh, 32);
          acc = fmaf(bh, wrow[hh * kC + c], acc);
        }
      }
    }
    acc += __shfl_xor(acc, 32);
    if (half == 0) {
      const float v = acc + b;
      if (isbf) ((__hip_bfloat16*)out)[(size_t)n * kC + c] = __float2bfloat16(v);
      else ((float*)out)[(size_t)n * kC + c] = v;
    }
  }
}

// ---------- host ----------
extern "C" void kernel_launch(void* const* d_in, const int* in_sizes, int n_in,
                              void* d_out, int out_size, void* d_ws, size_t ws_size,
                              hipStream_t stream) {
  (void)in_sizes; (void)n_in; (void)out_size; (void)ws_size;
  const int* s_idx = (const int*)d_in[0];
  const int* o_idx = (const int*)d_in[1];
  const void* nhots = d_in[2];
  const void* W1a = d_in[3]; const void* b1a = d_in[4];
  const void* W1b = d_in[5]; const void* b1b = d_in[6];
  const void* W2a = d_in[7]; const void* b2a = d_in[8];
  const void* W2b = d_in[9]; const void* b2b = d_in[10];
  const void* wt1 = d_in[11]; const void* wt2 = d_in[12];
  const void* bias1 = d_in[13]; const void* bias2 = d_in[14];

  char* ws = (char*)d_ws;
  size_t off = 0;
  auto alloc = [&](size_t bytes) -> char* {
    char* p = ws + off;
    off = (off + bytes + 255) & ~(size_t)255;
    return p;
  };
  int*   flag     = (int*)  alloc(4);
  char*  z0       = ws + off;                              // zero region start
  int*   cnt_s    = (int*)  alloc((size_t)kN * 4);
  int*   cnt_o    = (int*)  alloc((size_t)kN * 4);
  int*   cursor_s = (int*)  alloc((size_t)kN * 4);
  int*   cursor_o = (int*)  alloc((size_t)kN * 4);
  float* tots     = (float*)alloc(8);
  float* hrow0    = (float*)alloc((size_t)kE * 4);
  const size_t zbytes = (size_t)((ws + off) - z0);         // ~0.8 MB
  int*   rowptr_s = (int*)  alloc((size_t)(kN + 1) * 4);
  int*   rowptr_o = (int*)  alloc((size_t)(kN + 1) * 4);
  float* lat2     = (float*)alloc((size_t)kNT * kRP * 4);  // 19.2 MB
  int2*  eo_s     = (int2*) alloc((size_t)kNT * 8);        // 2.4 MB
  int*   e_o      = (int*)  alloc((size_t)kNT * 4);        // 1.2 MB
  float* C1       = (float*)alloc((size_t)kNRP * 4);       // 3.2 MB
  float* R2       = (float*)alloc((size_t)kNRP * 4);       // 3.2 MB
  float* csinv    = (float*)alloc((size_t)kNRP * 4);       // 3.2 MB
  float* rsinv    = (float*)alloc((size_t)kNRP * 4);       // 3.2 MB
  float* hbuf     = (float*)alloc((size_t)kN * kE * 4);    // 6.4 MB
  float* U        = (float*)alloc((size_t)kN * 15 * kE * 4); // 96 MB
  float* lat1     = U;   // alias: lat1 dead before k_u writes U
  // total ~139 MB (< 150.6 MB proven by round 3)

  hipMemsetAsync(z0, 0, zbytes, stream);
  k_detect<<<1, 256, 0, stream>>>(wt1, flag);

  const dim3 blk(256);
  const int gEdges = (kNT + 255) / 256;

  k_count<<<gEdges, blk, 0, stream>>>(s_idx, o_idx, cnt_s, cnt_o);
  k_scan2<<<2, 1024, 0, stream>>>(cnt_s, rowptr_s, cnt_o, rowptr_o);
  k_scatter2<<<gEdges, blk, 0, stream>>>(s_idx, o_idx, rowptr_s, cursor_s,
                                         rowptr_o, cursor_o, eo_s, e_o);
  k_lat_mfma<<<(kNT / 32 + 3) / 4, blk, 0, stream>>>(flag, nhots, W1a, b1a, W1b, b1b,
                                                     W2a, b2a, W2b, b2b, lat1, lat2);
  k_lat_valu<<<gEdges, blk, 0, stream>>>(flag, nhots, W1a, b1a, W1b, b1b,
                                         W2a, b2a, W2b, b2b, lat1, lat2);
  k_partials<<<512, blk, 0, stream>>>(rowptr_s, eo_s, rowptr_o, e_o,
                                      lat1, lat2, C1, R2, tots);
  k_norms<<<(kNRP + 255) / 256, blk, 0, stream>>>(C1, R2, tots, csinv, rsinv);
  k_layer1g<<<12500, blk, 0, stream>>>(rowptr_s, eo_s, lat1, csinv, wt1, bias1, flag, hbuf);
  k_hrow0<<<512, blk, 0, stream>>>(o_idx, lat2, hbuf, hrow0);
  k_u<<<12500, blk, 0, stream>>>(rowptr_s, eo_s, lat2, rsinv, hbuf, U);
  k_out2<<<1600, blk, 0, stream>>>(U, hrow0, rsinv, wt2, bias2, flag, d_out);
}

// Round 5
// 1370.423 us; speedup vs baseline: 6.6863x; 1.0171x over previous
//
#include <hip/hip_runtime.h>
#include <hip/hip_bf16.h>

#define DEV_INLINE __device__ __forceinline__

constexpr int kN   = 50000;
constexpr int kNT  = 300000;
constexpr int kR   = 64;
constexpr int kRP  = 16;
constexpr int kE   = 32;
constexpr int kC   = 32;
constexpr int kLW  = 64;
constexpr int kNRP = kN * kRP;   // 800000

typedef __attribute__((ext_vector_type(8))) short s8v;    // 8 bf16 (4 VGPRs)
typedef __attribute__((ext_vector_type(4))) float f32x4;  // MFMA acc

// ---------- dtype-flexible load ----------
DEV_INLINE float ldf(const void* p, long long i, int isbf) {
  if (isbf) return __bfloat162float(((const __hip_bfloat16*)p)[i]);
  return ((const float*)p)[i];
}

DEV_INLINE short f2bf(float f) {   // fp32 -> bf16 bits, RNE
  union { float f; unsigned u; } v; v.f = f;
  unsigned r = (v.u + 0x7fffu + ((v.u >> 16) & 1u)) >> 16;
  return (short)r;
}
DEV_INLINE float bf2f(short s) {
  union { unsigned u; float f; } v; v.u = ((unsigned)(unsigned short)s) << 16;
  return v.f;
}

// ---------- dtype detection (weights1 ~ N(0,0.05): bf16 values stay in [-1,1]) ----------
__global__ void k_detect(const void* __restrict__ w1, int* __restrict__ flag) {
  __shared__ int bad;
  if (threadIdx.x == 0) bad = 0;
  __syncthreads();
  const __hip_bfloat16* b = (const __hip_bfloat16*)w1;
  for (int i = threadIdx.x; i < 1024; i += blockDim.x) {
    float v = __bfloat162float(b[i]);
    if (!(v <= 1.0f && v >= -1.0f)) atomicOr(&bad, 1);
  }
  __syncthreads();
  if (threadIdx.x == 0) flag[0] = bad ? 0 : 1;   // 1 = bf16 tensors
}

// ---------- K0: degree counts for both CSRs ----------
__global__ void __launch_bounds__(256)
k_count(const int* __restrict__ s_idx, const int* __restrict__ o_idx,
        int* __restrict__ cnt_s, int* __restrict__ cnt_o) {
  const int e = blockIdx.x * 256 + threadIdx.x;
  if (e < kNT) {
    atomicAdd(&cnt_s[s_idx[e]], 1);
    atomicAdd(&cnt_o[o_idx[e]], 1);
  }
}

// ---------- exclusive scan (one 1024-thread block per array) ----------
DEV_INLINE void scan_block(const int* __restrict__ cnt, int* __restrict__ rowptr) {
  __shared__ int wsum[16];
  __shared__ int sbase;
  const int tid = threadIdx.x;
  const int wave = tid >> 6, lane = tid & 63;
  if (tid == 0) { sbase = 0; rowptr[0] = 0; }
  __syncthreads();
  for (int base = 0; base < kN; base += 1024) {
    const int i = base + tid;
    int incl = (i < kN) ? cnt[i] : 0;
#pragma unroll
    for (int off = 1; off < 64; off <<= 1) {
      int tmp = __shfl_up(incl, off, 64);
      if (lane >= off) incl += tmp;
    }
    if (lane == 63) wsum[wave] = incl;
    __syncthreads();
    if (wave == 0 && lane < 16) {
      int w = wsum[lane];
#pragma unroll
      for (int off = 1; off < 16; off <<= 1) {
        int tmp = __shfl_up(w, off, 64);
        if (lane >= off) w += tmp;
      }
      wsum[lane] = w;
    }
    __syncthreads();
    incl += sbase + (wave > 0 ? wsum[wave - 1] : 0);
    if (i < kN) rowptr[i + 1] = incl;
    __syncthreads();
    if (tid == 1023) sbase = incl;
    __syncthreads();
  }
}

__global__ void __launch_bounds__(1024)
k_scan2(const int* __restrict__ cnt_s, int* __restrict__ rowptr_s,
        const int* __restrict__ cnt_o, int* __restrict__ rowptr_o) {
  if (blockIdx.x == 0) scan_block(cnt_s, rowptr_s);
  else scan_block(cnt_o, rowptr_o);
}

// ---------- scatter edge ids into both CSRs ----------
__global__ void __launch_bounds__(256)
k_scatter2(const int* __restrict__ s_idx, const int* __restrict__ o_idx,
           const int* __restrict__ rowptr_s, int* __restrict__ cursor_s,
           const int* __restrict__ rowptr_o, int* __restrict__ cursor_o,
           int2* __restrict__ eo_s, int* __restrict__ e_o) {
  const int e = blockIdx.x * 256 + threadIdx.x;
  if (e < kNT) {
    const int s = s_idx[e], o = o_idx[e];
    const int ps = atomicAdd(&cursor_s[s], 1);
    int2 v; v.x = e; v.y = o;
    eo_s[rowptr_s[s] + ps] = v;
    const int po = atomicAdd(&cursor_o[o], 1);
    e_o[rowptr_o[o] + po] = e;
  }
}

// ---------- K1 (bf16 path): MFMA edge MLPs -> lat1/lat2, no atomics ----------
// Layouts [measured m89/m91/m118]: A[m=lane&15][k=(lane>>4)*8+j],
// B[k=(lane>>4)*8+j][n=lane&15], C/D col=lane&15, row=(lane>>4)*4+reg.
__global__ void __launch_bounds__(256)
k_lat_mfma(const int* __restrict__ flag, const void* __restrict__ nhots_,
           const void* W1a, const void* b1a, const void* W1b, const void* b1b,
           const void* W2a, const void* b2a, const void* W2b, const void* b2b,
           float* __restrict__ lat1o, float* __restrict__ lat2o) {
  if (*flag != 1) return;
  __shared__ short sW[kR * kLW];        // 8 KB staging (W1a then W2a)
  __shared__ short sWb[kLW * kRP];      // 2 KB (W1b then W2b)
  __shared__ float sbias[kLW + kRP];
  __shared__ short sH[4][32][72];       // per-wave H tile, pad 72 (2-way = free)
  const int tid = threadIdx.x;
  const int wave = tid >> 6, lane = tid & 63;
  const int p = lane & 15, q = lane >> 4, q8 = (lane >> 4) * 8;

  s8v   Ba[2][4][2];   // [mlp][ntile][kstep] layer-A W frags
  s8v   Bb[2][2];      // [mlp][kstep]       layer-B W frags
  float ba[2][4], bb2[2];

#pragma unroll
  for (int mlp = 0; mlp < 2; mlp++) {
    const short* Wa = (const short*)(mlp == 0 ? W1a : W2a);
    const short* Wb = (const short*)(mlp == 0 ? W1b : W2b);
    const __hip_bfloat16* bav = (const __hip_bfloat16*)(mlp == 0 ? b1a : b2a);
    const __hip_bfloat16* bbv = (const __hip_bfloat16*)(mlp == 0 ? b1b : b2b);
    if (mlp) __syncthreads();           // protect restage
    for (int i = tid; i < kR * kLW; i += 256) sW[i] = Wa[i];
    for (int i = tid; i < kLW * kRP; i += 256) sWb[i] = Wb[i];
    if (tid < kLW) sbias[tid] = __bfloat162float(bav[tid]);
    else if (tid < kLW + kRP) sbias[tid] = __bfloat162float(bbv[tid - kLW]);
    __syncthreads();
#pragma unroll
    for (int nt = 0; nt < 4; nt++) {
#pragma unroll
      for (int ks = 0; ks < 2; ks++)
#pragma unroll
        for (int j = 0; j < 8; j++)
          Ba[mlp][nt][ks][j] = sW[(ks * 32 + q8 + j) * kLW + nt * 16 + p];
      ba[mlp][nt] = sbias[nt * 16 + p];
    }
#pragma unroll
    for (int ks = 0; ks < 2; ks++)
#pragma unroll
      for (int j = 0; j < 8; j++)
        Bb[mlp][ks][j] = sWb[(ks * 32 + q8 + j) * kRP + p];
    bb2[mlp] = sbias[kLW + p];
  }
  __syncthreads();

  const int slot = blockIdx.x * 4 + wave;          // 32-edge tile id
  if (slot >= kNT / 32) return;                    // no barriers after this
  const int eb = slot * 32;
  const short* nh = (const short*)nhots_;

#pragma unroll
  for (int mlp = 0; mlp < 2; mlp++) {
#pragma unroll
    for (int h = 0; h < 2; h++) {
      const int mb = eb + h * 16;
      const short* arow = nh + (size_t)(mb + p) * kR;
      const s8v a0 = *(const s8v*)(arow + q8);
      const s8v a1 = *(const s8v*)(arow + 32 + q8);
      f32x4 acc[4];
#pragma unroll
      for (int nt = 0; nt < 4; nt++) {
        acc[nt] = (f32x4)0.f;
        acc[nt] = __builtin_amdgcn_mfma_f32_16x16x32_bf16(a0, Ba[mlp][nt][0], acc[nt], 0, 0, 0);
        acc[nt] = __builtin_amdgcn_mfma_f32_16x16x32_bf16(a1, Ba[mlp][nt][1], acc[nt], 0, 0, 0);
      }
#pragma unroll
      for (int nt = 0; nt < 4; nt++)
#pragma unroll
        for (int reg = 0; reg < 4; reg++) {
          const float v = fmaxf(acc[nt][reg] + ba[mlp][nt], 0.f);
          sH[wave][h * 16 + q * 4 + reg][nt * 16 + p] = f2bf(v);
        }
    }
#pragma unroll
    for (int h = 0; h < 2; h++) {
      const int mb = eb + h * 16;
      const short* hr = &sH[wave][h * 16 + p][0];
      const s8v hA0 = *(const s8v*)(hr + q8);
      const s8v hA1 = *(const s8v*)(hr + 32 + q8);
      f32x4 acc = (f32x4)0.f;
      acc = __builtin_amdgcn_mfma_f32_16x16x32_bf16(hA0, Bb[mlp][0], acc, 0, 0, 0);
      acc = __builtin_amdgcn_mfma_f32_16x16x32_bf16(hA1, Bb[mlp][1], acc, 0, 0, 0);
      float* outp = (mlp == 0 ? lat1o : lat2o);
#pragma unroll
      for (int reg = 0; reg < 4; reg++) {
        const float v = acc[reg] + bb2[mlp];
        float m = v;
#pragma unroll
        for (int d = 1; d < 16; d <<= 1) m = fmaxf(m, __shfl_xor(m, d));
        const float e = __expf(v - m);
        float sum = e;
#pragma unroll
        for (int d = 1; d < 16; d <<= 1) sum += __shfl_xor(sum, d);
        outp[(size_t)(mb + q * 4 + reg) * kRP + p] = e / sum;
      }
    }
  }
}

// ---------- K1 fallback (fp32 inputs): VALU MLP ----------
DEV_INLINE void load_w_lds(const void* Wa, const void* ba, const void* Wb, const void* bb,
                           int isbf, float* swa, float* sba, float* swb, float* sbb) {
  const int tid = threadIdx.x;
  for (int i = tid; i < kR * kLW; i += 256) swa[i] = ldf(Wa, i, isbf);
  for (int i = tid; i < kLW * kRP; i += 256) swb[i] = ldf(Wb, i, isbf);
  if (tid < kLW) sba[tid] = ldf(ba, tid, isbf);
  else if (tid < kLW + kRP) sbb[tid - kLW] = ldf(bb, tid - kLW, isbf);
  __syncthreads();
}

DEV_INLINE void compute_lat16(const void* nhots, long long t,
                              const float* swa, const float* sba,
                              const float* swb, const float* sbb, float lat[kRP]) {
  float x[kR];
  const float4* qv = (const float4*)((const float*)nhots + t * kR);
#pragma unroll
  for (int v = 0; v < 16; v++) {
    float4 u = qv[v];
    x[v * 4 + 0] = u.x; x[v * 4 + 1] = u.y; x[v * 4 + 2] = u.z; x[v * 4 + 3] = u.w;
  }
  float hid[kLW];
  const float4* swa4 = (const float4*)swa;
  const float4* sba4 = (const float4*)sba;
#pragma unroll 2
  for (int jt = 0; jt < kLW / 4; jt++) {
    float4 a = sba4[jt];
#pragma unroll
    for (int l = 0; l < kR; l++) {
      float4 w = swa4[l * (kLW / 4) + jt];
      a.x = fmaf(x[l], w.x, a.x); a.y = fmaf(x[l], w.y, a.y);
      a.z = fmaf(x[l], w.z, a.z); a.w = fmaf(x[l], w.w, a.w);
    }
    hid[jt * 4 + 0] = fmaxf(a.x, 0.f); hid[jt * 4 + 1] = fmaxf(a.y, 0.f);
    hid[jt * 4 + 2] = fmaxf(a.z, 0.f); hid[jt * 4 + 3] = fmaxf(a.w, 0.f);
  }
  const float4* swb4 = (const float4*)swb;
  const float4* sbb4 = (const float4*)sbb;
  float4 acc[4];
#pragma unroll
  for (int pt = 0; pt < 4; pt++) acc[pt] = sbb4[pt];
#pragma unroll
  for (int l = 0; l < kLW; l++) {
    const float hl = hid[l];
#pragma unroll
    for (int pt = 0; pt < 4; pt++) {
      float4 w = swb4[l * 4 + pt];
      acc[pt].x = fmaf(hl, w.x, acc[pt].x); acc[pt].y = fmaf(hl, w.y, acc[pt].y);
      acc[pt].z = fmaf(hl, w.z, acc[pt].z); acc[pt].w = fmaf(hl, w.w, acc[pt].w);
    }
  }
#pragma unroll
  for (int pt = 0; pt < 4; pt++) {
    lat[pt * 4 + 0] = acc[pt].x; lat[pt * 4 + 1] = acc[pt].y;
    lat[pt * 4 + 2] = acc[pt].z; lat[pt * 4 + 3] = acc[pt].w;
  }
  float m = lat[0];
#pragma unroll
  for (int pp = 1; pp < kRP; pp++) m = fmaxf(m, lat[pp]);
  float s = 0.f;
#pragma unroll
  for (int pp = 0; pp < kRP; pp++) { lat[pp] = __expf(lat[pp] - m); s += lat[pp]; }
  const float inv = 1.f / s;
#pragma unroll
  for (int pp = 0; pp < kRP; pp++) lat[pp] *= inv;
}

__global__ void __launch_bounds__(256)
k_lat_valu(const int* __restrict__ flag, const void* __restrict__ nhots,
           const void* W1a, const void* b1a, const void* W1b, const void* b1b,
           const void* W2a, const void* b2a, const void* W2b, const void* b2b,
           float* __restrict__ lat1o, float* __restrict__ lat2o) {
  if (*flag != 0) return;
  __shared__ __align__(16) float swa[kR * kLW];
  __shared__ __align__(16) float swb[kLW * kRP];
  __shared__ __align__(16) float sba[kLW];
  __shared__ __align__(16) float sbb[kRP];
  const long long t = (long long)blockIdx.x * 256 + threadIdx.x;
  const bool valid = t < kNT;
  const long long tt = valid ? t : 0;
  float lat[kRP];
  load_w_lds(W1a, b1a, W1b, b1b, 0, swa, sba, swb, sbb);
  compute_lat16(nhots, tt, swa, sba, swb, sbb, lat);
  if (valid) {
    float4* lp = (float4*)(lat1o + t * kRP);
#pragma unroll
    for (int qq = 0; qq < 4; qq++)
      lp[qq] = make_float4(lat[qq * 4], lat[qq * 4 + 1], lat[qq * 4 + 2], lat[qq * 4 + 3]);
  }
  __syncthreads();
  load_w_lds(W2a, b2a, W2b, b2b, 0, swa, sba, swb, sbb);
  compute_lat16(nhots, tt, swa, sba, swb, sbb, lat);
  if (valid) {
    float4* lp = (float4*)(lat2o + t * kRP);
#pragma unroll
    for (int qq = 0; qq < 4; qq++)
      lp[qq] = make_float4(lat[qq * 4], lat[qq * 4 + 1], lat[qq * 4 + 2], lat[qq * 4 + 3]);
  }
}

// ---------- per-node partial sums C1[o][k], R2[s][k] ----------
__global__ void __launch_bounds__(256)
k_partials(const int* __restrict__ rowptr_s, const int2* __restrict__ eo_s,
           const int* __restrict__ rowptr_o, const int* __restrict__ e_o,
           const float* __restrict__ lat1, const float* __restrict__ lat2,
           float* __restrict__ C1, float* __restrict__ R2,
           float* __restrict__ tots) {
  __shared__ float st[2][4];
  const int tid = threadIdx.x;
  const int wave = tid >> 6, lane = tid & 63;
  const int k = lane & 15, g = lane >> 4;
  float t1 = 0.f, t2 = 0.f;
  const int nw = gridDim.x * 4;
  for (int n = blockIdx.x * 4 + wave; n < kN; n += nw) {
    {
      const int beg = rowptr_s[n], end = rowptr_s[n + 1];
      float acc = 0.f;
      for (int j = beg + g; j < end; j += 4)
        acc += lat2[(size_t)eo_s[j].x * kRP + k];
      acc += __shfl_xor(acc, 16); acc += __shfl_xor(acc, 32);
      if (g == 0) { R2[n * kRP + k] = acc; if (k == 0) t2 += acc; }
    }
    {
      const int beg = rowptr_o[n], end = rowptr_o[n + 1];
      float acc = 0.f;
      for (int j = beg + g; j < end; j += 4)
        acc += lat1[(size_t)e_o[j] * kRP + k];
      acc += __shfl_xor(acc, 16); acc += __shfl_xor(acc, 32);
      if (g == 0) { C1[n * kRP + k] = acc; if (k == 0) t1 += acc; }
    }
  }
  if (lane == 0) { st[0][wave] = t1; st[1][wave] = t2; }
  __syncthreads();
  if (tid == 0) {
    atomicAdd(&tots[0], st[0][0] + st[0][1] + st[0][2] + st[0][3]);
    atomicAdd(&tots[1], st[1][0] + st[1][1] + st[1][2] + st[1][3]);
  }
}

// ---------- csinv/rsinv via divisor enumeration ----------
__global__ void __launch_bounds__(256)
k_norms(const float* __restrict__ C1, const float* __restrict__ R2,
        const float* __restrict__ tots,
        float* __restrict__ csinv, float* __restrict__ rsinv) {
  const int m = blockIdx.x * 256 + threadIdx.x;
  if (m < kNRP) {
    float cs = (m == 0) ? tots[0] : 0.f;
    float rs = (m == 0) ? tots[1] : 0.f;
#pragma unroll
    for (int k = 1; k < kRP; k++) {
      if (m % k == 0) {
        const int q = m / k;
        if (q < kN) { cs += C1[q * kRP + k]; rs += R2[q * kRP + k]; }
      }
    }
    csinv[m] = (cs != 0.f) ? 1.f / cs : 0.f;
    rsinv[m] = (rs != 0.f) ? 1.f / rs : 0.f;
  }
}

// ---------- layer-1 gather (normalization folded in) ----------
__global__ void __launch_bounds__(256)
k_layer1g(const int* __restrict__ rowptr, const int2* __restrict__ eo,
          const float* __restrict__ lat1, const float* __restrict__ csinv,
          const void* __restrict__ wt1, const void* __restrict__ bias1,
          const int* __restrict__ flag, float* __restrict__ h) {
  const int isbf = *flag;
  const int tid = threadIdx.x;
  const int wave = tid >> 6, lane = tid & 63;
  const int c = lane & 31, half = lane >> 5;
  for (int s = blockIdx.x * 4 + wave; s < kN; s += gridDim.x * 4) {
    float acc = 0.f;
    const int beg = rowptr[s], end = rowptr[s + 1];
    for (int j = beg; j < end; j++) {
      const int2 E = eo[j];
      const float4* lp = (const float4*)(lat1 + (size_t)E.x * kRP) + half * 2;
      const float4 la = lp[0], lb = lp[1];
      const float lv[8] = {la.x, la.y, la.z, la.w, lb.x, lb.y, lb.z, lb.w};
#pragma unroll
      for (int kk = 0; kk < 8; kk++) {
        const int k = half * 8 + kk;
        const int idx = E.y * k;
        const float t = lv[kk] * csinv[idx];
        acc = fmaf(t, ldf(wt1, (long long)idx * kE + c, isbf), acc);
      }
    }
    acc += __shfl_xor(acc, 32);
    if (half == 0) {
      const float v = acc + ldf(bias1, c, isbf);
      h[(size_t)s * kE + c] = fmaxf(v, 0.f);
    }
  }
}

// ---------- dense k=0 reduction (raw; scaled by rsinv[0] downstream) ----------
__global__ void __launch_bounds__(256)
k_hrow0(const int* __restrict__ o_idx, const float* __restrict__ lat2,
        const float* __restrict__ h, float* __restrict__ hrow0) {
  __shared__ float sacc[8][kE];
  const int tid = threadIdx.x;
  const int grp = tid >> 5, c = tid & 31;
  float acc = 0.f;
  for (int e = blockIdx.x * 8 + grp; e < kNT; e += gridDim.x * 8)
    acc = fmaf(lat2[(size_t)e * kRP], h[(size_t)o_idx[e] * kE + c], acc);
  sacc[grp][c] = acc;
  __syncthreads();
  if (tid < kE) {
    float a = 0.f;
#pragma unroll
    for (int g = 0; g < 8; g++) a += sacc[g][tid];
    atomicAdd(&hrow0[tid], a);
  }
}

// ---------- per-s walk -> U[s][k-1][c] (k=1..15); bf16 store on bf16 path ----------
__global__ void __launch_bounds__(256)
k_u(const int* __restrict__ rowptr, const int2* __restrict__ eo,
    const float* __restrict__ lat2, const float* __restrict__ rsinv,
    const float* __restrict__ h, const int* __restrict__ flag,
    short* __restrict__ Ub, float* __restrict__ Uf) {
  const int isbf = *flag;
  const int tid = threadIdx.x;
  const int wave = tid >> 6, lane = tid & 63;
  const int c = lane & 31, half = lane >> 5;
  for (int s = blockIdx.x * 4 + wave; s < kN; s += gridDim.x * 4) {
    float u[8];
#pragma unroll
    for (int kk = 0; kk < 8; kk++) u[kk] = 0.f;
    const int beg = rowptr[s], end = rowptr[s + 1];
    for (int j = beg; j < end; j++) {
      const int2 E = eo[j];
      const float hv = h[(size_t)E.y * kE + c];
      const float4* lp = (const float4*)(lat2 + (size_t)E.x * kRP) + half * 2;
      const float4 la = lp[0], lb = lp[1];
      const float lv[8] = {la.x, la.y, la.z, la.w, lb.x, lb.y, lb.z, lb.w};
#pragma unroll
      for (int kk = 0; kk < 8; kk++) u[kk] = fmaf(lv[kk], hv, u[kk]);
    }
#pragma unroll
    for (int kk = 0; kk < 8; kk++) {
      const int k = half * 8 + kk;
      if (k >= 1) {
        const float v = u[kk] * rsinv[s * k];
        const size_t idx = ((size_t)s * 15 + (k - 1)) * kE + c;
        if (isbf) Ub[idx] = f2bf(v);
        else Uf[idx] = v;
      }
    }
  }
}

// ---------- bf16 path: dense H2[n][r][c] via divisor gather (thread per (m,c)) ----------
__global__ void __launch_bounds__(256)
k_h2(const short* __restrict__ Ub, const float* __restrict__ hrow0,
     const float* __restrict__ rsinv, const int* __restrict__ flag,
     short* __restrict__ H2) {
  if (*flag != 1) return;
  const int i = blockIdx.x * 256 + threadIdx.x;   // < kNRP*32 = 25.6M
  const int m = i >> 5, c = i & 31;
  float row = (m == 0) ? hrow0[c] * rsinv[0] : 0.f;
#pragma unroll
  for (int k = 1; k < kRP; k++) {
    if (m % k == 0) {
      const int s = m / k;
      if (s < kN) row += bf2f(Ub[((size_t)s * 15 + (k - 1)) * kE + c]);
    }
  }
  const int r = m / kN, n = m - r * kN;
  H2[((size_t)n * kRP + r) * kE + c] = f2bf(row);
}

// ---------- bf16 path: out = H2[N,512] @ W2[512,32] + bias2 via MFMA ----------
__global__ void __launch_bounds__(256)
k_einsum(const short* __restrict__ H2, const void* __restrict__ W2,
         const void* __restrict__ bias2, const int* __restrict__ flag,
         void* __restrict__ out) {
  if (*flag != 1) return;
  __shared__ short sBW[16 * 2 * 64 * 8];   // 32 KB, B-frag swizzled
  const int tid = threadIdx.x;
  const short* w2 = (const short*)W2;
  for (int i = tid; i < 16384; i += 256) {
    const int j = i & 7, ln = (i >> 3) & 63, nt = (i >> 9) & 1, ks = i >> 10;
    const int pp = ln & 15, qq8 = (ln >> 4) * 8;
    sBW[i] = w2[(ks * 32 + qq8 + j) * 32 + nt * 16 + pp];
  }
  __syncthreads();
  const int wave = tid >> 6, lane = tid & 63;
  const int p = lane & 15, q = lane >> 4, q8 = q * 8;
  const __hip_bfloat16* b2 = (const __hip_bfloat16*)bias2;
  const float bias[2] = {__bfloat162float(b2[p]), __bfloat162float(b2[16 + p])};
  __hip_bfloat16* op = (__hip_bfloat16*)out;
  for (int tile = blockIdx.x * 4 + wave; tile < kN / 16; tile += gridDim.x * 4) {
    const int mb = tile * 16;
    f32x4 acc0 = (f32x4)0.f, acc1 = (f32x4)0.f;
    const short* arow = H2 + (size_t)(mb + p) * 512 + q8;
#pragma unroll
    for (int ks = 0; ks < 16; ks++) {
      const s8v a  = *(const s8v*)(arow + ks * 32);
      const s8v b0 = *(const s8v*)(sBW + ((ks * 2 + 0) * 64 + lane) * 8);
      const s8v b1 = *(const s8v*)(sBW + ((ks * 2 + 1) * 64 + lane) * 8);
      acc0 = __builtin_amdgcn_mfma_f32_16x16x32_bf16(a, b0, acc0, 0, 0, 0);
      acc1 = __builtin_amdgcn_mfma_f32_16x16x32_bf16(a, b1, acc1, 0, 0, 0);
    }
#pragma unroll
    for (int reg = 0; reg < 4; reg++) {
      const int n = mb + q * 4 + reg;
      op[(size_t)n * kC + p]      = __float2bfloat16(acc0[reg] + bias[0]);
      op[(size_t)n * kC + 16 + p] = __float2bfloat16(acc1[reg] + bias[1]);
    }
  }
}

// ---------- fp32 fallback: fused gather + einsum (old k_out2) ----------
__global__ void __launch_bounds__(256)
k_out_f32(const float* __restrict__ Uf, const float* __restrict__ hrow0,
          const float* __restrict__ rsinv, const void* __restrict__ W2,
          const void* __restrict__ bias2, const int* __restrict__ flag,
          void* __restrict__ out) {
  if (*flag != 0) return;
  __shared__ float sW2[kRP * kE * kC];   // 64 KB
  const int tid = threadIdx.x;
  for (int i = tid; i < kRP * kE * kC; i += 256) sW2[i] = ldf(W2, i, 0);
  __syncthreads();
  const int wave = tid >> 6, lane = tid & 63;
  const int c = lane & 31, half = lane >> 5;
  const float b = ldf(bias2, c, 0);
  const float rs0 = rsinv[0];
  for (int n = blockIdx.x * 4 + wave; n < kN; n += gridDim.x * 4) {
    float acc = 0.f;
#pragma unroll 1
    for (int rr = 0; rr < 8; rr++) {
      const int r = half * 8 + rr;
      const int m = r * kN + n;
      float row = (m == 0) ? hrow0[c] * rs0 : 0.f;
#pragma unroll
      for (int k = 1; k < kRP; k++) {
        if (m % k == 0) {
          const int s = m / k;
          if (s < kN) row += Uf[((size_t)s * 15 + (k - 1)) * kE + c];
        }
      }
      const float* wrow = sW2 + r * (kE * kC);
#pragma unroll
      for (int hh = 0; hh < kE; hh++) {
        const float bh = __shfl(row, hh, 32);
        acc = fmaf(bh, wrow[hh * kC + c], acc);
      }
    }
    acc += __shfl_xor(acc, 32);
    if (half == 0) ((float*)out)[(size_t)n * kC + c] = acc + b;
  }
}

// ---------- host ----------
extern "C" void kernel_launch(void* const* d_in, const int* in_sizes, int n_in,
                              void* d_out, int out_size, void* d_ws, size_t ws_size,
                              hipStream_t stream) {
  (void)in_sizes; (void)n_in; (void)out_size; (void)ws_size;
  const int* s_idx = (const int*)d_in[0];
  const int* o_idx = (const int*)d_in[1];
  const void* nhots = d_in[2];
  const void* W1a = d_in[3]; const void* b1a = d_in[4];
  const void* W1b = d_in[5]; const void* b1b = d_in[6];
  const void* W2a = d_in[7]; const void* b2a = d_in[8];
  const void* W2b = d_in[9]; const void* b2b = d_in[10];
  const void* wt1 = d_in[11]; const void* wt2 = d_in[12];
  const void* bias1 = d_in[13]; const void* bias2 = d_in[14];

  char* ws = (char*)d_ws;
  size_t off = 0;
  auto alloc = [&](size_t bytes) -> char* {
    char* p = ws + off;
    off = (off + bytes + 255) & ~(size_t)255;
    return p;
  };
  int*   flag     = (int*)  alloc(4);
  char*  z0       = ws + off;                              // zero region start
  int*   cnt_s    = (int*)  alloc((size_t)kN * 4);
  int*   cnt_o    = (int*)  alloc((size_t)kN * 4);
  int*   cursor_s = (int*)  alloc((size_t)kN * 4);
  int*   cursor_o = (int*)  alloc((size_t)kN * 4);
  float* tots     = (float*)alloc(8);
  float* hrow0    = (float*)alloc((size_t)kE * 4);
  const size_t zbytes = (size_t)((ws + off) - z0);         // ~0.8 MB
  int*   rowptr_s = (int*)  alloc((size_t)(kN + 1) * 4);
  int*   rowptr_o = (int*)  alloc((size_t)(kN + 1) * 4);
  float* lat2     = (float*)alloc((size_t)kNT * kRP * 4);  // 19.2 MB
  int2*  eo_s     = (int2*) alloc((size_t)kNT * 8);        // 2.4 MB
  int*   e_o      = (int*)  alloc((size_t)kNT * 4);        // 1.2 MB
  float* C1       = (float*)alloc((size_t)kNRP * 4);       // 3.2 MB
  float* R2       = (float*)alloc((size_t)kNRP * 4);       // 3.2 MB
  float* csinv    = (float*)alloc((size_t)kNRP * 4);       // 3.2 MB
  float* rsinv    = (float*)alloc((size_t)kNRP * 4);       // 3.2 MB
  float* hbuf     = (float*)alloc((size_t)kN * kE * 4);    // 6.4 MB
  // big region: bf16 path {Ub 48MB | H2 51.2MB}; fp32 path {Uf 96MB}
  char*  bigU     = alloc((size_t)kN * 15 * kE * 2 + (size_t)kN * kRP * kE * 2); // 99.2 MB
  short* Ub       = (short*)bigU;
  short* H2       = (short*)(bigU + (size_t)kN * 15 * kE * 2);
  float* Uf       = (float*)bigU;
  float* lat1     = (float*)bigU;   // alias: lat1 dead before k_u writes U
  // total ~142.4 MB (< 150.6 MB proven by round 3)

  hipMemsetAsync(z0, 0, zbytes, stream);
  k_detect<<<1, 256, 0, stream>>>(wt1, flag);

  const dim3 blk(256);
  const int gEdges = (kNT + 255) / 256;

  k_count<<<gEdges, blk, 0, stream>>>(s_idx, o_idx, cnt_s, cnt_o);
  k_scan2<<<2, 1024, 0, stream>>>(cnt_s, rowptr_s, cnt_o, rowptr_o);
  k_scatter2<<<gEdges, blk, 0, stream>>>(s_idx, o_idx, rowptr_s, cursor_s,
                                         rowptr_o, cursor_o, eo_s, e_o);
  k_lat_mfma<<<(kNT / 32 + 3) / 4, blk, 0, stream>>>(flag, nhots, W1a, b1a, W1b, b1b,
                                                     W2a, b2a, W2b, b2b, lat1, lat2);
  k_lat_valu<<<gEdges, blk, 0, stream>>>(flag, nhots, W1a, b1a, W1b, b1b,
                                         W2a, b2a, W2b, b2b, lat1, lat2);
  k_partials<<<512, blk, 0, stream>>>(rowptr_s, eo_s, rowptr_o, e_o,
                                      lat1, lat2, C1, R2, tots);
  k_norms<<<(kNRP + 255) / 256, blk, 0, stream>>>(C1, R2, tots, csinv, rsinv);
  k_layer1g<<<12500, blk, 0, stream>>>(rowptr_s, eo_s, lat1, csinv, wt1, bias1, flag, hbuf);
  k_hrow0<<<512, blk, 0, stream>>>(o_idx, lat2, hbuf, hrow0);
  k_u<<<12500, blk, 0, stream>>>(rowptr_s, eo_s, lat2, rsinv, hbuf, flag, Ub, Uf);
  k_h2<<<(kNRP * kE) / 256, blk, 0, stream>>>(Ub, hrow0, rsinv, flag, H2);
  k_einsum<<<782, blk, 0, stream>>>(H2, wt2, bias2, flag, d_out);
  k_out_f32<<<1600, blk, 0, stream>>>(Uf, hrow0, rsinv, wt2, bias2, flag, d_out);
}

// Round 6
// 783.350 us; speedup vs baseline: 11.6973x; 1.7494x over previous
//
#include <hip/hip_runtime.h>
#include <hip/hip_bf16.h>

#define DEV_INLINE __device__ __forceinline__

constexpr int kN   = 50000;
constexpr int kNT  = 300000;
constexpr int kR   = 64;
constexpr int kRP  = 16;
constexpr int kE   = 32;
constexpr int kC   = 32;
constexpr int kLW  = 64;
constexpr int kNRP = kN * kRP;   // 800000

typedef __attribute__((ext_vector_type(8))) short s8v;    // 8 bf16 (4 VGPRs)
typedef __attribute__((ext_vector_type(4))) float f32x4;  // MFMA acc

DEV_INLINE short f2bf(float f) {   // fp32 -> bf16 bits, RNE
  union { float f; unsigned u; } v; v.f = f;
  unsigned r = (v.u + 0x7fffu + ((v.u >> 16) & 1u)) >> 16;
  return (short)r;
}
DEV_INLINE float bf2f(short s) {
  union { unsigned u; float f; } v; v.u = ((unsigned)(unsigned short)s) << 16;
  return v.f;
}

// ---------- K0: degree counts for both CSRs ----------
__global__ void __launch_bounds__(256)
k_count(const int* __restrict__ s_idx, const int* __restrict__ o_idx,
        int* __restrict__ cnt_s, int* __restrict__ cnt_o) {
  const int e = blockIdx.x * 256 + threadIdx.x;
  if (e < kNT) {
    atomicAdd(&cnt_s[s_idx[e]], 1);
    atomicAdd(&cnt_o[o_idx[e]], 1);
  }
}

// ---------- exclusive scan (one 1024-thread block per array) ----------
DEV_INLINE void scan_block(const int* __restrict__ cnt, int* __restrict__ rowptr) {
  __shared__ int wsum[16];
  __shared__ int sbase;
  const int tid = threadIdx.x;
  const int wave = tid >> 6, lane = tid & 63;
  if (tid == 0) { sbase = 0; rowptr[0] = 0; }
  __syncthreads();
  for (int base = 0; base < kN; base += 1024) {
    const int i = base + tid;
    int incl = (i < kN) ? cnt[i] : 0;
#pragma unroll
    for (int off = 1; off < 64; off <<= 1) {
      int tmp = __shfl_up(incl, off, 64);
      if (lane >= off) incl += tmp;
    }
    if (lane == 63) wsum[wave] = incl;
    __syncthreads();
    if (wave == 0 && lane < 16) {
      int w = wsum[lane];
#pragma unroll
      for (int off = 1; off < 16; off <<= 1) {
        int tmp = __shfl_up(w, off, 64);
        if (lane >= off) w += tmp;
      }
      wsum[lane] = w;
    }
    __syncthreads();
    incl += sbase + (wave > 0 ? wsum[wave - 1] : 0);
    if (i < kN) rowptr[i + 1] = incl;
    __syncthreads();
    if (tid == 1023) sbase = incl;
    __syncthreads();
  }
}

__global__ void __launch_bounds__(1024)
k_scan2(const int* __restrict__ cnt_s, int* __restrict__ rowptr_s,
        const int* __restrict__ cnt_o, int* __restrict__ rowptr_o) {
  if (blockIdx.x == 0) scan_block(cnt_s, rowptr_s);
  else scan_block(cnt_o, rowptr_o);
}

// ---------- scatter edge ids into both CSRs ----------
__global__ void __launch_bounds__(256)
k_scatter2(const int* __restrict__ s_idx, const int* __restrict__ o_idx,
           const int* __restrict__ rowptr_s, int* __restrict__ cursor_s,
           const int* __restrict__ rowptr_o, int* __restrict__ cursor_o,
           int2* __restrict__ eo_s, int* __restrict__ e_o) {
  const int e = blockIdx.x * 256 + threadIdx.x;
  if (e < kNT) {
    const int s = s_idx[e], o = o_idx[e];
    const int ps = atomicAdd(&cursor_s[s], 1);
    int2 v; v.x = e; v.y = o;
    eo_s[rowptr_s[s] + ps] = v;
    const int po = atomicAdd(&cursor_o[o], 1);
    e_o[rowptr_o[o] + po] = e;
  }
}

// ---------- K1: edge MLP + softmax via split-bf16 MFMA (fp32-accurate) ----------
// x = xh + xl (bf16 pair); x*w = xh*wh + xh*wl + xl*wh (drop xl*wl ~2^-18).
// MFMA layouts [measured m89/m91/m118]: A[m=lane&15][k=(lane>>4)*8+j],
// B[k=(lane>>4)*8+j][n=lane&15], C/D col=lane&15, row=(lane>>4)*4+reg.
__global__ void __launch_bounds__(256)
k_lat_split(const float* __restrict__ nhots, const float* __restrict__ Wa,
            const float* __restrict__ ba, const float* __restrict__ Wb,
            const float* __restrict__ bb, float* __restrict__ lato) {
  __shared__ float sWa[kR * kLW];            // 16 KB
  __shared__ float sWb[kLW * kRP];           // 4 KB
  __shared__ float sb[kLW + kRP];
  __shared__ float sHf[4][32][68];           // per-wave hidden tile, fp32, pad 68
  const int tid = threadIdx.x;
  const int wave = tid >> 6, lane = tid & 63;
  const int p = lane & 15, q = lane >> 4, q8 = (lane >> 4) * 8;

  for (int i = tid; i < kR * kLW; i += 256) sWa[i] = Wa[i];
  for (int i = tid; i < kLW * kRP; i += 256) sWb[i] = Wb[i];
  if (tid < kLW) sb[tid] = ba[tid];
  else if (tid < kLW + kRP) sb[tid] = bb[tid - kLW];
  __syncthreads();

  s8v Bh[4][2], Bl[4][2], Bbh[2], Bbl[2];
  float bav[4];
#pragma unroll
  for (int nt = 0; nt < 4; nt++) {
#pragma unroll
    for (int ks = 0; ks < 2; ks++)
#pragma unroll
      for (int j = 0; j < 8; j++) {
        const float v = sWa[(ks * 32 + q8 + j) * kLW + nt * 16 + p];
        const short h = f2bf(v);
        Bh[nt][ks][j] = h;
        Bl[nt][ks][j] = f2bf(v - bf2f(h));
      }
    bav[nt] = sb[nt * 16 + p];
  }
#pragma unroll
  for (int ks = 0; ks < 2; ks++)
#pragma unroll
    for (int j = 0; j < 8; j++) {
      const float v = sWb[(ks * 32 + q8 + j) * kRP + p];
      const short h = f2bf(v);
      Bbh[ks][j] = h;
      Bbl[ks][j] = f2bf(v - bf2f(h));
    }
  const float bbv = sb[kLW + p];

  const int slot = blockIdx.x * 4 + wave;    // 32-edge tile; no barriers below
  if (slot >= kNT / 32) return;
  const int eb = slot * 32;

  // ---- layer A: H = relu(X @ Wa + ba), two 16-edge M-tiles ----
#pragma unroll
  for (int ht = 0; ht < 2; ht++) {
    const int mb = eb + ht * 16;
    const float* arow = nhots + (size_t)(mb + p) * kR;
    s8v ah[2], al[2];
#pragma unroll
    for (int ks = 0; ks < 2; ks++) {
      const float4 xa = *(const float4*)(arow + ks * 32 + q8);
      const float4 xb = *(const float4*)(arow + ks * 32 + q8 + 4);
      const float fv[8] = {xa.x, xa.y, xa.z, xa.w, xb.x, xb.y, xb.z, xb.w};
#pragma unroll
      for (int j = 0; j < 8; j++) {
        const short h = f2bf(fv[j]);
        ah[ks][j] = h;
        al[ks][j] = f2bf(fv[j] - bf2f(h));
      }
    }
    f32x4 acc[4];
#pragma unroll
    for (int nt = 0; nt < 4; nt++) {
      acc[nt] = (f32x4)0.f;
#pragma unroll
      for (int ks = 0; ks < 2; ks++) {
        acc[nt] = __builtin_amdgcn_mfma_f32_16x16x32_bf16(ah[ks], Bh[nt][ks], acc[nt], 0, 0, 0);
        acc[nt] = __builtin_amdgcn_mfma_f32_16x16x32_bf16(ah[ks], Bl[nt][ks], acc[nt], 0, 0, 0);
        acc[nt] = __builtin_amdgcn_mfma_f32_16x16x32_bf16(al[ks], Bh[nt][ks], acc[nt], 0, 0, 0);
      }
    }
#pragma unroll
    for (int nt = 0; nt < 4; nt++)
#pragma unroll
      for (int reg = 0; reg < 4; reg++)
        sHf[wave][ht * 16 + q * 4 + reg][nt * 16 + p] = fmaxf(acc[nt][reg] + bav[nt], 0.f);
  }

  // ---- layer B: logits = H @ Wb + bb, softmax over p ----
#pragma unroll
  for (int ht = 0; ht < 2; ht++) {
    const int mb = eb + ht * 16;
    const float* hr = &sHf[wave][ht * 16 + p][0];
    s8v ah[2], al[2];
#pragma unroll
    for (int ks = 0; ks < 2; ks++) {
      const float4 xa = *(const float4*)(hr + ks * 32 + q8);
      const float4 xb = *(const float4*)(hr + ks * 32 + q8 + 4);
      const float fv[8] = {xa.x, xa.y, xa.z, xa.w, xb.x, xb.y, xb.z, xb.w};
#pragma unroll
      for (int j = 0; j < 8; j++) {
        const short h = f2bf(fv[j]);
        ah[ks][j] = h;
        al[ks][j] = f2bf(fv[j] - bf2f(h));
      }
    }
    f32x4 acc = (f32x4)0.f;
#pragma unroll
    for (int ks = 0; ks < 2; ks++) {
      acc = __builtin_amdgcn_mfma_f32_16x16x32_bf16(ah[ks], Bbh[ks], acc, 0, 0, 0);
      acc = __builtin_amdgcn_mfma_f32_16x16x32_bf16(ah[ks], Bbl[ks], acc, 0, 0, 0);
      acc = __builtin_amdgcn_mfma_f32_16x16x32_bf16(al[ks], Bbh[ks], acc, 0, 0, 0);
    }
#pragma unroll
    for (int reg = 0; reg < 4; reg++) {
      const float v = acc[reg] + bbv;
      float m = v;
#pragma unroll
      for (int d = 1; d < 16; d <<= 1) m = fmaxf(m, __shfl_xor(m, d));
      const float e = __expf(v - m);
      float sum = e;
#pragma unroll
      for (int d = 1; d < 16; d <<= 1) sum += __shfl_xor(sum, d);
      lato[(size_t)(mb + q * 4 + reg) * kRP + p] = e / sum;
    }
  }
}

// ---------- per-node partial sums C1[o][k], R2[s][k] ----------
__global__ void __launch_bounds__(256)
k_partials(const int* __restrict__ rowptr_s, const int2* __restrict__ eo_s,
           const int* __restrict__ rowptr_o, const int* __restrict__ e_o,
           const float* __restrict__ lat1, const float* __restrict__ lat2,
           float* __restrict__ C1, float* __restrict__ R2,
           float* __restrict__ tots) {
  __shared__ float st[2][4];
  const int tid = threadIdx.x;
  const int wave = tid >> 6, lane = tid & 63;
  const int k = lane & 15, g = lane >> 4;
  float t1 = 0.f, t2 = 0.f;
  const int nw = gridDim.x * 4;
  for (int n = blockIdx.x * 4 + wave; n < kN; n += nw) {
    {
      const int beg = rowptr_s[n], end = rowptr_s[n + 1];
      float acc = 0.f;
      for (int j = beg + g; j < end; j += 4)
        acc += lat2[(size_t)eo_s[j].x * kRP + k];
      acc += __shfl_xor(acc, 16); acc += __shfl_xor(acc, 32);
      if (g == 0) { R2[n * kRP + k] = acc; if (k == 0) t2 += acc; }
    }
    {
      const int beg = rowptr_o[n], end = rowptr_o[n + 1];
      float acc = 0.f;
      for (int j = beg + g; j < end; j += 4)
        acc += lat1[(size_t)e_o[j] * kRP + k];
      acc += __shfl_xor(acc, 16); acc += __shfl_xor(acc, 32);
      if (g == 0) { C1[n * kRP + k] = acc; if (k == 0) t1 += acc; }
    }
  }
  if (lane == 0) { st[0][wave] = t1; st[1][wave] = t2; }
  __syncthreads();
  if (tid == 0) {
    atomicAdd(&tots[0], st[0][0] + st[0][1] + st[0][2] + st[0][3]);
    atomicAdd(&tots[1], st[1][0] + st[1][1] + st[1][2] + st[1][3]);
  }
}

// ---------- csinv/rsinv via divisor enumeration ----------
__global__ void __launch_bounds__(256)
k_norms(const float* __restrict__ C1, const float* __restrict__ R2,
        const float* __restrict__ tots,
        float* __restrict__ csinv, float* __restrict__ rsinv) {
  const int m = blockIdx.x * 256 + threadIdx.x;
  if (m < kNRP) {
    float cs = (m == 0) ? tots[0] : 0.f;
    float rs = (m == 0) ? tots[1] : 0.f;
#pragma unroll
    for (int k = 1; k < kRP; k++) {
      if (m % k == 0) {
        const int q = m / k;
        if (q < kN) { cs += C1[q * kRP + k]; rs += R2[q * kRP + k]; }
      }
    }
    csinv[m] = (cs != 0.f) ? 1.f / cs : 0.f;
    rsinv[m] = (rs != 0.f) ? 1.f / rs : 0.f;
  }
}

// ---------- layer-1 gather (normalization folded in) ----------
__global__ void __launch_bounds__(256)
k_layer1g(const int* __restrict__ rowptr, const int2* __restrict__ eo,
          const float* __restrict__ lat1, const float* __restrict__ csinv,
          const float* __restrict__ wt1, const float* __restrict__ bias1,
          float* __restrict__ h) {
  const int tid = threadIdx.x;
  const int wave = tid >> 6, lane = tid & 63;
  const int c = lane & 31, half = lane >> 5;
  for (int s = blockIdx.x * 4 + wave; s < kN; s += gridDim.x * 4) {
    float acc = 0.f;
    const int beg = rowptr[s], end = rowptr[s + 1];
    for (int j = beg; j < end; j++) {
      const int2 E = eo[j];
      const float4* lp = (const float4*)(lat1 + (size_t)E.x * kRP) + half * 2;
      const float4 la = lp[0], lb = lp[1];
      const float lv[8] = {la.x, la.y, la.z, la.w, lb.x, lb.y, lb.z, lb.w};
#pragma unroll
      for (int kk = 0; kk < 8; kk++) {
        const int k = half * 8 + kk;
        const int idx = E.y * k;
        const float t = lv[kk] * csinv[idx];
        acc = fmaf(t, wt1[(size_t)idx * kE + c], acc);
      }
    }
    acc += __shfl_xor(acc, 32);
    if (half == 0) h[(size_t)s * kE + c] = fmaxf(acc + bias1[c], 0.f);
  }
}

// ---------- dense k=0 reduction (raw; scaled by rsinv[0] downstream) ----------
__global__ void __launch_bounds__(256)
k_hrow0(const int* __restrict__ o_idx, const float* __restrict__ lat2,
        const float* __restrict__ h, float* __restrict__ hrow0) {
  __shared__ float sacc[8][kE];
  const int tid = threadIdx.x;
  const int grp = tid >> 5, c = tid & 31;
  float acc = 0.f;
  for (int e = blockIdx.x * 8 + grp; e < kNT; e += gridDim.x * 8)
    acc = fmaf(lat2[(size_t)e * kRP], h[(size_t)o_idx[e] * kE + c], acc);
  sacc[grp][c] = acc;
  __syncthreads();
  if (tid < kE) {
    float a = 0.f;
#pragma unroll
    for (int g = 0; g < 8; g++) a += sacc[g][tid];
    atomicAdd(&hrow0[tid], a);
  }
}

// ---------- per-s walk -> U[s][k-1][c] (k=1..15), bf16, no atomics ----------
__global__ void __launch_bounds__(256)
k_u(const int* __restrict__ rowptr, const int2* __restrict__ eo,
    const float* __restrict__ lat2, const float* __restrict__ rsinv,
    const float* __restrict__ h, short* __restrict__ Ub) {
  const int tid = threadIdx.x;
  const int wave = tid >> 6, lane = tid & 63;
  const int c = lane & 31, half = lane >> 5;
  for (int s = blockIdx.x * 4 + wave; s < kN; s += gridDim.x * 4) {
    float u[8];
#pragma unroll
    for (int kk = 0; kk < 8; kk++) u[kk] = 0.f;
    const int beg = rowptr[s], end = rowptr[s + 1];
    for (int j = beg; j < end; j++) {
      const int2 E = eo[j];
      const float hv = h[(size_t)E.y * kE + c];
      const float4* lp = (const float4*)(lat2 + (size_t)E.x * kRP) + half * 2;
      const float4 la = lp[0], lb = lp[1];
      const float lv[8] = {la.x, la.y, la.z, la.w, lb.x, lb.y, lb.z, lb.w};
#pragma unroll
      for (int kk = 0; kk < 8; kk++) u[kk] = fmaf(lv[kk], hv, u[kk]);
    }
#pragma unroll
    for (int kk = 0; kk < 8; kk++) {
      const int k = half * 8 + kk;
      if (k >= 1)
        Ub[((size_t)s * 15 + (k - 1)) * kE + c] = f2bf(u[kk] * rsinv[s * k]);
    }
  }
}

// ---------- dense H2[n][r][c] (bf16) via divisor gather; contiguous writes ----------
__global__ void __launch_bounds__(256)
k_h2(const short* __restrict__ Ub, const float* __restrict__ hrow0,
     const float* __restrict__ rsinv, short* __restrict__ H2) {
  const int tid = threadIdx.x;
  const int g = tid >> 5, c = tid & 31;
  const int n = blockIdx.x * 8 + g;          // grid = kN/8 exact
  const float rs0 = rsinv[0];
#pragma unroll 1
  for (int r = 0; r < kRP; r++) {
    const int m = r * kN + n;
    float row = (m == 0) ? hrow0[c] * rs0 : 0.f;
#pragma unroll
    for (int k = 1; k < kRP; k++) {
      if (m % k == 0) {
        const int s = m / k;
        if (s < kN) row += bf2f(Ub[((size_t)s * 15 + (k - 1)) * kE + c]);
      }
    }
    H2[((size_t)n * kRP + r) * kE + c] = f2bf(row);
  }
}

// ---------- out = H2[N,512]bf16 @ W2[512,32] (split hi/lo) + bias2, fp32 out ----------
__global__ void __launch_bounds__(256)
k_einsum(const short* __restrict__ H2, const float* __restrict__ W2,
         const float* __restrict__ bias2, float* __restrict__ out) {
  __shared__ short sBWh[16 * 2 * 64 * 8];    // 32 KB
  __shared__ short sBWl[16 * 2 * 64 * 8];    // 32 KB
  const int tid = threadIdx.x;
  for (int i = tid; i < 16384; i += 256) {
    const int j = i & 7, ln = (i >> 3) & 63, nt = (i >> 9) & 1, ks = i >> 10;
    const int pp = ln & 15, qq8 = (ln >> 4) * 8;
    const float v = W2[(ks * 32 + qq8 + j) * 32 + nt * 16 + pp];
    const short h = f2bf(v);
    sBWh[i] = h;
    sBWl[i] = f2bf(v - bf2f(h));
  }
  __syncthreads();
  const int wave = tid >> 6, lane = tid & 63;
  const int p = lane & 15, q = lane >> 4, q8 = q * 8;
  const float bias0 = bias2[p], bias1v = bias2[16 + p];
  for (int tile = blockIdx.x * 4 + wave; tile < kN / 16; tile += gridDim.x * 4) {
    const int mb = tile * 16;
    f32x4 acc0 = (f32x4)0.f, acc1 = (f32x4)0.f;
    const short* arow = H2 + (size_t)(mb + p) * 512 + q8;
#pragma unroll
    for (int ks = 0; ks < 16; ks++) {
      const s8v a   = *(const s8v*)(arow + ks * 32);
      const s8v b0h = *(const s8v*)(sBWh + ((ks * 2 + 0) * 64 + lane) * 8);
      const s8v b0l = *(const s8v*)(sBWl + ((ks * 2 + 0) * 64 + lane) * 8);
      const s8v b1h = *(const s8v*)(sBWh + ((ks * 2 + 1) * 64 + lane) * 8);
      const s8v b1l = *(const s8v*)(sBWl + ((ks * 2 + 1) * 64 + lane) * 8);
      acc0 = __builtin_amdgcn_mfma_f32_16x16x32_bf16(a, b0h, acc0, 0, 0, 0);
      acc0 = __builtin_amdgcn_mfma_f32_16x16x32_bf16(a, b0l, acc0, 0, 0, 0);
      acc1 = __builtin_amdgcn_mfma_f32_16x16x32_bf16(a, b1h, acc1, 0, 0, 0);
      acc1 = __builtin_amdgcn_mfma_f32_16x16x32_bf16(a, b1l, acc1, 0, 0, 0);
    }
#pragma unroll
    for (int reg = 0; reg < 4; reg++) {
      const int n = mb + q * 4 + reg;
      out[(size_t)n * kC + p]      = acc0[reg] + bias0;
      out[(size_t)n * kC + 16 + p] = acc1[reg] + bias1v;
    }
  }
}

// ---------- host ----------
extern "C" void kernel_launch(void* const* d_in, const int* in_sizes, int n_in,
                              void* d_out, int out_size, void* d_ws, size_t ws_size,
                              hipStream_t stream) {
  (void)in_sizes; (void)n_in; (void)out_size; (void)ws_size;
  const int* s_idx = (const int*)d_in[0];
  const int* o_idx = (const int*)d_in[1];
  const float* nhots = (const float*)d_in[2];
  const float* W1a = (const float*)d_in[3]; const float* b1a = (const float*)d_in[4];
  const float* W1b = (const float*)d_in[5]; const float* b1b = (const float*)d_in[6];
  const float* W2a = (const float*)d_in[7]; const float* b2a = (const float*)d_in[8];
  const float* W2b = (const float*)d_in[9]; const float* b2b = (const float*)d_in[10];
  const float* wt1 = (const float*)d_in[11]; const float* wt2 = (const float*)d_in[12];
  const float* bias1 = (const float*)d_in[13]; const float* bias2 = (const float*)d_in[14];

  char* ws = (char*)d_ws;
  size_t off = 0;
  auto alloc = [&](size_t bytes) -> char* {
    char* p = ws + off;
    off = (off + bytes + 255) & ~(size_t)255;
    return p;
  };
  char*  z0       = ws;                                    // zero region start
  int*   cnt_s    = (int*)  alloc((size_t)kN * 4);
  int*   cnt_o    = (int*)  alloc((size_t)kN * 4);
  int*   cursor_s = (int*)  alloc((size_t)kN * 4);
  int*   cursor_o = (int*)  alloc((size_t)kN * 4);
  float* tots     = (float*)alloc(8);
  float* hrow0    = (float*)alloc((size_t)kE * 4);
  const size_t zbytes = (size_t)((ws + off) - z0);         // ~0.8 MB
  int*   rowptr_s = (int*)  alloc((size_t)(kN + 1) * 4);
  int*   rowptr_o = (int*)  alloc((size_t)(kN + 1) * 4);
  float* lat2     = (float*)alloc((size_t)kNT * kRP * 4);  // 19.2 MB
  int2*  eo_s     = (int2*) alloc((size_t)kNT * 8);        // 2.4 MB
  int*   e_o      = (int*)  alloc((size_t)kNT * 4);        // 1.2 MB
  float* C1       = (float*)alloc((size_t)kNRP * 4);       // 3.2 MB
  float* R2       = (float*)alloc((size_t)kNRP * 4);       // 3.2 MB
  float* csinv    = (float*)alloc((size_t)kNRP * 4);       // 3.2 MB
  float* rsinv    = (float*)alloc((size_t)kNRP * 4);       // 3.2 MB
  float* hbuf     = (float*)alloc((size_t)kN * kE * 4);    // 6.4 MB
  short* Ub       = (short*)alloc((size_t)kN * 15 * kE * 2);        // 48 MB
  short* H2       = (short*)alloc((size_t)kN * kRP * kE * 2);       // 51.2 MB
  float* lat1     = (float*)Ub;  // 19.2 MB alias: lat1 dead before k_u writes Ub
  // total ~142.4 MB (same footprint as round 5, which ran fine)

  hipMemsetAsync(z0, 0, zbytes, stream);

  const dim3 blk(256);
  const int gEdges = (kNT + 255) / 256;
  const int gLat = (kNT / 32 + 3) / 4;   // 9375 wave-slots, 4 waves/block

  k_count<<<gEdges, blk, 0, stream>>>(s_idx, o_idx, cnt_s, cnt_o);
  k_scan2<<<2, 1024, 0, stream>>>(cnt_s, rowptr_s, cnt_o, rowptr_o);
  k_scatter2<<<gEdges, blk, 0, stream>>>(s_idx, o_idx, rowptr_s, cursor_s,
                                         rowptr_o, cursor_o, eo_s, e_o);
  k_lat_split<<<gLat, blk, 0, stream>>>(nhots, W1a, b1a, W1b, b1b, lat1);
  k_lat_split<<<gLat, blk, 0, stream>>>(nhots, W2a, b2a, W2b, b2b, lat2);
  k_partials<<<512, blk, 0, stream>>>(rowptr_s, eo_s, rowptr_o, e_o,
                                      lat1, lat2, C1, R2, tots);
  k_norms<<<(kNRP + 255) / 256, blk, 0, stream>>>(C1, R2, tots, csinv, rsinv);
  k_layer1g<<<12500, blk, 0, stream>>>(rowptr_s, eo_s, lat1, csinv, wt1, bias1, hbuf);
  k_hrow0<<<512, blk, 0, stream>>>(o_idx, lat2, hbuf, hrow0);
  k_u<<<12500, blk, 0, stream>>>(rowptr_s, eo_s, lat2, rsinv, hbuf, Ub);
  k_h2<<<kN / 8, blk, 0, stream>>>(Ub, hrow0, rsinv, H2);
  k_einsum<<<782, blk, 0, stream>>>(H2, wt2, bias2, (float*)d_out);
}

// Round 7
// 685.623 us; speedup vs baseline: 13.3646x; 1.1425x over previous
//
#include <hip/hip_runtime.h>
#include <hip/hip_bf16.h>

#define DEV_INLINE __device__ __forceinline__

constexpr int kN   = 50000;
constexpr int kNT  = 300000;
constexpr int kR   = 64;
constexpr int kRP  = 16;
constexpr int kE   = 32;
constexpr int kC   = 32;
constexpr int kLW  = 64;
constexpr int kNRP = kN * kRP;     // 800000
constexpr int kChunks = (kN + 255) / 256;   // 196

typedef __attribute__((ext_vector_type(8))) short s8v;    // 8 bf16 (4 VGPRs)
typedef __attribute__((ext_vector_type(4))) float f32x4;  // MFMA acc

DEV_INLINE short f2bf(float f) {   // fp32 -> bf16 bits, RNE
  union { float f; unsigned u; } v; v.f = f;
  unsigned r = (v.u + 0x7fffu + ((v.u >> 16) & 1u)) >> 16;
  return (short)r;
}
DEV_INLINE float bf2f(short s) {
  union { unsigned u; float f; } v; v.u = ((unsigned)(unsigned short)s) << 16;
  return v.f;
}
DEV_INLINE float bflo(unsigned u) { union { unsigned x; float f; } a; a.x = u << 16;        return a.f; }
DEV_INLINE float bfhi(unsigned u) { union { unsigned x; float f; } a; a.x = u & 0xffff0000u; return a.f; }

// ---------- K0: degree counts for both CSRs ----------
__global__ void __launch_bounds__(256)
k_count(const int* __restrict__ s_idx, const int* __restrict__ o_idx,
        int* __restrict__ cnt_s, int* __restrict__ cnt_o) {
  const int e = blockIdx.x * 256 + threadIdx.x;
  if (e < kNT) {
    atomicAdd(&cnt_s[s_idx[e]], 1);
    atomicAdd(&cnt_o[o_idx[e]], 1);
  }
}

// ---------- parallel scan, phase 1: per-chunk inclusive scan + chunk sums ----------
__global__ void __launch_bounds__(256)
k_scan_p1(const int* __restrict__ cnt_s, const int* __restrict__ cnt_o,
          int* __restrict__ rp_s, int* __restrict__ rp_o,
          int* __restrict__ bs_s, int* __restrict__ bs_o) {
  const int b = blockIdx.x;                 // 0..2*kChunks-1
  const bool iso = b >= kChunks;
  const int chunk = iso ? b - kChunks : b;
  const int* cnt = iso ? cnt_o : cnt_s;
  int* rp = iso ? rp_o : rp_s;
  int* bs = iso ? bs_o : bs_s;
  __shared__ int ws[4];
  const int tid = threadIdx.x, wave = tid >> 6, lane = tid & 63;
  const int i = chunk * 256 + tid;
  int v = (i < kN) ? cnt[i] : 0;
  int incl = v;
#pragma unroll
  for (int off = 1; off < 64; off <<= 1) {
    int tmp = __shfl_up(incl, off, 64);
    if (lane >= off) incl += tmp;
  }
  if (lane == 63) ws[wave] = incl;
  __syncthreads();
  int add = 0;
#pragma unroll
  for (int w = 0; w < 4; w++) if (w < wave) add += ws[w];
  incl += add;
  if (i < kN) rp[i + 1] = incl;
  if (tid == 255) bs[chunk] = incl;
}

// ---------- phase 2: exclusive scan of the chunk sums (1 block) ----------
__global__ void __launch_bounds__(256)
k_scan_p2(int* __restrict__ bs_s, int* __restrict__ bs_o) {
  __shared__ int ws[4];
  const int tid = threadIdx.x, wave = tid >> 6, lane = tid & 63;
#pragma unroll 1
  for (int a = 0; a < 2; a++) {
    int* bs = a ? bs_o : bs_s;
    const int v = (tid < kChunks) ? bs[tid] : 0;
    int incl = v;
#pragma unroll
    for (int off = 1; off < 64; off <<= 1) {
      int tmp = __shfl_up(incl, off, 64);
      if (lane >= off) incl += tmp;
    }
    if (lane == 63) ws[wave] = incl;
    __syncthreads();
    int add = 0;
#pragma unroll
    for (int w = 0; w < 4; w++) if (w < wave) add += ws[w];
    incl += add;
    __syncthreads();
    if (tid < kChunks) bs[tid] = incl - v;   // exclusive
    __syncthreads();
  }
}

// ---------- phase 3: add chunk offsets ----------
__global__ void __launch_bounds__(256)
k_scan_p3(const int* __restrict__ bs_s, const int* __restrict__ bs_o,
          int* __restrict__ rp_s, int* __restrict__ rp_o) {
  const int b = blockIdx.x;
  const bool iso = b >= kChunks;
  const int chunk = iso ? b - kChunks : b;
  int* rp = iso ? rp_o : rp_s;
  const int* bs = iso ? bs_o : bs_s;
  const int i = chunk * 256 + threadIdx.x;
  if (i < kN) rp[i + 1] += bs[chunk];
  if (chunk == 0 && threadIdx.x == 0) rp[0] = 0;
}

// ---------- scatter edge ids into both CSRs ----------
__global__ void __launch_bounds__(256)
k_scatter2(const int* __restrict__ s_idx, const int* __restrict__ o_idx,
           const int* __restrict__ rowptr_s, int* __restrict__ cursor_s,
           const int* __restrict__ rowptr_o, int* __restrict__ cursor_o,
           int2* __restrict__ eo_s, int* __restrict__ e_o) {
  const int e = blockIdx.x * 256 + threadIdx.x;
  if (e < kNT) {
    const int s = s_idx[e], o = o_idx[e];
    const int ps = atomicAdd(&cursor_s[s], 1);
    int2 v; v.x = e; v.y = o;
    eo_s[rowptr_s[s] + ps] = v;
    const int po = atomicAdd(&cursor_o[o], 1);
    e_o[rowptr_o[o] + po] = e;
  }
}

// ---------- K1: BOTH edge MLPs + softmax via split-bf16 MFMA, one nhots pass ----------
// x = xh + xl; x*w = xh*wh + xh*wl + xl*wh. Layouts [m89/m91/m118]:
// A[m=lane&15][k=(lane>>4)*8+j], B[k=(lane>>4)*8+j][n=lane&15],
// C/D col=lane&15, row=(lane>>4)*4+reg.  2 tiles (64 edges) per wave.
__global__ void __launch_bounds__(256)
k_lat(const float* __restrict__ nhots,
      const float* __restrict__ W1a, const float* __restrict__ b1a,
      const float* __restrict__ W1b, const float* __restrict__ b1b,
      const float* __restrict__ W2a, const float* __restrict__ b2a,
      const float* __restrict__ W2b, const float* __restrict__ b2b,
      float* __restrict__ lat1o, float* __restrict__ lat2o) {
  __shared__ float sWa[2][kR * kLW];     // 32 KB
  __shared__ float sWb[2][kLW * kRP];    // 8 KB
  __shared__ float sb[2][kLW + kRP];
  __shared__ float sHf[4][32][68];       // 34.8 KB
  const int tid = threadIdx.x;
  const int wave = tid >> 6, lane = tid & 63;
  const int p = lane & 15, q = lane >> 4, q8 = (lane >> 4) * 8;

  for (int i = tid; i < kR * kLW; i += 256) { sWa[0][i] = W1a[i]; sWa[1][i] = W2a[i]; }
  for (int i = tid; i < kLW * kRP; i += 256) { sWb[0][i] = W1b[i]; sWb[1][i] = W2b[i]; }
  if (tid < kLW) { sb[0][tid] = b1a[tid]; sb[1][tid] = b2a[tid]; }
  else if (tid < kLW + kRP) { sb[0][tid] = b1b[tid - kLW]; sb[1][tid] = b2b[tid - kLW]; }
  __syncthreads();

  const int w2 = (blockIdx.x * 4 + wave) * 2;   // first of 2 tile slots

#pragma unroll 1
  for (int mlp = 0; mlp < 2; mlp++) {
    s8v Bh[4][2], Bl[4][2], Bbh[2], Bbl[2];
    float bav[4];
#pragma unroll
    for (int nt = 0; nt < 4; nt++) {
#pragma unroll
      for (int ks = 0; ks < 2; ks++)
#pragma unroll
        for (int j = 0; j < 8; j++) {
          const float v = sWa[mlp][(ks * 32 + q8 + j) * kLW + nt * 16 + p];
          const short h = f2bf(v);
          Bh[nt][ks][j] = h;
          Bl[nt][ks][j] = f2bf(v - bf2f(h));
        }
      bav[nt] = sb[mlp][nt * 16 + p];
    }
#pragma unroll
    for (int ks = 0; ks < 2; ks++)
#pragma unroll
      for (int j = 0; j < 8; j++) {
        const float v = sWb[mlp][(ks * 32 + q8 + j) * kRP + p];
        const short h = f2bf(v);
        Bbh[ks][j] = h;
        Bbl[ks][j] = f2bf(v - bf2f(h));
      }
    const float bbv = sb[mlp][kLW + p];
    float* lato = mlp ? lat2o : lat1o;

#pragma unroll 1
    for (int t = 0; t < 2; t++) {
      const int slot = w2 + t;
      if (slot >= kNT / 32) break;
      const int eb = slot * 32;
      // layer A
#pragma unroll
      for (int ht = 0; ht < 2; ht++) {
        const int mb = eb + ht * 16;
        const float* arow = nhots + (size_t)(mb + p) * kR;
        s8v ah[2], al[2];
#pragma unroll
        for (int ks = 0; ks < 2; ks++) {
          const float4 xa = *(const float4*)(arow + ks * 32 + q8);
          const float4 xb = *(const float4*)(arow + ks * 32 + q8 + 4);
          const float fv[8] = {xa.x, xa.y, xa.z, xa.w, xb.x, xb.y, xb.z, xb.w};
#pragma unroll
          for (int j = 0; j < 8; j++) {
            const short h = f2bf(fv[j]);
            ah[ks][j] = h;
            al[ks][j] = f2bf(fv[j] - bf2f(h));
          }
        }
        f32x4 acc[4];
#pragma unroll
        for (int nt = 0; nt < 4; nt++) {
          acc[nt] = (f32x4)0.f;
#pragma unroll
          for (int ks = 0; ks < 2; ks++) {
            acc[nt] = __builtin_amdgcn_mfma_f32_16x16x32_bf16(ah[ks], Bh[nt][ks], acc[nt], 0, 0, 0);
            acc[nt] = __builtin_amdgcn_mfma_f32_16x16x32_bf16(ah[ks], Bl[nt][ks], acc[nt], 0, 0, 0);
            acc[nt] = __builtin_amdgcn_mfma_f32_16x16x32_bf16(al[ks], Bh[nt][ks], acc[nt], 0, 0, 0);
          }
        }
#pragma unroll
        for (int nt = 0; nt < 4; nt++)
#pragma unroll
          for (int reg = 0; reg < 4; reg++)
            sHf[wave][ht * 16 + q * 4 + reg][nt * 16 + p] = fmaxf(acc[nt][reg] + bav[nt], 0.f);
      }
      // layer B + softmax
#pragma unroll
      for (int ht = 0; ht < 2; ht++) {
        const int mb = eb + ht * 16;
        const float* hr = &sHf[wave][ht * 16 + p][0];
        s8v ah[2], al[2];
#pragma unroll
        for (int ks = 0; ks < 2; ks++) {
          const float4 xa = *(const float4*)(hr + ks * 32 + q8);
          const float4 xb = *(const float4*)(hr + ks * 32 + q8 + 4);
          const float fv[8] = {xa.x, xa.y, xa.z, xa.w, xb.x, xb.y, xb.z, xb.w};
#pragma unroll
          for (int j = 0; j < 8; j++) {
            const short h = f2bf(fv[j]);
            ah[ks][j] = h;
            al[ks][j] = f2bf(fv[j] - bf2f(h));
          }
        }
        f32x4 acc = (f32x4)0.f;
#pragma unroll
        for (int ks = 0; ks < 2; ks++) {
          acc = __builtin_amdgcn_mfma_f32_16x16x32_bf16(ah[ks], Bbh[ks], acc, 0, 0, 0);
          acc = __builtin_amdgcn_mfma_f32_16x16x32_bf16(ah[ks], Bbl[ks], acc, 0, 0, 0);
          acc = __builtin_amdgcn_mfma_f32_16x16x32_bf16(al[ks], Bbh[ks], acc, 0, 0, 0);
        }
#pragma unroll
        for (int reg = 0; reg < 4; reg++) {
          const float v = acc[reg] + bbv;
          float m = v;
#pragma unroll
          for (int d = 1; d < 16; d <<= 1) m = fmaxf(m, __shfl_xor(m, d));
          const float e = __expf(v - m);
          float sum = e;
#pragma unroll
          for (int d = 1; d < 16; d <<= 1) sum += __shfl_xor(sum, d);
          lato[(size_t)(mb + q * 4 + reg) * kRP + p] = e / sum;
        }
      }
    }
  }
}

// ---------- per-node partial sums C1[o][k], R2[s][k] ----------
__global__ void __launch_bounds__(256)
k_partials(const int* __restrict__ rowptr_s, const int2* __restrict__ eo_s,
           const int* __restrict__ rowptr_o, const int* __restrict__ e_o,
           const float* __restrict__ lat1, const float* __restrict__ lat2,
           float* __restrict__ C1, float* __restrict__ R2,
           float* __restrict__ tots) {
  __shared__ float st[2][4];
  const int tid = threadIdx.x;
  const int wave = tid >> 6, lane = tid & 63;
  const int k = lane & 15, g = lane >> 4;
  float t1 = 0.f, t2 = 0.f;
  const int nw = gridDim.x * 4;
  for (int n = blockIdx.x * 4 + wave; n < kN; n += nw) {
    {
      const int beg = rowptr_s[n], end = rowptr_s[n + 1];
      float acc = 0.f;
      for (int j = beg + g; j < end; j += 4)
        acc += lat2[(size_t)eo_s[j].x * kRP + k];
      acc += __shfl_xor(acc, 16); acc += __shfl_xor(acc, 32);
      if (g == 0) { R2[n * kRP + k] = acc; if (k == 0) t2 += acc; }
    }
    {
      const int beg = rowptr_o[n], end = rowptr_o[n + 1];
      float acc = 0.f;
      for (int j = beg + g; j < end; j += 4)
        acc += lat1[(size_t)e_o[j] * kRP + k];
      acc += __shfl_xor(acc, 16); acc += __shfl_xor(acc, 32);
      if (g == 0) { C1[n * kRP + k] = acc; if (k == 0) t1 += acc; }
    }
  }
  if (lane == 0) { st[0][wave] = t1; st[1][wave] = t2; }
  __syncthreads();
  if (tid == 0) {
    atomicAdd(&tots[0], st[0][0] + st[0][1] + st[0][2] + st[0][3]);
    atomicAdd(&tots[1], st[1][0] + st[1][1] + st[1][2] + st[1][3]);
  }
}

// ---------- csinv/rsinv via divisor enumeration ----------
__global__ void __launch_bounds__(256)
k_norms(const float* __restrict__ C1, const float* __restrict__ R2,
        const float* __restrict__ tots,
        float* __restrict__ csinv, float* __restrict__ rsinv) {
  const int m = blockIdx.x * 256 + threadIdx.x;
  if (m < kNRP) {
    float cs = (m == 0) ? tots[0] : 0.f;
    float rs = (m == 0) ? tots[1] : 0.f;
#pragma unroll
    for (int k = 1; k < kRP; k++) {
      if (m % k == 0) {
        const int q = m / k;
        if (q < kN) { cs += C1[q * kRP + k]; rs += R2[q * kRP + k]; }
      }
    }
    csinv[m] = (cs != 0.f) ? 1.f / cs : 0.f;
    rsinv[m] = (rs != 0.f) ? 1.f / rs : 0.f;
  }
}

// ---------- G build: G8[o][l][j] bf16, l=c*2+kh, j=0..7, k=kh*8+j ----------
// value = csinv[o*k] * wt1[o*k][c].  1 KB per o, coalesced write.
__global__ void __launch_bounds__(256)
k_gbuild(const float* __restrict__ wt1, const float* __restrict__ csinv,
         unsigned* __restrict__ G8u) {
  __shared__ float sT[16][33];
  const int o = blockIdx.x;
  const int tid = threadIdx.x;
#pragma unroll
  for (int half = 0; half < 2; half++) {
    const int e = half * 256 + tid;          // (k,c)
    const int k = e >> 5, c = e & 31;
    const int idx = o * k;
    sT[k][c] = csinv[idx] * wt1[(size_t)idx * kE + c];
  }
  __syncthreads();
  // pack 2 bf16 per thread: word t -> shorts f=2t,2t+1
  const int l = tid >> 2;                    // 0..63
  const int c = l >> 1, kh = l & 1;
  const int j0 = (2 * tid) & 7;
  const int k0 = kh * 8 + j0, k1 = k0 + 1;
  const unsigned lo = (unsigned short)f2bf(sT[k0][c]);
  const unsigned hi = (unsigned short)f2bf(sT[k1][c]);
  G8u[(size_t)o * 256 + tid] = lo | (hi << 16);
}

// ---------- layer-1 gather via G: 16 B/lane/edge, contiguous ----------
__global__ void __launch_bounds__(256)
k_layer1g(const int* __restrict__ rowptr, const int2* __restrict__ eo,
          const float* __restrict__ lat1, const uint4* __restrict__ G8,
          const float* __restrict__ bias1, float* __restrict__ h) {
  const int tid = threadIdx.x;
  const int wave = tid >> 6, lane = tid & 63;
  const int c = lane >> 1, kh = lane & 1;
  const float b1 = bias1[c];
  for (int s = blockIdx.x * 4 + wave; s < kN; s += gridDim.x * 4) {
    float acc = 0.f;
    const int beg = rowptr[s], end = rowptr[s + 1];
    for (int j = beg; j < end; j++) {
      const int2 E = eo[j];
      const uint4 g = G8[(size_t)E.y * 64 + lane];
      const float4 la = *(const float4*)(lat1 + (size_t)E.x * kRP + kh * 8);
      const float4 lb = *(const float4*)(lat1 + (size_t)E.x * kRP + kh * 8 + 4);
      acc = fmaf(la.x, bflo(g.x), acc); acc = fmaf(la.y, bfhi(g.x), acc);
      acc = fmaf(la.z, bflo(g.y), acc); acc = fmaf(la.w, bfhi(g.y), acc);
      acc = fmaf(lb.x, bflo(g.z), acc); acc = fmaf(lb.y, bfhi(g.z), acc);
      acc = fmaf(lb.z, bflo(g.w), acc); acc = fmaf(lb.w, bfhi(g.w), acc);
    }
    acc += __shfl_xor(acc, 1);
    if (kh == 0) h[(size_t)s * kE + c] = fmaxf(acc + b1, 0.f);
  }
}

// ---------- per-s walk -> Ub[s][k-1][c] bf16; also hrow0 partials (k=0) ----------
__global__ void __launch_bounds__(256)
k_u(const int* __restrict__ rowptr, const int2* __restrict__ eo,
    const float* __restrict__ lat2, const float* __restrict__ rsinv,
    const float* __restrict__ h, short* __restrict__ Ub,
    float* __restrict__ pblk) {
  __shared__ float sacc[kE];
  const int tid = threadIdx.x;
  const int wave = tid >> 6, lane = tid & 63;
  const int c = lane & 31, half = lane >> 5;
  if (tid < kE) sacc[tid] = 0.f;
  __syncthreads();
  float hpart = 0.f;
  for (int s = blockIdx.x * 4 + wave; s < kN; s += gridDim.x * 4) {
    float u[8];
#pragma unroll
    for (int kk = 0; kk < 8; kk++) u[kk] = 0.f;
    const int beg = rowptr[s], end = rowptr[s + 1];
    for (int j = beg; j < end; j++) {
      const int2 E = eo[j];
      const float hv = h[(size_t)E.y * kE + c];
      const float4* lp = (const float4*)(lat2 + (size_t)E.x * kRP) + half * 2;
      const float4 la = lp[0], lb = lp[1];
      const float lv[8] = {la.x, la.y, la.z, la.w, lb.x, lb.y, lb.z, lb.w};
#pragma unroll
      for (int kk = 0; kk < 8; kk++) u[kk] = fmaf(lv[kk], hv, u[kk]);
    }
    if (half == 0) hpart += u[0];      // k=0 contribution to h2 row 0 (raw)
#pragma unroll
    for (int kk = 0; kk < 8; kk++) {
      const int k = half * 8 + kk;
      if (k >= 1)
        Ub[((size_t)s * 15 + (k - 1)) * kE + c] = f2bf(u[kk] * rsinv[s * k]);
    }
  }
  atomicAdd(&sacc[c], hpart);          // LDS atomic
  __syncthreads();
  if (tid < kE) pblk[(size_t)blockIdx.x * kE + tid] = sacc[tid];
}

// ---------- reduce per-block hrow0 partials ----------
__global__ void __launch_bounds__(256)
k_hred(const float* __restrict__ pblk, int nblk, float* __restrict__ hrow0) {
  __shared__ float sacc[kE];
  const int tid = threadIdx.x;
  if (tid < kE) sacc[tid] = 0.f;
  __syncthreads();
  const int total = nblk * kE;
  float r = 0.f;
  for (int i = blockIdx.x * 256 + tid; i < total; i += gridDim.x * 256)
    r += pblk[i];
  atomicAdd(&sacc[tid & 31], r);       // stride gridDim*256 ≡ 0 mod 32 -> c fixed
  __syncthreads();
  if (tid < kE) atomicAdd(&hrow0[tid], sacc[tid]);
}

// ---------- dense H2[n][r][c] (bf16) via divisor gather ----------
__global__ void __launch_bounds__(256)
k_h2(const short* __restrict__ Ub, const float* __restrict__ hrow0,
     const float* __restrict__ rsinv, short* __restrict__ H2) {
  const int tid = threadIdx.x;
  const int g = tid >> 5, c = tid & 31;
  const int n = blockIdx.x * 8 + g;          // grid = kN/8 exact
  const float rs0 = rsinv[0];
#pragma unroll 1
  for (int r = 0; r < kRP; r++) {
    const int m = r * kN + n;
    float row = (m == 0) ? hrow0[c] * rs0 : 0.f;
#pragma unroll
    for (int k = 1; k < kRP; k++) {
      if (m % k == 0) {
        const int s = m / k;
        if (s < kN) row += bf2f(Ub[((size_t)s * 15 + (k - 1)) * kE + c]);
      }
    }
    H2[((size_t)n * kRP + r) * kE + c] = f2bf(row);
  }
}

// ---------- out = H2[N,512]bf16 @ W2[512,32] (split hi/lo) + bias2, fp32 out ----------
__global__ void __launch_bounds__(256)
k_einsum(const short* __restrict__ H2, const float* __restrict__ W2,
         const float* __restrict__ bias2, float* __restrict__ out) {
  __shared__ short sBWh[16 * 2 * 64 * 8];    // 32 KB
  __shared__ short sBWl[16 * 2 * 64 * 8];    // 32 KB
  const int tid = threadIdx.x;
  for (int i = tid; i < 16384; i += 256) {
    const int j = i & 7, ln = (i >> 3) & 63, nt = (i >> 9) & 1, ks = i >> 10;
    const int pp = ln & 15, qq8 = (ln >> 4) * 8;
    const float v = W2[(ks * 32 + qq8 + j) * 32 + nt * 16 + pp];
    const short h = f2bf(v);
    sBWh[i] = h;
    sBWl[i] = f2bf(v - bf2f(h));
  }
  __syncthreads();
  const int wave = tid >> 6, lane = tid & 63;
  const int p = lane & 15, q = lane >> 4, q8 = q * 8;
  const float bias0 = bias2[p], bias1v = bias2[16 + p];
  for (int tile = blockIdx.x * 4 + wave; tile < kN / 16; tile += gridDim.x * 4) {
    const int mb = tile * 16;
    f32x4 acc0 = (f32x4)0.f, acc1 = (f32x4)0.f;
    const short* arow = H2 + (size_t)(mb + p) * 512 + q8;
#pragma unroll
    for (int ks = 0; ks < 16; ks++) {
      const s8v a   = *(const s8v*)(arow + ks * 32);
      const s8v b0h = *(const s8v*)(sBWh + ((ks * 2 + 0) * 64 + lane) * 8);
      const s8v b0l = *(const s8v*)(sBWl + ((ks * 2 + 0) * 64 + lane) * 8);
      const s8v b1h = *(const s8v*)(sBWh + ((ks * 2 + 1) * 64 + lane) * 8);
      const s8v b1l = *(const s8v*)(sBWl + ((ks * 2 + 1) * 64 + lane) * 8);
      acc0 = __builtin_amdgcn_mfma_f32_16x16x32_bf16(a, b0h, acc0, 0, 0, 0);
      acc0 = __builtin_amdgcn_mfma_f32_16x16x32_bf16(a, b0l, acc0, 0, 0, 0);
      acc1 = __builtin_amdgcn_mfma_f32_16x16x32_bf16(a, b1h, acc1, 0, 0, 0);
      acc1 = __builtin_amdgcn_mfma_f32_16x16x32_bf16(a, b1l, acc1, 0, 0, 0);
    }
#pragma unroll
    for (int reg = 0; reg < 4; reg++) {
      const int n = mb + q * 4 + reg;
      out[(size_t)n * kC + p]      = acc0[reg] + bias0;
      out[(size_t)n * kC + 16 + p] = acc1[reg] + bias1v;
    }
  }
}

// ---------- host ----------
extern "C" void kernel_launch(void* const* d_in, const int* in_sizes, int n_in,
                              void* d_out, int out_size, void* d_ws, size_t ws_size,
                              hipStream_t stream) {
  (void)in_sizes; (void)n_in; (void)out_size; (void)ws_size;
  const int* s_idx = (const int*)d_in[0];
  const int* o_idx = (const int*)d_in[1];
  const float* nhots = (const float*)d_in[2];
  const float* W1a = (const float*)d_in[3]; const float* b1a = (const float*)d_in[4];
  const float* W1b = (const float*)d_in[5]; const float* b1b = (const float*)d_in[6];
  const float* W2a = (const float*)d_in[7]; const float* b2a = (const float*)d_in[8];
  const float* W2b = (const float*)d_in[9]; const float* b2b = (const float*)d_in[10];
  const float* wt1 = (const float*)d_in[11]; const float* wt2 = (const float*)d_in[12];
  const float* bias1 = (const float*)d_in[13]; const float* bias2 = (const float*)d_in[14];

  char* ws = (char*)d_ws;
  size_t off = 0;
  auto alloc = [&](size_t bytes) -> char* {
    char* p = ws + off;
    off = (off + bytes + 255) & ~(size_t)255;
    return p;
  };
  char*  z0       = ws;                                    // zero region start
  int*   cnt_s    = (int*)  alloc((size_t)kN * 4);
  int*   cnt_o    = (int*)  alloc((size_t)kN * 4);
  int*   cursor_s = (int*)  alloc((size_t)kN * 4);
  int*   cursor_o = (int*)  alloc((size_t)kN * 4);
  float* tots     = (float*)alloc(8);
  float* hrow0    = (float*)alloc((size_t)kE * 4);
  const size_t zbytes = (size_t)((ws + off) - z0);         // ~0.8 MB
  int*   bs_s     = (int*)  alloc((size_t)kChunks * 4);
  int*   bs_o     = (int*)  alloc((size_t)kChunks * 4);
  int*   rowptr_s = (int*)  alloc((size_t)(kN + 1) * 4);
  int*   rowptr_o = (int*)  alloc((size_t)(kN + 1) * 4);
  float* pblk     = (float*)alloc((size_t)12500 * kE * 4); // 1.6 MB
  float* lat2     = (float*)alloc((size_t)kNT * kRP * 4);  // 19.2 MB
  int2*  eo_s     = (int2*) alloc((size_t)kNT * 8);        // 2.4 MB
  int*   e_o      = (int*)  alloc((size_t)kNT * 4);        // 1.2 MB
  float* C1       = (float*)alloc((size_t)kNRP * 4);       // 3.2 MB
  float* R2       = (float*)alloc((size_t)kNRP * 4);       // 3.2 MB
  float* csinv    = (float*)alloc((size_t)kNRP * 4);       // 3.2 MB
  float* rsinv    = (float*)alloc((size_t)kNRP * 4);       // 3.2 MB
  float* hbuf     = (float*)alloc((size_t)kN * kE * 4);    // 6.4 MB
  short* Ub       = (short*)alloc((size_t)kN * 15 * kE * 2);   // 48 MB
  char*  Greg     = alloc((size_t)kN * 1024);                  // 51.2 MB (G8, then H2)
  float* lat1     = (float*)Ub;        // alias: lat1 dead before k_u writes Ub
  unsigned* G8u   = (unsigned*)Greg;   // G dead before k_h2 writes H2
  short* H2       = (short*)Greg;
  // total ~144 MB (< 150.6 MB proven by round 3)

  hipMemsetAsync(z0, 0, zbytes, stream);

  const dim3 blk(256);
  const int gEdges = (kNT + 255) / 256;
  const int gLat = ((kNT / 32 + 1) / 2 + 3) / 4;   // 2 tiles/wave, 4 waves/block

  k_count<<<gEdges, blk, 0, stream>>>(s_idx, o_idx, cnt_s, cnt_o);
  k_scan_p1<<<2 * kChunks, blk, 0, stream>>>(cnt_s, cnt_o, rowptr_s, rowptr_o, bs_s, bs_o);
  k_scan_p2<<<1, blk, 0, stream>>>(bs_s, bs_o);
  k_scan_p3<<<2 * kChunks, blk, 0, stream>>>(bs_s, bs_o, rowptr_s, rowptr_o);
  k_scatter2<<<gEdges, blk, 0, stream>>>(s_idx, o_idx, rowptr_s, cursor_s,
                                         rowptr_o, cursor_o, eo_s, e_o);
  k_lat<<<gLat, blk, 0, stream>>>(nhots, W1a, b1a, W1b, b1b,
                                  W2a, b2a, W2b, b2b, lat1, lat2);
  k_partials<<<512, blk, 0, stream>>>(rowptr_s, eo_s, rowptr_o, e_o,
                                      lat1, lat2, C1, R2, tots);
  k_norms<<<(kNRP + 255) / 256, blk, 0, stream>>>(C1, R2, tots, csinv, rsinv);
  k_gbuild<<<kN, blk, 0, stream>>>(wt1, csinv, G8u);
  k_layer1g<<<12500, blk, 0, stream>>>(rowptr_s, eo_s, lat1, (const uint4*)G8u, bias1, hbuf);
  k_u<<<12500, blk, 0, stream>>>(rowptr_s, eo_s, lat2, rsinv, hbuf, Ub, pblk);
  k_hred<<<50, blk, 0, stream>>>(pblk, 12500, hrow0);
  k_h2<<<kN / 8, blk, 0, stream>>>(Ub, hrow0, rsinv, H2);
  k_einsum<<<782, blk, 0, stream>>>(H2, wt2, bias2, (float*)d_out);
}

// Round 8
// 642.863 us; speedup vs baseline: 14.2535x; 1.0665x over previous
//
#include <hip/hip_runtime.h>
#include <hip/hip_bf16.h>

#define DEV_INLINE __device__ __forceinline__

constexpr int kN   = 50000;
constexpr int kNT  = 300000;
constexpr int kR   = 64;
constexpr int kRP  = 16;
constexpr int kE   = 32;
constexpr int kC   = 32;
constexpr int kLW  = 64;
constexpr int kNRP = kN * kRP;     // 800000
constexpr int kChunks = (kN + 255) / 256;   // 196

typedef __attribute__((ext_vector_type(8))) short s8v;    // 8 bf16 (4 VGPRs)
typedef __attribute__((ext_vector_type(4))) float f32x4;  // MFMA acc

DEV_INLINE short f2bf(float f) {   // fp32 -> bf16 bits, RNE
  union { float f; unsigned u; } v; v.f = f;
  unsigned r = (v.u + 0x7fffu + ((v.u >> 16) & 1u)) >> 16;
  return (short)r;
}
DEV_INLINE float bf2f(short s) {
  union { unsigned u; float f; } v; v.u = ((unsigned)(unsigned short)s) << 16;
  return v.f;
}
DEV_INLINE float bflo(unsigned u) { union { unsigned x; float f; } a; a.x = u << 16;        return a.f; }
DEV_INLINE float bfhi(unsigned u) { union { unsigned x; float f; } a; a.x = u & 0xffff0000u; return a.f; }

union U4S8 { uint4 u; s8v s; };

// split 8 fp32 -> hi (truncated bf16) + lo (exact residual, truncated bf16)
DEV_INLINE void split8(const float4 A, const float4 B, s8v& hi, s8v& lo) {
  const float f[8] = {A.x, A.y, A.z, A.w, B.x, B.y, B.z, B.w};
  unsigned u[8], l[8];
#pragma unroll
  for (int i = 0; i < 8; i++) { union { float f; unsigned u; } c; c.f = f[i]; u[i] = c.u; }
#pragma unroll
  for (int i = 0; i < 8; i++) {
    union { unsigned u; float f; } t; t.u = u[i] & 0xffff0000u;
    union { float f; unsigned u; } c; c.f = f[i] - t.f; l[i] = c.u;
  }
  U4S8 H, L;
  H.u.x = (u[1] & 0xffff0000u) | (u[0] >> 16);
  H.u.y = (u[3] & 0xffff0000u) | (u[2] >> 16);
  H.u.z = (u[5] & 0xffff0000u) | (u[4] >> 16);
  H.u.w = (u[7] & 0xffff0000u) | (u[6] >> 16);
  L.u.x = (l[1] & 0xffff0000u) | (l[0] >> 16);
  L.u.y = (l[3] & 0xffff0000u) | (l[2] >> 16);
  L.u.z = (l[5] & 0xffff0000u) | (l[4] >> 16);
  L.u.w = (l[7] & 0xffff0000u) | (l[6] >> 16);
  hi = H.s; lo = L.s;
}

// ---------- K0: degree counts for both CSRs ----------
__global__ void __launch_bounds__(256)
k_count(const int* __restrict__ s_idx, const int* __restrict__ o_idx,
        int* __restrict__ cnt_s, int* __restrict__ cnt_o) {
  const int e = blockIdx.x * 256 + threadIdx.x;
  if (e < kNT) {
    atomicAdd(&cnt_s[s_idx[e]], 1);
    atomicAdd(&cnt_o[o_idx[e]], 1);
  }
}

// ---------- parallel scan, phase 1 ----------
__global__ void __launch_bounds__(256)
k_scan_p1(const int* __restrict__ cnt_s, const int* __restrict__ cnt_o,
          int* __restrict__ rp_s, int* __restrict__ rp_o,
          int* __restrict__ bs_s, int* __restrict__ bs_o) {
  const int b = blockIdx.x;
  const bool iso = b >= kChunks;
  const int chunk = iso ? b - kChunks : b;
  const int* cnt = iso ? cnt_o : cnt_s;
  int* rp = iso ? rp_o : rp_s;
  int* bs = iso ? bs_o : bs_s;
  __shared__ int ws[4];
  const int tid = threadIdx.x, wave = tid >> 6, lane = tid & 63;
  const int i = chunk * 256 + tid;
  int v = (i < kN) ? cnt[i] : 0;
  int incl = v;
#pragma unroll
  for (int off = 1; off < 64; off <<= 1) {
    int tmp = __shfl_up(incl, off, 64);
    if (lane >= off) incl += tmp;
  }
  if (lane == 63) ws[wave] = incl;
  __syncthreads();
  int add = 0;
#pragma unroll
  for (int w = 0; w < 4; w++) if (w < wave) add += ws[w];
  incl += add;
  if (i < kN) rp[i + 1] = incl;
  if (tid == 255) bs[chunk] = incl;
}

// ---------- phase 2 ----------
__global__ void __launch_bounds__(256)
k_scan_p2(int* __restrict__ bs_s, int* __restrict__ bs_o) {
  __shared__ int ws[4];
  const int tid = threadIdx.x, wave = tid >> 6, lane = tid & 63;
#pragma unroll 1
  for (int a = 0; a < 2; a++) {
    int* bs = a ? bs_o : bs_s;
    const int v = (tid < kChunks) ? bs[tid] : 0;
    int incl = v;
#pragma unroll
    for (int off = 1; off < 64; off <<= 1) {
      int tmp = __shfl_up(incl, off, 64);
      if (lane >= off) incl += tmp;
    }
    if (lane == 63) ws[wave] = incl;
    __syncthreads();
    int add = 0;
#pragma unroll
    for (int w = 0; w < 4; w++) if (w < wave) add += ws[w];
    incl += add;
    __syncthreads();
    if (tid < kChunks) bs[tid] = incl - v;
    __syncthreads();
  }
}

// ---------- phase 3 ----------
__global__ void __launch_bounds__(256)
k_scan_p3(const int* __restrict__ bs_s, const int* __restrict__ bs_o,
          int* __restrict__ rp_s, int* __restrict__ rp_o) {
  const int b = blockIdx.x;
  const bool iso = b >= kChunks;
  const int chunk = iso ? b - kChunks : b;
  int* rp = iso ? rp_o : rp_s;
  const int* bs = iso ? bs_o : bs_s;
  const int i = chunk * 256 + threadIdx.x;
  if (i < kN) rp[i + 1] += bs[chunk];
  if (chunk == 0 && threadIdx.x == 0) rp[0] = 0;
}

// ---------- scatter edge ids into both CSRs ----------
__global__ void __launch_bounds__(256)
k_scatter2(const int* __restrict__ s_idx, const int* __restrict__ o_idx,
           const int* __restrict__ rowptr_s, int* __restrict__ cursor_s,
           const int* __restrict__ rowptr_o, int* __restrict__ cursor_o,
           int2* __restrict__ eo_s, int* __restrict__ e_o) {
  const int e = blockIdx.x * 256 + threadIdx.x;
  if (e < kNT) {
    const int s = s_idx[e], o = o_idx[e];
    const int ps = atomicAdd(&cursor_s[s], 1);
    int2 v; v.x = e; v.y = o;
    eo_s[rowptr_s[s] + ps] = v;
    const int po = atomicAdd(&cursor_o[o], 1);
    e_o[rowptr_o[o] + po] = e;
  }
}

// ---------- W-frag prep: split-bf16 fragments in B-layout, once ----------
// Layout (shorts): BaH[8192] | BaL[8192] | BbH[2048] | BbL[2048]
// Ba idx: ((mlp*4+nt)*2+ks)*512 + lane*8 + j ; Bb idx: (mlp*2+ks)*512 + lane*8 + j
__global__ void __launch_bounds__(256)
k_wprep(const float* __restrict__ W1a, const float* __restrict__ W1b,
        const float* __restrict__ W2a, const float* __restrict__ W2b,
        short* __restrict__ Wf) {
  const int tid = threadIdx.x;
  for (int i = tid; i < 8192; i += 256) {
    const int j = i & 7, lane = (i >> 3) & 63, ks = (i >> 9) & 1,
              nt = (i >> 10) & 3, mlp = i >> 12;
    const int p = lane & 15, q8 = (lane >> 4) * 8;
    const float* Wa = mlp ? W2a : W1a;
    const float v = Wa[(ks * 32 + q8 + j) * kLW + nt * 16 + p];
    union { float f; unsigned u; } c; c.f = v;
    const short h = (short)(c.u >> 16);
    Wf[i] = h;
    Wf[8192 + i] = f2bf(v - bf2f(h));
  }
  for (int i = tid; i < 2048; i += 256) {
    const int j = i & 7, lane = (i >> 3) & 63, ks = (i >> 9) & 1, mlp = i >> 10;
    const int p = lane & 15, q8 = (lane >> 4) * 8;
    const float* Wb = mlp ? W2b : W1b;
    const float v = Wb[(ks * 32 + q8 + j) * kRP + p];
    union { float f; unsigned u; } c; c.f = v;
    const short h = (short)(c.u >> 16);
    Wf[16384 + i] = h;
    Wf[18432 + i] = f2bf(v - bf2f(h));
  }
}

// ---------- K1: BOTH edge MLPs + softmax via split-bf16 MFMA ----------
// Layouts [m89/m91/m118]: A[m=lane&15][k=(lane>>4)*8+j],
// B[k=(lane>>4)*8+j][n=lane&15], C/D col=lane&15, row=(lane>>4)*4+reg.
__global__ void __launch_bounds__(256)
k_lat(const float* __restrict__ nhots, const short* __restrict__ Wf,
      const float* __restrict__ b1a, const float* __restrict__ b1b,
      const float* __restrict__ b2a, const float* __restrict__ b2b,
      float* __restrict__ lat1o, float* __restrict__ lat2o) {
  __shared__ float sHf[4][16][68];       // 17.4 KB, per-wave tile (stride 68: 16B-aligned, 2-way free)
  const int tid = threadIdx.x;
  const int wave = tid >> 6, lane = tid & 63;
  const int p = lane & 15, q = lane >> 4, q8 = (lane >> 4) * 8;

  const uint4* BaH4 = (const uint4*)(Wf);
  const uint4* BaL4 = (const uint4*)(Wf + 8192);
  const uint4* BbH4 = (const uint4*)(Wf + 16384);
  const uint4* BbL4 = (const uint4*)(Wf + 18432);

  const int w2 = (blockIdx.x * 4 + wave) * 2;   // first of 2 tile slots

#pragma unroll 1
  for (int mlp = 0; mlp < 2; mlp++) {
    s8v Bh[4][2], Bl[4][2], Bbh[2], Bbl[2];
#pragma unroll
    for (int nt = 0; nt < 4; nt++)
#pragma unroll
      for (int ks = 0; ks < 2; ks++) {
        U4S8 a, b;
        a.u = BaH4[((mlp * 4 + nt) * 2 + ks) * 64 + lane];
        b.u = BaL4[((mlp * 4 + nt) * 2 + ks) * 64 + lane];
        Bh[nt][ks] = a.s; Bl[nt][ks] = b.s;
      }
#pragma unroll
    for (int ks = 0; ks < 2; ks++) {
      U4S8 a, b;
      a.u = BbH4[(mlp * 2 + ks) * 64 + lane];
      b.u = BbL4[(mlp * 2 + ks) * 64 + lane];
      Bbh[ks] = a.s; Bbl[ks] = b.s;
    }
    const float* bA = mlp ? b2a : b1a;
    const float* bB = mlp ? b2b : b1b;
    float bav[4];
#pragma unroll
    for (int nt = 0; nt < 4; nt++) bav[nt] = bA[nt * 16 + p];
    const float bbv = bB[p];
    float* lato = mlp ? lat2o : lat1o;

#pragma unroll 1
    for (int t = 0; t < 2; t++) {
      const int slot = w2 + t;
      if (slot >= kNT / 32) break;
      const int eb = slot * 32;
#pragma unroll 1
      for (int ht = 0; ht < 2; ht++) {
        const int mb = eb + ht * 16;
        // ---- layer A ----
        const float* arow = nhots + (size_t)(mb + p) * kR;
        s8v ah[2], al[2];
#pragma unroll
        for (int ks = 0; ks < 2; ks++) {
          const float4 xa = *(const float4*)(arow + ks * 32 + q8);
          const float4 xb = *(const float4*)(arow + ks * 32 + q8 + 4);
          split8(xa, xb, ah[ks], al[ks]);
        }
        f32x4 acc[4];
#pragma unroll
        for (int nt = 0; nt < 4; nt++) {
          acc[nt] = (f32x4)0.f;
#pragma unroll
          for (int ks = 0; ks < 2; ks++) {
            acc[nt] = __builtin_amdgcn_mfma_f32_16x16x32_bf16(ah[ks], Bh[nt][ks], acc[nt], 0, 0, 0);
            acc[nt] = __builtin_amdgcn_mfma_f32_16x16x32_bf16(ah[ks], Bl[nt][ks], acc[nt], 0, 0, 0);
            acc[nt] = __builtin_amdgcn_mfma_f32_16x16x32_bf16(al[ks], Bh[nt][ks], acc[nt], 0, 0, 0);
          }
        }
#pragma unroll
        for (int nt = 0; nt < 4; nt++)
#pragma unroll
          for (int reg = 0; reg < 4; reg++)
            sHf[wave][q * 4 + reg][nt * 16 + p] = fmaxf(acc[nt][reg] + bav[nt], 0.f);
        // ---- layer B + softmax (same wave; compiler inserts lgkmcnt) ----
        const float* hr = &sHf[wave][p][0];
        s8v hh[2], hl[2];
#pragma unroll
        for (int ks = 0; ks < 2; ks++) {
          const float4 xa = *(const float4*)(hr + ks * 32 + q8);
          const float4 xb = *(const float4*)(hr + ks * 32 + q8 + 4);
          split8(xa, xb, hh[ks], hl[ks]);
        }
        f32x4 accB = (f32x4)0.f;
#pragma unroll
        for (int ks = 0; ks < 2; ks++) {
          accB = __builtin_amdgcn_mfma_f32_16x16x32_bf16(hh[ks], Bbh[ks], accB, 0, 0, 0);
          accB = __builtin_amdgcn_mfma_f32_16x16x32_bf16(hh[ks], Bbl[ks], accB, 0, 0, 0);
          accB = __builtin_amdgcn_mfma_f32_16x16x32_bf16(hl[ks], Bbh[ks], accB, 0, 0, 0);
        }
#pragma unroll
        for (int reg = 0; reg < 4; reg++) {
          const float v = accB[reg] + bbv;
          float m = v;
#pragma unroll
          for (int d = 1; d < 16; d <<= 1) m = fmaxf(m, __shfl_xor(m, d));
          const float e = __expf(v - m);
          float sum = e;
#pragma unroll
          for (int d = 1; d < 16; d <<= 1) sum += __shfl_xor(sum, d);
          lato[(size_t)(mb + q * 4 + reg) * kRP + p] = e / sum;
        }
      }
    }
  }
}

// ---------- per-node partial sums C1[o][k], R2[s][k] ----------
__global__ void __launch_bounds__(256)
k_partials(const int* __restrict__ rowptr_s, const int2* __restrict__ eo_s,
           const int* __restrict__ rowptr_o, const int* __restrict__ e_o,
           const float* __restrict__ lat1, const float* __restrict__ lat2,
           float* __restrict__ C1, float* __restrict__ R2,
           float* __restrict__ tots) {
  __shared__ float st[2][4];
  const int tid = threadIdx.x;
  const int wave = tid >> 6, lane = tid & 63;
  const int k = lane & 15, g = lane >> 4;
  float t1 = 0.f, t2 = 0.f;
  const int nw = gridDim.x * 4;
  for (int n = blockIdx.x * 4 + wave; n < kN; n += nw) {
    {
      const int beg = rowptr_s[n], end = rowptr_s[n + 1];
      float acc = 0.f;
      for (int j = beg + g; j < end; j += 4)
        acc += lat2[(size_t)eo_s[j].x * kRP + k];
      acc += __shfl_xor(acc, 16); acc += __shfl_xor(acc, 32);
      if (g == 0) { R2[n * kRP + k] = acc; if (k == 0) t2 += acc; }
    }
    {
      const int beg = rowptr_o[n], end = rowptr_o[n + 1];
      float acc = 0.f;
      for (int j = beg + g; j < end; j += 4)
        acc += lat1[(size_t)e_o[j] * kRP + k];
      acc += __shfl_xor(acc, 16); acc += __shfl_xor(acc, 32);
      if (g == 0) { C1[n * kRP + k] = acc; if (k == 0) t1 += acc; }
    }
  }
  if (lane == 0) { st[0][wave] = t1; st[1][wave] = t2; }
  __syncthreads();
  if (tid == 0) {
    atomicAdd(&tots[0], st[0][0] + st[0][1] + st[0][2] + st[0][3]);
    atomicAdd(&tots[1], st[1][0] + st[1][1] + st[1][2] + st[1][3]);
  }
}

// ---------- csinv/rsinv via divisor enumeration ----------
__global__ void __launch_bounds__(256)
k_norms(const float* __restrict__ C1, const float* __restrict__ R2,
        const float* __restrict__ tots,
        float* __restrict__ csinv, float* __restrict__ rsinv) {
  const int m = blockIdx.x * 256 + threadIdx.x;
  if (m < kNRP) {
    float cs = (m == 0) ? tots[0] : 0.f;
    float rs = (m == 0) ? tots[1] : 0.f;
#pragma unroll
    for (int k = 1; k < kRP; k++) {
      if (m % k == 0) {
        const int q = m / k;
        if (q < kN) { cs += C1[q * kRP + k]; rs += R2[q * kRP + k]; }
      }
    }
    csinv[m] = (cs != 0.f) ? 1.f / cs : 0.f;
    rsinv[m] = (rs != 0.f) ? 1.f / rs : 0.f;
  }
}

// ---------- G build: G8[o][lane][j] bf16 = csinv[o*k]*wt1[o*k][c] ----------
__global__ void __launch_bounds__(256)
k_gbuild(const float* __restrict__ wt1, const float* __restrict__ csinv,
         unsigned* __restrict__ G8u) {
  __shared__ float sT[16][33];
  const int o = blockIdx.x;
  const int tid = threadIdx.x;
#pragma unroll
  for (int half = 0; half < 2; half++) {
    const int e = half * 256 + tid;
    const int k = e >> 5, c = e & 31;
    const int idx = o * k;
    sT[k][c] = csinv[idx] * wt1[(size_t)idx * kE + c];
  }
  __syncthreads();
  const int l = tid >> 2;
  const int c = l >> 1, kh = l & 1;
  const int j0 = (2 * tid) & 7;
  const int k0 = kh * 8 + j0, k1 = k0 + 1;
  const unsigned lo = (unsigned short)f2bf(sT[k0][c]);
  const unsigned hi = (unsigned short)f2bf(sT[k1][c]);
  G8u[(size_t)o * 256 + tid] = lo | (hi << 16);
}

// ---------- layer-1 gather via G: 16 B/lane/edge ----------
__global__ void __launch_bounds__(256)
k_layer1g(const int* __restrict__ rowptr, const int2* __restrict__ eo,
          const float* __restrict__ lat1, const uint4* __restrict__ G8,
          const float* __restrict__ bias1, float* __restrict__ h) {
  const int tid = threadIdx.x;
  const int wave = tid >> 6, lane = tid & 63;
  const int c = lane >> 1, kh = lane & 1;
  const float b1 = bias1[c];
  for (int s = blockIdx.x * 4 + wave; s < kN; s += gridDim.x * 4) {
    float acc = 0.f;
    const int beg = rowptr[s], end = rowptr[s + 1];
    for (int j = beg; j < end; j++) {
      const int2 E = eo[j];
      const uint4 g = G8[(size_t)E.y * 64 + lane];
      const float4 la = *(const float4*)(lat1 + (size_t)E.x * kRP + kh * 8);
      const float4 lb = *(const float4*)(lat1 + (size_t)E.x * kRP + kh * 8 + 4);
      acc = fmaf(la.x, bflo(g.x), acc); acc = fmaf(la.y, bfhi(g.x), acc);
      acc = fmaf(la.z, bflo(g.y), acc); acc = fmaf(la.w, bfhi(g.y), acc);
      acc = fmaf(lb.x, bflo(g.z), acc); acc = fmaf(lb.y, bfhi(g.z), acc);
      acc = fmaf(lb.z, bflo(g.w), acc); acc = fmaf(lb.w, bfhi(g.w), acc);
    }
    acc += __shfl_xor(acc, 1);
    if (kh == 0) h[(size_t)s * kE + c] = fmaxf(acc + b1, 0.f);
  }
}

// ---------- per-s walk -> Ub[s][k-1][c] bf16; also hrow0 partials (k=0) ----------
__global__ void __launch_bounds__(256)
k_u(const int* __restrict__ rowptr, const int2* __restrict__ eo,
    const float* __restrict__ lat2, const float* __restrict__ rsinv,
    const float* __restrict__ h, short* __restrict__ Ub,
    float* __restrict__ pblk) {
  __shared__ float sacc[kE];
  const int tid = threadIdx.x;
  const int wave = tid >> 6, lane = tid & 63;
  const int c = lane & 31, half = lane >> 5;
  if (tid < kE) sacc[tid] = 0.f;
  __syncthreads();
  float hpart = 0.f;
  for (int s = blockIdx.x * 4 + wave; s < kN; s += gridDim.x * 4) {
    float u[8];
#pragma unroll
    for (int kk = 0; kk < 8; kk++) u[kk] = 0.f;
    const int beg = rowptr[s], end = rowptr[s + 1];
    for (int j = beg; j < end; j++) {
      const int2 E = eo[j];
      const float hv = h[(size_t)E.y * kE + c];
      const float4* lp = (const float4*)(lat2 + (size_t)E.x * kRP) + half * 2;
      const float4 la = lp[0], lb = lp[1];
      const float lv[8] = {la.x, la.y, la.z, la.w, lb.x, lb.y, lb.z, lb.w};
#pragma unroll
      for (int kk = 0; kk < 8; kk++) u[kk] = fmaf(lv[kk], hv, u[kk]);
    }
    if (half == 0) hpart += u[0];
#pragma unroll
    for (int kk = 0; kk < 8; kk++) {
      const int k = half * 8 + kk;
      if (k >= 1)
        Ub[((size_t)s * 15 + (k - 1)) * kE + c] = f2bf(u[kk] * rsinv[s * k]);
    }
  }
  atomicAdd(&sacc[c], hpart);
  __syncthreads();
  if (tid < kE) pblk[(size_t)blockIdx.x * kE + tid] = sacc[tid];
}

// ---------- reduce per-block hrow0 partials ----------
__global__ void __launch_bounds__(256)
k_hred(const float* __restrict__ pblk, int nblk, float* __restrict__ hrow0) {
  __shared__ float sacc[kE];
  const int tid = threadIdx.x;
  if (tid < kE) sacc[tid] = 0.f;
  __syncthreads();
  const int total = nblk * kE;
  float r = 0.f;
  for (int i = blockIdx.x * 256 + tid; i < total; i += gridDim.x * 256)
    r += pblk[i];
  atomicAdd(&sacc[tid & 31], r);
  __syncthreads();
  if (tid < kE) atomicAdd(&hrow0[tid], sacc[tid]);
}

// ---------- dense H2[n][r][c] (bf16) via divisor gather, hoisted n%k ----------
// m = r*50000 + n; m%k==0 <=> n%k == (k - (r*50000)%k)%k (const);
// s = m/k < kN <=> k > r.
__global__ void __launch_bounds__(256)
k_h2(const short* __restrict__ Ub, const float* __restrict__ hrow0,
     const float* __restrict__ rsinv, short* __restrict__ H2) {
  const int tid = threadIdx.x;
  const int g = tid >> 5, c = tid & 31;
  const int n = blockIdx.x * 8 + g;          // grid = kN/8 exact
  const float rs0 = rsinv[0];
  int nm[16];
  nm[0] = 0; nm[1] = 0;
#pragma unroll
  for (int k = 2; k < kRP; k++) nm[k] = n % k;   // magic-mul per const k
#pragma unroll
  for (int r = 0; r < kRP; r++) {
    float row = 0.f;
    if (r == 0 && n == 0) row = hrow0[c] * rs0;
#pragma unroll
    for (int k = r + 1; k < kRP; k++) {
      const int target = (k - (r * 50000) % k) % k;   // compile-time const
      if (nm[k] == target) {
        const int s = (r * 50000 + n) / k;            // magic-div per const k
        row += bf2f(Ub[((size_t)s * 15 + (k - 1)) * kE + c]);
      }
    }
    H2[((size_t)n * kRP + r) * kE + c] = f2bf(row);
  }
}

// ---------- out = H2[N,512]bf16 @ W2[512,32] (split hi/lo) + bias2 ----------
__global__ void __launch_bounds__(256)
k_einsum(const short* __restrict__ H2, const float* __restrict__ W2,
         const float* __restrict__ bias2, float* __restrict__ out) {
  __shared__ short sBWh[16 * 2 * 64 * 8];    // 32 KB
  __shared__ short sBWl[16 * 2 * 64 * 8];    // 32 KB
  const int tid = threadIdx.x;
  for (int i = tid; i < 16384; i += 256) {
    const int j = i & 7, ln = (i >> 3) & 63, nt = (i >> 9) & 1, ks = i >> 10;
    const int pp = ln & 15, qq8 = (ln >> 4) * 8;
    const float v = W2[(ks * 32 + qq8 + j) * 32 + nt * 16 + pp];
    const short h = f2bf(v);
    sBWh[i] = h;
    sBWl[i] = f2bf(v - bf2f(h));
  }
  __syncthreads();
  const int wave = tid >> 6, lane = tid & 63;
  const int p = lane & 15, q = lane >> 4, q8 = q * 8;
  const float bias0 = bias2[p], bias1v = bias2[16 + p];
  for (int tile = blockIdx.x * 4 + wave; tile < kN / 16; tile += gridDim.x * 4) {
    const int mb = tile * 16;
    f32x4 acc0 = (f32x4)0.f, acc1 = (f32x4)0.f;
    const short* arow = H2 + (size_t)(mb + p) * 512 + q8;
#pragma unroll
    for (int ks = 0; ks < 16; ks++) {
      const s8v a   = *(const s8v*)(arow + ks * 32);
      const s8v b0h = *(const s8v*)(sBWh + ((ks * 2 + 0) * 64 + lane) * 8);
      const s8v b0l = *(const s8v*)(sBWl + ((ks * 2 + 0) * 64 + lane) * 8);
      const s8v b1h = *(const s8v*)(sBWh + ((ks * 2 + 1) * 64 + lane) * 8);
      const s8v b1l = *(const s8v*)(sBWl + ((ks * 2 + 1) * 64 + lane) * 8);
      acc0 = __builtin_amdgcn_mfma_f32_16x16x32_bf16(a, b0h, acc0, 0, 0, 0);
      acc0 = __builtin_amdgcn_mfma_f32_16x16x32_bf16(a, b0l, acc0, 0, 0, 0);
      acc1 = __builtin_amdgcn_mfma_f32_16x16x32_bf16(a, b1h, acc1, 0, 0, 0);
      acc1 = __builtin_amdgcn_mfma_f32_16x16x32_bf16(a, b1l, acc1, 0, 0, 0);
    }
#pragma unroll
    for (int reg = 0; reg < 4; reg++) {
      const int n = mb + q * 4 + reg;
      out[(size_t)n * kC + p]      = acc0[reg] + bias0;
      out[(size_t)n * kC + 16 + p] = acc1[reg] + bias1v;
    }
  }
}

// ---------- host ----------
extern "C" void kernel_launch(void* const* d_in, const int* in_sizes, int n_in,
                              void* d_out, int out_size, void* d_ws, size_t ws_size,
                              hipStream_t stream) {
  (void)in_sizes; (void)n_in; (void)out_size; (void)ws_size;
  const int* s_idx = (const int*)d_in[0];
  const int* o_idx = (const int*)d_in[1];
  const float* nhots = (const float*)d_in[2];
  const float* W1a = (const float*)d_in[3]; const float* b1a = (const float*)d_in[4];
  const float* W1b = (const float*)d_in[5]; const float* b1b = (const float*)d_in[6];
  const float* W2a = (const float*)d_in[7]; const float* b2a = (const float*)d_in[8];
  const float* W2b = (const float*)d_in[9]; const float* b2b = (const float*)d_in[10];
  const float* wt1 = (const float*)d_in[11]; const float* wt2 = (const float*)d_in[12];
  const float* bias1 = (const float*)d_in[13]; const float* bias2 = (const float*)d_in[14];

  char* ws = (char*)d_ws;
  size_t off = 0;
  auto alloc = [&](size_t bytes) -> char* {
    char* p = ws + off;
    off = (off + bytes + 255) & ~(size_t)255;
    return p;
  };
  char*  z0       = ws;                                    // zero region start
  int*   cnt_s    = (int*)  alloc((size_t)kN * 4);
  int*   cnt_o    = (int*)  alloc((size_t)kN * 4);
  int*   cursor_s = (int*)  alloc((size_t)kN * 4);
  int*   cursor_o = (int*)  alloc((size_t)kN * 4);
  float* tots     = (float*)alloc(8);
  float* hrow0    = (float*)alloc((size_t)kE * 4);
  const size_t zbytes = (size_t)((ws + off) - z0);         // ~0.8 MB
  short* Wf       = (short*)alloc((size_t)20480 * 2);      // 40 KB W frags
  int*   bs_s     = (int*)  alloc((size_t)kChunks * 4);
  int*   bs_o     = (int*)  alloc((size_t)kChunks * 4);
  int*   rowptr_s = (int*)  alloc((size_t)(kN + 1) * 4);
  int*   rowptr_o = (int*)  alloc((size_t)(kN + 1) * 4);
  float* pblk     = (float*)alloc((size_t)12500 * kE * 4); // 1.6 MB
  float* lat2     = (float*)alloc((size_t)kNT * kRP * 4);  // 19.2 MB
  int2*  eo_s     = (int2*) alloc((size_t)kNT * 8);        // 2.4 MB
  int*   e_o      = (int*)  alloc((size_t)kNT * 4);        // 1.2 MB
  float* C1       = (float*)alloc((size_t)kNRP * 4);       // 3.2 MB
  float* R2       = (float*)alloc((size_t)kNRP * 4);       // 3.2 MB
  float* csinv    = (float*)alloc((size_t)kNRP * 4);       // 3.2 MB
  float* rsinv    = (float*)alloc((size_t)kNRP * 4);       // 3.2 MB
  float* hbuf     = (float*)alloc((size_t)kN * kE * 4);    // 6.4 MB
  short* Ub       = (short*)alloc((size_t)kN * 15 * kE * 2);   // 48 MB
  char*  Greg     = alloc((size_t)kN * 1024);                  // 51.2 MB (G8, then H2)
  float* lat1     = (float*)Ub;        // alias: lat1 dead before k_u writes Ub
  unsigned* G8u   = (unsigned*)Greg;   // G dead before k_h2 writes H2
  short* H2       = (short*)Greg;
  // total ~144 MB (< 150.6 MB proven by round 3)

  hipMemsetAsync(z0, 0, zbytes, stream);

  const dim3 blk(256);
  const int gEdges = (kNT + 255) / 256;
  const int gLat = ((kNT / 32 + 1) / 2 + 3) / 4;   // 2 tiles/wave, 4 waves/block

  k_count<<<gEdges, blk, 0, stream>>>(s_idx, o_idx, cnt_s, cnt_o);
  k_scan_p1<<<2 * kChunks, blk, 0, stream>>>(cnt_s, cnt_o, rowptr_s, rowptr_o, bs_s, bs_o);
  k_scan_p2<<<1, blk, 0, stream>>>(bs_s, bs_o);
  k_scan_p3<<<2 * kChunks, blk, 0, stream>>>(bs_s, bs_o, rowptr_s, rowptr_o);
  k_scatter2<<<gEdges, blk, 0, stream>>>(s_idx, o_idx, rowptr_s, cursor_s,
                                         rowptr_o, cursor_o, eo_s, e_o);
  k_wprep<<<1, blk, 0, stream>>>(W1a, W1b, W2a, W2b, Wf);
  k_lat<<<gLat, blk, 0, stream>>>(nhots, Wf, b1a, b1b, b2a, b2b, lat1, lat2);
  k_partials<<<512, blk, 0, stream>>>(rowptr_s, eo_s, rowptr_o, e_o,
                                      lat1, lat2, C1, R2, tots);
  k_norms<<<(kNRP + 255) / 256, blk, 0, stream>>>(C1, R2, tots, csinv, rsinv);
  k_gbuild<<<kN, blk, 0, stream>>>(wt1, csinv, G8u);
  k_layer1g<<<12500, blk, 0, stream>>>(rowptr_s, eo_s, lat1, (const uint4*)G8u, bias1, hbuf);
  k_u<<<12500, blk, 0, stream>>>(rowptr_s, eo_s, lat2, rsinv, hbuf, Ub, pblk);
  k_hred<<<50, blk, 0, stream>>>(pblk, 12500, hrow0);
  k_h2<<<kN / 8, blk, 0, stream>>>(Ub, hrow0, rsinv, H2);
  k_einsum<<<782, blk, 0, stream>>>(H2, wt2, bias2, (float*)d_out);
}